// Round 2
// baseline (906.008 us; speedup 1.0000x reference)
//
#include <hip/hip_runtime.h>

// Problem constants (fixed by setup_inputs)
#define M_ROWS 262144   // B*A*T = 16*64*256
#define TILE_M 64
#define BK 32

typedef unsigned short ushort_t;
typedef unsigned int uint_t;

// bf16 (stored as ushort) <-> fp32 helpers. Load is exact; store is RNE.
__device__ __forceinline__ float b2f(ushort_t u) {
    union { uint_t i; float f; } c; c.i = ((uint_t)u) << 16; return c.f;
}
__device__ __forceinline__ ushort_t f2b(float f) {
    union { float f; uint_t i; } c; c.f = f;
    uint_t u = c.i;
    return (ushort_t)((u + 0x7fffu + ((u >> 16) & 1u)) >> 16);
}
__device__ __forceinline__ uint_t pack2(float a, float b) {
    return (uint_t)f2b(a) | ((uint_t)f2b(b) << 16);
}

// Generic tiled GEMM: C = act(A) @ W(K,N) + bias ; fp32 accumulate.
// AT: float or ushort_t(bf16). CT: float or ushort_t(bf16).
// MODE 0: plain A (row-major M x K, row stride K)
// MODE 1: A is raw pre-BN output; apply relu(a*scale[k]+shift[k]) on load
// MODE 2: concat: k<128 from A, k>=128 from A2 (both row stride 128)
template<int K, int N, int MODE, typename AT, typename CT>
__launch_bounds__(256)
__global__ void gemm_k(const AT* __restrict__ A, const AT* __restrict__ A2,
                       const float* __restrict__ W, const float* __restrict__ bias,
                       const float* __restrict__ scale, const float* __restrict__ shift,
                       CT* __restrict__ C) {
    constexpr int TX = N / 4;        // 32 (N=128) or 16 (N=64)
    constexpr int TY = 256 / TX;     // 8 or 16
    constexpr int RM = TILE_M / TY;  // 8 or 4
    constexpr int RS = (MODE == 2) ? 128 : K;  // A row stride

    __shared__ float As[TILE_M][BK + 1];   // +1 pad breaks pow2 stride
    __shared__ float Ws[BK][N];
    __shared__ float s_scale[MODE == 1 ? K : 1];
    __shared__ float s_shift[MODE == 1 ? K : 1];

    const int tid = threadIdx.x;
    const int tx = tid % TX;
    const int ty = tid / TX;
    const int row0 = blockIdx.x * TILE_M;

    // A staging geometry: 64x32 tile = 2048 elems, 8 per thread, contiguous
    const int arow = tid >> 2;           // 0..63
    const int acol = (tid & 3) * 8;      // 0,8,16,24

    if (MODE == 1) {
        for (int i = tid; i < K; i += 256) { s_scale[i] = scale[i]; s_shift[i] = shift[i]; }
        __syncthreads();
    }

    float acc[RM][4];
    #pragma unroll
    for (int r = 0; r < RM; ++r)
        #pragma unroll
        for (int c = 0; c < 4; ++c) acc[r][c] = 0.f;

    for (int k0 = 0; k0 < K; k0 += BK) {
        // ---- stage A tile: 8 contiguous elements per thread ----
        {
            const int kg0 = k0 + acol;
            const AT* src;
            int col;
            if (MODE == 2) { src = (kg0 < 128) ? A : A2; col = kg0 & 127; }
            else           { src = A;                    col = kg0; }
            float v[8];
            if constexpr (sizeof(AT) == 4) {  // fp32: two float4 loads (32 B)
                const float4* p = (const float4*)&src[(size_t)(row0 + arow) * RS + col];
                float4 x0 = p[0], x1 = p[1];
                v[0] = x0.x; v[1] = x0.y; v[2] = x0.z; v[3] = x0.w;
                v[4] = x1.x; v[5] = x1.y; v[6] = x1.z; v[7] = x1.w;
            } else {                          // bf16: one 16 B load of 8 elems
                uint4 pk = *(const uint4*)&src[(size_t)(row0 + arow) * RS + col];
                v[0] = b2f((ushort_t)(pk.x & 0xffff)); v[1] = b2f((ushort_t)(pk.x >> 16));
                v[2] = b2f((ushort_t)(pk.y & 0xffff)); v[3] = b2f((ushort_t)(pk.y >> 16));
                v[4] = b2f((ushort_t)(pk.z & 0xffff)); v[5] = b2f((ushort_t)(pk.z >> 16));
                v[6] = b2f((ushort_t)(pk.w & 0xffff)); v[7] = b2f((ushort_t)(pk.w >> 16));
            }
            if (MODE == 1) {
                #pragma unroll
                for (int i = 0; i < 8; ++i)
                    v[i] = fmaxf(fmaf(v[i], s_scale[kg0 + i], s_shift[kg0 + i]), 0.f);
            }
            #pragma unroll
            for (int i = 0; i < 8; ++i) As[arow][acol + i] = v[i];
        }
        // ---- stage W tile (32 x N), fp32, coalesced ----
        #pragma unroll
        for (int i = 0; i < (BK * N) / 256; ++i) {
            int e = i * 256 + tid;
            int kk = e / N, n = e % N;
            Ws[kk][n] = W[(size_t)(k0 + kk) * N + n];
        }
        __syncthreads();
        #pragma unroll
        for (int kk = 0; kk < BK; ++kk) {
            float4 wv = *(const float4*)&Ws[kk][tx * 4];
            #pragma unroll
            for (int r = 0; r < RM; ++r) {
                float a = As[ty * RM + r][kk];
                acc[r][0] = fmaf(a, wv.x, acc[r][0]);
                acc[r][1] = fmaf(a, wv.y, acc[r][1]);
                acc[r][2] = fmaf(a, wv.z, acc[r][2]);
                acc[r][3] = fmaf(a, wv.w, acc[r][3]);
            }
        }
        __syncthreads();
    }
    float4 bv = *(const float4*)&bias[tx * 4];
    #pragma unroll
    for (int r = 0; r < RM; ++r) {
        float a0 = acc[r][0] + bv.x, a1 = acc[r][1] + bv.y;
        float a2 = acc[r][2] + bv.z, a3 = acc[r][3] + bv.w;
        size_t off = (size_t)(row0 + ty * RM + r) * N + tx * 4;
        if constexpr (sizeof(CT) == 4) {
            float4 o; o.x = a0; o.y = a1; o.z = a2; o.w = a3;
            *(float4*)&C[off] = o;
        } else {
            uint2 o; o.x = pack2(a0, a1); o.y = pack2(a2, a3);
            *(uint2*)&C[off] = o;
        }
    }
}

// Zero a small fp32 region (replaces hipMemsetAsync for graph-capture safety)
__global__ void zero_k(float* __restrict__ p, int n) {
    int i = blockIdx.x * blockDim.x + threadIdx.x;
    if (i < n) p[i] = 0.f;
}

// Per-column sum / sumsq over bf16 Y (M x 128). 512 blocks x 512 rows each.
// Thread handles a column PAIR (4 B loads). tid = rg*64 + cp.
__global__ __launch_bounds__(256) void stats_k(const ushort_t* __restrict__ Y,
                                               float* __restrict__ gsum,
                                               float* __restrict__ gsq) {
    const int tid = threadIdx.x;
    const int cp = tid & 63;   // column pair 0..63
    const int rg = tid >> 6;   // row group 0..3
    const int rowStart = blockIdx.x * 512;
    float s0 = 0.f, q0 = 0.f, s1 = 0.f, q1 = 0.f;
    for (int i = 0; i < 128; ++i) {
        int row = rowStart + rg + i * 4;
        uint_t u = *(const uint_t*)&Y[(size_t)row * 128 + cp * 2];
        float a = b2f((ushort_t)(u & 0xffff));
        float b = b2f((ushort_t)(u >> 16));
        s0 += a; q0 = fmaf(a, a, q0);
        s1 += b; q1 = fmaf(b, b, q1);
    }
    __shared__ float red[4][64][4];
    red[rg][cp][0] = s0; red[rg][cp][1] = q0; red[rg][cp][2] = s1; red[rg][cp][3] = q1;
    __syncthreads();
    if (tid < 64) {
        float S0 = 0, Q0 = 0, S1 = 0, Q1 = 0;
        #pragma unroll
        for (int r = 0; r < 4; ++r) {
            S0 += red[r][tid][0]; Q0 += red[r][tid][1];
            S1 += red[r][tid][2]; Q1 += red[r][tid][3];
        }
        atomicAdd(&gsum[tid * 2], S0);     atomicAdd(&gsq[tid * 2], Q0);
        atomicAdd(&gsum[tid * 2 + 1], S1); atomicAdd(&gsq[tid * 2 + 1], Q1);
    }
}

// scale = g * rsqrt(var + eps); shift = be - mean*scale   (population var, ddof=0)
__global__ void finalize_k(const float* __restrict__ gsum, const float* __restrict__ gsq,
                           const float* __restrict__ g, const float* __restrict__ be,
                           float* __restrict__ scale, float* __restrict__ shift) {
    const int f = threadIdx.x;  // 128 threads
    const float invM = 1.f / (float)M_ROWS;
    float mean = gsum[f] * invM;
    float var = gsq[f] * invM - mean * mean;
    float sc = g[f] * rsqrtf(var + 1e-5f);
    scale[f] = sc;
    shift[f] = fmaf(-mean, sc, be[f]);
}

// Apply BN+ReLU to raw Y (in place -> X), causal cummax over T=256 -> P.
// Thread per (ba, feature-pair): 4 B coalesced loads/stores.
__global__ __launch_bounds__(256) void cummax_concat_k(ushort_t* __restrict__ Y,
                                                       const float* __restrict__ scale,
                                                       const float* __restrict__ shift,
                                                       ushort_t* __restrict__ P) {
    const int g = blockIdx.x * 256 + threadIdx.x;  // 1024*64 threads
    const int cp = g & 63;
    const size_t base = (size_t)(g >> 6) * 256 * 128 + cp * 2;
    const float sc0 = scale[cp * 2], sh0 = shift[cp * 2];
    const float sc1 = scale[cp * 2 + 1], sh1 = shift[cp * 2 + 1];
    float run0 = 0.f, run1 = 0.f;  // post-relu >= 0
    for (int t = 0; t < 256; ++t) {
        size_t idx = base + (size_t)t * 128;
        uint_t u = *(const uint_t*)&Y[idx];
        float v0 = fmaxf(fmaf(b2f((ushort_t)(u & 0xffff)), sc0, sh0), 0.f);
        float v1 = fmaxf(fmaf(b2f((ushort_t)(u >> 16)), sc1, sh1), 0.f);
        run0 = fmaxf(run0, v0);
        run1 = fmaxf(run1, v1);
        *(uint_t*)&Y[idx] = pack2(v0, v1);   // X in place
        *(uint_t*)&P[idx] = pack2(run0, run1);
    }
}

// Same but pooled-only, fully in place.
__global__ __launch_bounds__(256) void cummax_pool_k(ushort_t* __restrict__ Y,
                                                     const float* __restrict__ scale,
                                                     const float* __restrict__ shift) {
    const int g = blockIdx.x * 256 + threadIdx.x;
    const int cp = g & 63;
    const size_t base = (size_t)(g >> 6) * 256 * 128 + cp * 2;
    const float sc0 = scale[cp * 2], sh0 = shift[cp * 2];
    const float sc1 = scale[cp * 2 + 1], sh1 = shift[cp * 2 + 1];
    float run0 = 0.f, run1 = 0.f;
    for (int t = 0; t < 256; ++t) {
        size_t idx = base + (size_t)t * 128;
        uint_t u = *(const uint_t*)&Y[idx];
        float v0 = fmaxf(fmaf(b2f((ushort_t)(u & 0xffff)), sc0, sh0), 0.f);
        float v1 = fmaxf(fmaf(b2f((ushort_t)(u >> 16)), sc1, sh1), 0.f);
        run0 = fmaxf(run0, v0);
        run1 = fmaxf(run1, v1);
        *(uint_t*)&Y[idx] = pack2(run0, run1);
    }
}

extern "C" void kernel_launch(void* const* d_in, const int* in_sizes, int n_in,
                              void* d_out, int out_size, void* d_ws, size_t ws_size,
                              hipStream_t stream) {
    const float* poly = (const float*)d_in[0];
    const float* W0 = (const float*)d_in[1];
    const float* b0 = (const float*)d_in[2];
    const float* g0 = (const float*)d_in[3];
    const float* be0 = (const float*)d_in[4];
    const float* W1 = (const float*)d_in[5];
    const float* b1 = (const float*)d_in[6];
    const float* g1 = (const float*)d_in[7];
    const float* be1 = (const float*)d_in[8];
    const float* W2 = (const float*)d_in[9];
    const float* b2 = (const float*)d_in[10];
    const float* g2 = (const float*)d_in[11];
    const float* be2 = (const float*)d_in[12];
    const float* W3 = (const float*)d_in[13];
    const float* b3 = (const float*)d_in[14];
    const float* g3 = (const float*)d_in[15];
    const float* be3 = (const float*)d_in[16];
    const float* W4 = (const float*)d_in[17];
    const float* b4 = (const float*)d_in[18];
    float* out = (float*)d_out;

    // Workspace layout: 8 KB fp32 stats | slot0 (M*128 bf16) | slot1 (M*128 bf16)
    // Total: 8192 + 2*67108864 = ~128 MB
    float* st = (float*)d_ws;  // 4 layers x {sum[128], sq[128], scale[128], shift[128]}
    ushort_t* h0 = (ushort_t*)((char*)d_ws + 8192);
    ushort_t* h1 = h0 + (size_t)M_ROWS * 128;

    const int GEMM_GRID = M_ROWS / TILE_M;  // 4096

    // zero the atomic stats accumulators (ws is poisoned before every launch)
    zero_k<<<8, 256, 0, stream>>>(st, 2048);

    // Layer 0: y0 = poly @ W0 + b0  -> h0 (raw bf16)
    gemm_k<32, 128, 0, float, ushort_t><<<GEMM_GRID, 256, 0, stream>>>(
        poly, nullptr, W0, b0, nullptr, nullptr, h0);
    stats_k<<<512, 256, 0, stream>>>(h0, st + 0, st + 128);
    finalize_k<<<1, 128, 0, stream>>>(st + 0, st + 128, g0, be0, st + 256, st + 384);

    // BN+ReLU (X in place in h0) + causal cummax -> P in h1
    cummax_concat_k<<<256, 256, 0, stream>>>(h0, st + 256, st + 384, h1);

    // Layer 1: y1 = [X, P] @ W1 + b1 -> h0 (in place; block reads only own rows)
    gemm_k<256, 128, 2, ushort_t, ushort_t><<<GEMM_GRID, 256, 0, stream>>>(
        h0, h1, W1, b1, nullptr, nullptr, h0);
    stats_k<<<512, 256, 0, stream>>>(h0, st + 512, st + 640);
    finalize_k<<<1, 128, 0, stream>>>(st + 512, st + 640, g1, be1, st + 768, st + 896);

    // Layer 2: y2 = bnrelu1(y1) @ W2 + b2 -> h0 (in place)
    gemm_k<128, 128, 1, ushort_t, ushort_t><<<GEMM_GRID, 256, 0, stream>>>(
        h0, nullptr, W2, b2, st + 768, st + 896, h0);
    stats_k<<<512, 256, 0, stream>>>(h0, st + 1024, st + 1152);
    finalize_k<<<1, 128, 0, stream>>>(st + 1024, st + 1152, g2, be2, st + 1280, st + 1408);

    // BN+ReLU + causal cummax, pooled-only, in place in h0
    cummax_pool_k<<<256, 256, 0, stream>>>(h0, st + 1280, st + 1408);

    // Layer 3: y3 = pooled @ W3 + b3 -> h0 (in place)
    gemm_k<128, 128, 0, ushort_t, ushort_t><<<GEMM_GRID, 256, 0, stream>>>(
        h0, nullptr, W3, b3, nullptr, nullptr, h0);
    stats_k<<<512, 256, 0, stream>>>(h0, st + 1536, st + 1664);
    finalize_k<<<1, 128, 0, stream>>>(st + 1536, st + 1664, g3, be3, st + 1792, st + 1920);

    // Layer 4: out = bnrelu3(y3) @ W4 + b4 -> d_out (fp32)
    gemm_k<128, 64, 1, ushort_t, float><<<GEMM_GRID, 256, 0, stream>>>(
        h0, nullptr, W4, b4, st + 1792, st + 1920, out);
}

// Round 3
// 678.176 us; speedup vs baseline: 1.3359x; 1.3359x over previous
//
#include <hip/hip_runtime.h>

// Problem constants (fixed by setup_inputs)
#define M_ROWS 262144   // B*A*T = 16*64*256
#define TILE_M 64
#define BK 32

typedef unsigned short ushort_t;
typedef unsigned int uint_t;
typedef __attribute__((ext_vector_type(8))) short short8_t;   // 8 bf16 = 4 VGPRs
typedef __attribute__((ext_vector_type(4))) float float4_t;   // MFMA acc

// bf16 (stored as ushort) <-> fp32 helpers. Load is exact; store is RNE.
__device__ __forceinline__ float b2f(ushort_t u) {
    union { uint_t i; float f; } c; c.i = ((uint_t)u) << 16; return c.f;
}
__device__ __forceinline__ ushort_t f2b(float f) {
    union { float f; uint_t i; } c; c.f = f;
    uint_t u = c.i;
    return (ushort_t)((u + 0x7fffu + ((u >> 16) & 1u)) >> 16);
}
__device__ __forceinline__ uint_t pack2(float a, float b) {
    return (uint_t)f2b(a) | ((uint_t)f2b(b) << 16);
}

// ---------------------------------------------------------------------------
// MFMA bf16 GEMM: C = act(A) @ W + bias, fp32 accumulate, optional fused stats.
// A: bf16 (M x K). WT: bf16, TRANSPOSED (N x K). C: bf16 or fp32 (M x N).
// MODE 0: plain A. MODE 1: relu(a*scale[k]+shift[k]) on load. MODE 2: concat
//   (k<128 from A, k>=128 from A2, both row-stride 128).
// STATS: per-column sum/sumsq of (acc+bias) atomically added to gsum/gsq.
// Block: 256 thr = 4 waves in 2x2; wave tile 64 x (N/2); 16x16x32 MFMA.
// In-place safe when C==A: block reads only rows [row0,row0+128) and writes
// them only after all K-loop reads complete.
// ---------------------------------------------------------------------------
template<int K, int N, int MODE, int STATS, typename CT>
__launch_bounds__(256)
__global__ void mfma_gemm_k(const ushort_t* __restrict__ A, const ushort_t* __restrict__ A2,
                            const ushort_t* __restrict__ WT, const float* __restrict__ bias,
                            const float* __restrict__ scale, const float* __restrict__ shift,
                            CT* __restrict__ C, float* __restrict__ gsum, float* __restrict__ gsq) {
    constexpr int BM = 128;
    constexpr int BN = N;            // 128 or 64
    constexpr int WN = BN / 2;       // 64 or 32
    constexpr int MT = 4;            // 4 x 16 = 64 rows per wave
    constexpr int NT = WN / 16;      // 4 or 2
    constexpr int RS = (MODE == 2) ? 128 : K;  // A row stride
    constexpr int LDA = BK + 8;      // 40 elems = 80 B row stride: 2-way bank alias (free)

    __shared__ __attribute__((aligned(16))) ushort_t AsL[BM * LDA];
    __shared__ __attribute__((aligned(16))) ushort_t BsL[BN * LDA];
    __shared__ float s_scale[MODE == 1 ? K : 1];
    __shared__ float s_shift[MODE == 1 ? K : 1];

    const int tid = threadIdx.x;
    const int lane = tid & 63;
    const int wave = tid >> 6;
    const int wm = wave & 1;         // wave row (0/1)
    const int wn = wave >> 1;        // wave col (0/1)
    const int quad = lane >> 4;
    const int l16 = lane & 15;
    const int row0 = blockIdx.x * BM;

    if (MODE == 1) {
        for (int i = tid; i < K; i += 256) { s_scale[i] = scale[i]; s_shift[i] = shift[i]; }
    }
    __syncthreads();

    float4_t acc[MT][NT];
    #pragma unroll
    for (int mt = 0; mt < MT; ++mt)
        #pragma unroll
        for (int nt = 0; nt < NT; ++nt)
            acc[mt][nt] = (float4_t)0.f;

    for (int k0 = 0; k0 < K; k0 += BK) {
        // ---- stage A tile (128 x 32 bf16): 16 B per thread-slot, 2 passes ----
        #pragma unroll
        for (int p = 0; p < 2; ++p) {
            int s = p * 256 + tid;          // 512 slots
            int row = s >> 2;               // 0..127
            int col8 = (s & 3) * 8;         // 0,8,16,24
            int kc = k0 + col8;
            const ushort_t* src = A;
            int cc = kc;
            if (MODE == 2) { src = (kc < 128) ? A : A2; cc = kc & 127; }
            uint4 raw = *(const uint4*)&src[(size_t)(row0 + row) * RS + cc];
            if (MODE == 1) {
                uint_t w[4] = {raw.x, raw.y, raw.z, raw.w};
                #pragma unroll
                for (int h = 0; h < 4; ++h) {
                    int kk = kc + h * 2;
                    float v0 = fmaxf(fmaf(b2f((ushort_t)(w[h] & 0xffff)), s_scale[kk],     s_shift[kk]),     0.f);
                    float v1 = fmaxf(fmaf(b2f((ushort_t)(w[h] >> 16)),    s_scale[kk + 1], s_shift[kk + 1]), 0.f);
                    w[h] = pack2(v0, v1);
                }
                raw.x = w[0]; raw.y = w[1]; raw.z = w[2]; raw.w = w[3];
            }
            *(uint4*)&AsL[row * LDA + col8] = raw;
        }
        // ---- stage B tile (BN x 32 bf16) from WT[N][K] ----
        #pragma unroll
        for (int p = 0; p < BN / 64; ++p) {
            int s = p * 256 + tid;
            int n = s >> 2;
            int col8 = (s & 3) * 8;
            uint4 raw = *(const uint4*)&WT[(size_t)n * K + k0 + col8];
            *(uint4*)&BsL[n * LDA + col8] = raw;
        }
        __syncthreads();

        // ---- fragments: 8 contiguous k per lane (ds_read_b128) ----
        short8_t a[MT], b[NT];
        #pragma unroll
        for (int mt = 0; mt < MT; ++mt)
            a[mt] = *(const short8_t*)&AsL[(wm * 64 + mt * 16 + l16) * LDA + quad * 8];
        #pragma unroll
        for (int nt = 0; nt < NT; ++nt)
            b[nt] = *(const short8_t*)&BsL[(wn * WN + nt * 16 + l16) * LDA + quad * 8];
        #pragma unroll
        for (int mt = 0; mt < MT; ++mt)
            #pragma unroll
            for (int nt = 0; nt < NT; ++nt)
                acc[mt][nt] = __builtin_amdgcn_mfma_f32_16x16x32_bf16(a[mt], b[nt], acc[mt][nt], 0, 0, 0);
        __syncthreads();
    }

    // ---- epilogue: bias, optional stats, store ----
    // C/D layout: col = lane&15, row = quad*4 + reg  [m89-verified]
    #pragma unroll
    for (int nt = 0; nt < NT; ++nt) {
        int col = wn * WN + nt * 16 + l16;
        float bv = bias[col];
        float s = 0.f, q = 0.f;
        #pragma unroll
        for (int mt = 0; mt < MT; ++mt) {
            int rbase = row0 + wm * 64 + mt * 16 + quad * 4;
            #pragma unroll
            for (int r = 0; r < 4; ++r) {
                float v = acc[mt][nt][r] + bv;
                if (STATS) { s += v; q = fmaf(v, v, q); }
                size_t off = (size_t)(rbase + r) * N + col;
                if constexpr (sizeof(CT) == 4) C[off] = v;
                else                           C[off] = (CT)f2b(v);
            }
        }
        if (STATS) {
            s += __shfl_xor(s, 16); q += __shfl_xor(q, 16);
            s += __shfl_xor(s, 32); q += __shfl_xor(q, 32);
            if (lane < 16) { atomicAdd(&gsum[col], s); atomicAdd(&gsq[col], q); }
        }
    }
}

// ---------------------------------------------------------------------------
// fp32 vector GEMM (layer 0 only: K=32, fp32 input, keeps full input precision)
// ---------------------------------------------------------------------------
template<int K, int N>
__launch_bounds__(256)
__global__ void gemm_f32_k(const float* __restrict__ A, const float* __restrict__ W,
                           const float* __restrict__ bias, ushort_t* __restrict__ C) {
    constexpr int TX = N / 4;        // 32
    constexpr int TY = 256 / TX;     // 8
    constexpr int RM = TILE_M / TY;  // 8

    __shared__ float As[TILE_M][BK + 1];
    __shared__ float Ws[BK][N];

    const int tid = threadIdx.x;
    const int tx = tid % TX;
    const int ty = tid / TX;
    const int row0 = blockIdx.x * TILE_M;
    const int arow = tid >> 2;
    const int acol = (tid & 3) * 8;

    float acc[RM][4];
    #pragma unroll
    for (int r = 0; r < RM; ++r)
        #pragma unroll
        for (int c = 0; c < 4; ++c) acc[r][c] = 0.f;

    for (int k0 = 0; k0 < K; k0 += BK) {
        {
            const float4* p = (const float4*)&A[(size_t)(row0 + arow) * K + k0 + acol];
            float4 x0 = p[0], x1 = p[1];
            As[arow][acol + 0] = x0.x; As[arow][acol + 1] = x0.y;
            As[arow][acol + 2] = x0.z; As[arow][acol + 3] = x0.w;
            As[arow][acol + 4] = x1.x; As[arow][acol + 5] = x1.y;
            As[arow][acol + 6] = x1.z; As[arow][acol + 7] = x1.w;
        }
        #pragma unroll
        for (int i = 0; i < (BK * N) / 256; ++i) {
            int e = i * 256 + tid;
            Ws[e / N][e % N] = W[(size_t)(k0 + e / N) * N + e % N];
        }
        __syncthreads();
        #pragma unroll
        for (int kk = 0; kk < BK; ++kk) {
            float4 wv = *(const float4*)&Ws[kk][tx * 4];
            #pragma unroll
            for (int r = 0; r < RM; ++r) {
                float a = As[ty * RM + r][kk];
                acc[r][0] = fmaf(a, wv.x, acc[r][0]);
                acc[r][1] = fmaf(a, wv.y, acc[r][1]);
                acc[r][2] = fmaf(a, wv.z, acc[r][2]);
                acc[r][3] = fmaf(a, wv.w, acc[r][3]);
            }
        }
        __syncthreads();
    }
    float4 bv = *(const float4*)&bias[tx * 4];
    #pragma unroll
    for (int r = 0; r < RM; ++r) {
        size_t off = (size_t)(row0 + ty * RM + r) * N + tx * 4;
        uint2 o;
        o.x = pack2(acc[r][0] + bv.x, acc[r][1] + bv.y);
        o.y = pack2(acc[r][2] + bv.z, acc[r][3] + bv.w);
        *(uint2*)&C[off] = o;
    }
}

// Zero a small fp32 region (graph-capture-safe memset)
__global__ void zero_k(float* __restrict__ p, int n) {
    int i = blockIdx.x * blockDim.x + threadIdx.x;
    if (i < n) p[i] = 0.f;
}

// fp32 W[K][N] -> bf16 WT[N][K] (tiny)
__global__ void transpose_w_k(const float* __restrict__ W, ushort_t* __restrict__ WT,
                              int K, int N) {
    int idx = blockIdx.x * 256 + threadIdx.x;
    if (idx < K * N) {
        int k = idx / N, n = idx % N;
        WT[(size_t)n * K + k] = f2b(W[idx]);
    }
}

// Per-column sum/sumsq over bf16 Y (M x 128) — layer 0 only now.
__global__ __launch_bounds__(256) void stats_k(const ushort_t* __restrict__ Y,
                                               float* __restrict__ gsum,
                                               float* __restrict__ gsq) {
    const int tid = threadIdx.x;
    const int cp = tid & 63;
    const int rg = tid >> 6;
    const int rowStart = blockIdx.x * 512;
    float s0 = 0.f, q0 = 0.f, s1 = 0.f, q1 = 0.f;
    for (int i = 0; i < 128; ++i) {
        int row = rowStart + rg + i * 4;
        uint_t u = *(const uint_t*)&Y[(size_t)row * 128 + cp * 2];
        float a = b2f((ushort_t)(u & 0xffff));
        float b = b2f((ushort_t)(u >> 16));
        s0 += a; q0 = fmaf(a, a, q0);
        s1 += b; q1 = fmaf(b, b, q1);
    }
    __shared__ float red[4][64][4];
    red[rg][cp][0] = s0; red[rg][cp][1] = q0; red[rg][cp][2] = s1; red[rg][cp][3] = q1;
    __syncthreads();
    if (tid < 64) {
        float S0 = 0, Q0 = 0, S1 = 0, Q1 = 0;
        #pragma unroll
        for (int r = 0; r < 4; ++r) {
            S0 += red[r][tid][0]; Q0 += red[r][tid][1];
            S1 += red[r][tid][2]; Q1 += red[r][tid][3];
        }
        atomicAdd(&gsum[tid * 2], S0);     atomicAdd(&gsq[tid * 2], Q0);
        atomicAdd(&gsum[tid * 2 + 1], S1); atomicAdd(&gsq[tid * 2 + 1], Q1);
    }
}

// scale = g * rsqrt(var + eps); shift = be - mean*scale  (population var)
__global__ void finalize_k(const float* __restrict__ gsum, const float* __restrict__ gsq,
                           const float* __restrict__ g, const float* __restrict__ be,
                           float* __restrict__ scale, float* __restrict__ shift) {
    const int f = threadIdx.x;  // 128
    const float invM = 1.f / (float)M_ROWS;
    float mean = gsum[f] * invM;
    float var = gsq[f] * invM - mean * mean;
    float sc = g[f] * rsqrtf(var + 1e-5f);
    scale[f] = sc;
    shift[f] = fmaf(-mean, sc, be[f]);
}

// BN+ReLU in place (Y->X) + causal cummax -> P. 4 B coalesced per thread per t.
__global__ __launch_bounds__(256) void cummax_concat_k(ushort_t* __restrict__ Y,
                                                       const float* __restrict__ scale,
                                                       const float* __restrict__ shift,
                                                       ushort_t* __restrict__ P) {
    const int g = blockIdx.x * 256 + threadIdx.x;  // 1024*64 threads
    const int cp = g & 63;
    const size_t base = (size_t)(g >> 6) * 256 * 128 + cp * 2;
    const float sc0 = scale[cp * 2], sh0 = shift[cp * 2];
    const float sc1 = scale[cp * 2 + 1], sh1 = shift[cp * 2 + 1];
    float run0 = 0.f, run1 = 0.f;  // post-relu >= 0
    for (int t = 0; t < 256; ++t) {
        size_t idx = base + (size_t)t * 128;
        uint_t u = *(const uint_t*)&Y[idx];
        float v0 = fmaxf(fmaf(b2f((ushort_t)(u & 0xffff)), sc0, sh0), 0.f);
        float v1 = fmaxf(fmaf(b2f((ushort_t)(u >> 16)), sc1, sh1), 0.f);
        run0 = fmaxf(run0, v0);
        run1 = fmaxf(run1, v1);
        *(uint_t*)&Y[idx] = pack2(v0, v1);
        *(uint_t*)&P[idx] = pack2(run0, run1);
    }
}

// BN+ReLU + causal cummax, pooled-only, fully in place.
__global__ __launch_bounds__(256) void cummax_pool_k(ushort_t* __restrict__ Y,
                                                     const float* __restrict__ scale,
                                                     const float* __restrict__ shift) {
    const int g = blockIdx.x * 256 + threadIdx.x;
    const int cp = g & 63;
    const size_t base = (size_t)(g >> 6) * 256 * 128 + cp * 2;
    const float sc0 = scale[cp * 2], sh0 = shift[cp * 2];
    const float sc1 = scale[cp * 2 + 1], sh1 = shift[cp * 2 + 1];
    float run0 = 0.f, run1 = 0.f;
    for (int t = 0; t < 256; ++t) {
        size_t idx = base + (size_t)t * 128;
        uint_t u = *(const uint_t*)&Y[idx];
        float v0 = fmaxf(fmaf(b2f((ushort_t)(u & 0xffff)), sc0, sh0), 0.f);
        float v1 = fmaxf(fmaf(b2f((ushort_t)(u >> 16)), sc1, sh1), 0.f);
        run0 = fmaxf(run0, v0);
        run1 = fmaxf(run1, v1);
        *(uint_t*)&Y[idx] = pack2(run0, run1);
    }
}

extern "C" void kernel_launch(void* const* d_in, const int* in_sizes, int n_in,
                              void* d_out, int out_size, void* d_ws, size_t ws_size,
                              hipStream_t stream) {
    const float* poly = (const float*)d_in[0];
    const float* W0 = (const float*)d_in[1];
    const float* b0 = (const float*)d_in[2];
    const float* g0 = (const float*)d_in[3];
    const float* be0 = (const float*)d_in[4];
    const float* W1 = (const float*)d_in[5];
    const float* b1 = (const float*)d_in[6];
    const float* g1 = (const float*)d_in[7];
    const float* be1 = (const float*)d_in[8];
    const float* W2 = (const float*)d_in[9];
    const float* b2 = (const float*)d_in[10];
    const float* g2 = (const float*)d_in[11];
    const float* be2 = (const float*)d_in[12];
    const float* W3 = (const float*)d_in[13];
    const float* b3 = (const float*)d_in[14];
    const float* g3 = (const float*)d_in[15];
    const float* be3 = (const float*)d_in[16];
    const float* W4 = (const float*)d_in[17];
    const float* b4 = (const float*)d_in[18];
    float* out = (float*)d_out;

    // Workspace: stats (8 KB) | WT1..WT4 bf16 (144 KB) | h0 | h1 (M*128 bf16 each)
    float* st = (float*)d_ws;
    ushort_t* wt1 = (ushort_t*)((char*)d_ws + 8192);            // 128 x 256
    ushort_t* wt2 = wt1 + 128 * 256;                            // 128 x 128
    ushort_t* wt3 = wt2 + 128 * 128;                            // 128 x 128
    ushort_t* wt4 = wt3 + 128 * 128;                            // 64 x 128
    ushort_t* h0 = (ushort_t*)((char*)d_ws + 8192 + 147456);
    ushort_t* h1 = h0 + (size_t)M_ROWS * 128;

    const int G64 = M_ROWS / TILE_M;   // 4096 (fp32 gemm)
    const int G128 = M_ROWS / 128;     // 2048 (mfma gemm)

    zero_k<<<8, 256, 0, stream>>>(st, 2048);
    transpose_w_k<<<128, 256, 0, stream>>>(W1, wt1, 256, 128);
    transpose_w_k<<<64, 256, 0, stream>>>(W2, wt2, 128, 128);
    transpose_w_k<<<64, 256, 0, stream>>>(W3, wt3, 128, 128);
    transpose_w_k<<<32, 256, 0, stream>>>(W4, wt4, 128, 64);

    // Layer 0 (fp32 precision): y0 = poly @ W0 + b0 -> h0 (raw bf16)
    gemm_f32_k<32, 128><<<G64, 256, 0, stream>>>(poly, W0, b0, h0);
    stats_k<<<512, 256, 0, stream>>>(h0, st + 0, st + 128);
    finalize_k<<<1, 128, 0, stream>>>(st + 0, st + 128, g0, be0, st + 256, st + 384);

    // BN+ReLU (X in place in h0) + causal cummax -> P in h1
    cummax_concat_k<<<256, 256, 0, stream>>>(h0, st + 256, st + 384, h1);

    // Layer 1: y1 = [X,P] @ W1 + b1 -> h0 (in place), fused stats
    mfma_gemm_k<256, 128, 2, 1, ushort_t><<<G128, 256, 0, stream>>>(
        h0, h1, wt1, b1, nullptr, nullptr, h0, st + 512, st + 640);
    finalize_k<<<1, 128, 0, stream>>>(st + 512, st + 640, g1, be1, st + 768, st + 896);

    // Layer 2: y2 = bnrelu1(y1) @ W2 + b2 -> h0 (in place), fused stats
    mfma_gemm_k<128, 128, 1, 1, ushort_t><<<G128, 256, 0, stream>>>(
        h0, nullptr, wt2, b2, st + 768, st + 896, h0, st + 1024, st + 1152);
    finalize_k<<<1, 128, 0, stream>>>(st + 1024, st + 1152, g2, be2, st + 1280, st + 1408);

    // BN+ReLU + causal cummax, pooled-only, in place in h0
    cummax_pool_k<<<256, 256, 0, stream>>>(h0, st + 1280, st + 1408);

    // Layer 3: y3 = pooled @ W3 + b3 -> h0 (in place), fused stats
    mfma_gemm_k<128, 128, 0, 1, ushort_t><<<G128, 256, 0, stream>>>(
        h0, nullptr, wt3, b3, nullptr, nullptr, h0, st + 1536, st + 1664);
    finalize_k<<<1, 128, 0, stream>>>(st + 1536, st + 1664, g3, be3, st + 1792, st + 1920);

    // Layer 4: out = bnrelu3(y3) @ W4 + b4 -> d_out (fp32)
    mfma_gemm_k<128, 64, 1, 0, float><<<G128, 256, 0, stream>>>(
        h0, nullptr, wt4, b4, st + 1792, st + 1920, out, nullptr, nullptr);
}

// Round 4
// 675.781 us; speedup vs baseline: 1.3407x; 1.0035x over previous
//
#include <hip/hip_runtime.h>

// Problem constants (fixed by setup_inputs)
#define M_ROWS 262144   // B*A*T = 16*64*256
#define TILE_M 64
#define BK 32

typedef unsigned short ushort_t;
typedef unsigned int uint_t;
typedef __attribute__((ext_vector_type(8))) short short8_t;   // 8 bf16 = 4 VGPRs
typedef __attribute__((ext_vector_type(4))) float float4_t;   // MFMA acc

// bf16 (stored as ushort) <-> fp32 helpers. Load is exact; store is RNE.
__device__ __forceinline__ float b2f(ushort_t u) {
    union { uint_t i; float f; } c; c.i = ((uint_t)u) << 16; return c.f;
}
__device__ __forceinline__ ushort_t f2b(float f) {
    union { float f; uint_t i; } c; c.f = f;
    uint_t u = c.i;
    return (ushort_t)((u + 0x7fffu + ((u >> 16) & 1u)) >> 16);
}
__device__ __forceinline__ uint_t pack2(float a, float b) {
    return (uint_t)f2b(a) | ((uint_t)f2b(b) << 16);
}

// ---------------------------------------------------------------------------
// MFMA bf16 GEMM: C = act(A) @ W + bias, fp32 accumulate, fused stats.
// A: bf16 (M x K). WT: bf16 TRANSPOSED (N x K). C: bf16 or fp32 (M x N).
// MODE 0: plain A. MODE 1: relu(a*scale[k]+shift[k]) on load. MODE 2: concat.
// Pipeline: register-prefetch of next K-tile overlaps global latency with MFMA.
// Epilogue: LDS transpose (two 64-row halves) -> fully coalesced 16 B stores.
// In-place safe when C==A (block reads only its own 128 rows before writing).
// ---------------------------------------------------------------------------
template<int K, int N, int MODE, int STATS, typename CT>
__launch_bounds__(256)
__global__ void mfma_gemm_k(const ushort_t* __restrict__ A, const ushort_t* __restrict__ A2,
                            const ushort_t* __restrict__ WT, const float* __restrict__ bias,
                            const float* __restrict__ scale, const float* __restrict__ shift,
                            CT* __restrict__ C, float* __restrict__ gsum, float* __restrict__ gsq) {
    constexpr int BM = 128;
    constexpr int BN = N;            // 128 or 64
    constexpr int WN = BN / 2;       // 64 or 32
    constexpr int MT = 4;            // 4 x 16 = 64 rows per wave
    constexpr int NT = WN / 16;      // 4 or 2
    constexpr int RS = (MODE == 2) ? 128 : K;  // A row stride
    constexpr int LDA = BK + 8;      // 40 elems = 80 B row: 16B-aligned, mild aliasing
    constexpr int BPASS = BN / 64;   // B staging slots per thread (2 or 1)
    constexpr int LDC = (sizeof(CT) == 4) ? (BN + 4) : (BN + 8);  // 272B / 144B rows
    constexpr size_t STAGE_B = (size_t)(BM + BN) * LDA * 2;
    constexpr size_t EPI_B = (size_t)64 * LDC * sizeof(CT);
    constexpr size_t SMEM_B = STAGE_B > EPI_B ? STAGE_B : EPI_B;

    __shared__ __attribute__((aligned(16))) char smem[SMEM_B];
    ushort_t* As = (ushort_t*)smem;
    ushort_t* Bs = As + BM * LDA;
    __shared__ float s_scale[MODE == 1 ? K : 1];
    __shared__ float s_shift[MODE == 1 ? K : 1];

    const int tid = threadIdx.x;
    const int lane = tid & 63;
    const int wave = tid >> 6;
    const int wm = wave & 1;         // wave row (0/1)
    const int wn = wave >> 1;        // wave col (0/1)
    const int quad = lane >> 4;
    const int l16 = lane & 15;
    const int row0 = blockIdx.x * BM;

    if (MODE == 1) {
        for (int i = tid; i < K; i += 256) { s_scale[i] = scale[i]; s_shift[i] = shift[i]; }
    }
    __syncthreads();

    // staging geometry (shared by load + LDS-write)
    const int a_row = tid >> 2;          // 0..63 (slot s = p*256+tid -> row = s>>2)
    const int a_col8 = (tid & 3) * 8;    // 0,8,16,24

    float4_t acc[MT][NT];
    #pragma unroll
    for (int mt = 0; mt < MT; ++mt)
        #pragma unroll
        for (int nt = 0; nt < NT; ++nt)
            acc[mt][nt] = (float4_t)0.f;

    uint4 pa[2], pb[BPASS];
    auto load_tile = [&](int k0) {
        #pragma unroll
        for (int p = 0; p < 2; ++p) {
            int row = a_row + p * 64;
            int kc = k0 + a_col8;
            const ushort_t* src = A;
            int cc = kc;
            if (MODE == 2) { src = (kc < 128) ? A : A2; cc = kc & 127; }
            pa[p] = *(const uint4*)&src[(size_t)(row0 + row) * RS + cc];
        }
        #pragma unroll
        for (int p = 0; p < BPASS; ++p) {
            int n = a_row + p * 64;
            pb[p] = *(const uint4*)&WT[(size_t)n * K + k0 + a_col8];
        }
    };

    load_tile(0);
    for (int k0 = 0; k0 < K; k0 += BK) {
        // ---- commit prefetched regs to LDS (apply MODE1 act here) ----
        #pragma unroll
        for (int p = 0; p < 2; ++p) {
            uint4 raw = pa[p];
            if (MODE == 1) {
                int kc = k0 + a_col8;
                uint_t w[4] = {raw.x, raw.y, raw.z, raw.w};
                #pragma unroll
                for (int h = 0; h < 4; ++h) {
                    int kk = kc + h * 2;
                    float v0 = fmaxf(fmaf(b2f((ushort_t)(w[h] & 0xffff)), s_scale[kk],     s_shift[kk]),     0.f);
                    float v1 = fmaxf(fmaf(b2f((ushort_t)(w[h] >> 16)),    s_scale[kk + 1], s_shift[kk + 1]), 0.f);
                    w[h] = pack2(v0, v1);
                }
                raw.x = w[0]; raw.y = w[1]; raw.z = w[2]; raw.w = w[3];
            }
            *(uint4*)&As[(a_row + p * 64) * LDA + a_col8] = raw;
        }
        #pragma unroll
        for (int p = 0; p < BPASS; ++p)
            *(uint4*)&Bs[(a_row + p * 64) * LDA + a_col8] = pb[p];
        __syncthreads();

        // ---- prefetch next tile (overlaps with frag reads + MFMA) ----
        if (k0 + BK < K) load_tile(k0 + BK);

        // ---- fragments: 8 contiguous k per lane (ds_read_b128) ----
        short8_t a[MT], b[NT];
        #pragma unroll
        for (int mt = 0; mt < MT; ++mt)
            a[mt] = *(const short8_t*)&As[(wm * 64 + mt * 16 + l16) * LDA + quad * 8];
        #pragma unroll
        for (int nt = 0; nt < NT; ++nt)
            b[nt] = *(const short8_t*)&Bs[(wn * WN + nt * 16 + l16) * LDA + quad * 8];
        #pragma unroll
        for (int mt = 0; mt < MT; ++mt)
            #pragma unroll
            for (int nt = 0; nt < NT; ++nt)
                acc[mt][nt] = __builtin_amdgcn_mfma_f32_16x16x32_bf16(a[mt], b[nt], acc[mt][nt], 0, 0, 0);
        __syncthreads();
    }

    // ---- bias + fused stats (reg level; C/D layout: col=l16, row=quad*4+r) ----
    #pragma unroll
    for (int nt = 0; nt < NT; ++nt) {
        int col = wn * WN + nt * 16 + l16;
        float bv = bias[col];
        float s = 0.f, q = 0.f;
        #pragma unroll
        for (int mt = 0; mt < MT; ++mt) {
            #pragma unroll
            for (int r = 0; r < 4; ++r) {
                float v = acc[mt][nt][r] + bv;
                acc[mt][nt][r] = v;
                if (STATS) { s += v; q = fmaf(v, v, q); }
            }
        }
        if (STATS) {
            s += __shfl_xor(s, 16); q += __shfl_xor(q, 16);
            s += __shfl_xor(s, 32); q += __shfl_xor(q, 32);
            if (lane < 16) { atomicAdd(&gsum[col], s); atomicAdd(&gsq[col], q); }
        }
    }

    // ---- epilogue: LDS transpose in two 64-row halves -> coalesced stores ----
    CT* Ct = (CT*)smem;
    #pragma unroll
    for (int h = 0; h < 2; ++h) {
        if (h) __syncthreads();   // prev half's reads before overwriting
        if (wm == h) {
            #pragma unroll
            for (int nt = 0; nt < NT; ++nt) {
                int col = wn * WN + nt * 16 + l16;
                #pragma unroll
                for (int mt = 0; mt < MT; ++mt) {
                    int rbase = mt * 16 + quad * 4;
                    #pragma unroll
                    for (int r = 0; r < 4; ++r) {
                        float v = acc[mt][nt][r];
                        if constexpr (sizeof(CT) == 4) Ct[(rbase + r) * LDC + col] = v;
                        else                           Ct[(rbase + r) * LDC + col] = (CT)f2b(v);
                    }
                }
            }
        }
        __syncthreads();
        if constexpr (sizeof(CT) == 2) {
            constexpr int CPT = BN / 8;     // 8-elem col groups per row
            #pragma unroll
            for (int p = 0; p < (64 * CPT) / 256; ++p) {
                int s = p * 256 + tid;
                int row = s / CPT, col8 = (s % CPT) * 8;
                uint4 v = *(const uint4*)&((const ushort_t*)smem)[row * LDC + col8];
                *(uint4*)&C[(size_t)(row0 + h * 64 + row) * N + col8] = v;
            }
        } else {
            constexpr int CPT = BN / 4;     // 4-elem col groups per row
            #pragma unroll
            for (int p = 0; p < (64 * CPT) / 256; ++p) {
                int s = p * 256 + tid;
                int row = s / CPT, col4 = (s % CPT) * 4;
                float4 v = *(const float4*)&((const float*)smem)[row * LDC + col4];
                *(float4*)&C[(size_t)(row0 + h * 64 + row) * N + col4] = v;
            }
        }
    }
}

// ---------------------------------------------------------------------------
// fp32 vector GEMM (layer 0 only: K=32, fp32 input, keeps full input precision)
// ---------------------------------------------------------------------------
template<int K, int N>
__launch_bounds__(256)
__global__ void gemm_f32_k(const float* __restrict__ A, const float* __restrict__ W,
                           const float* __restrict__ bias, ushort_t* __restrict__ C) {
    constexpr int TX = N / 4;        // 32
    constexpr int TY = 256 / TX;     // 8
    constexpr int RM = TILE_M / TY;  // 8

    __shared__ float As[TILE_M][BK + 1];
    __shared__ float Ws[BK][N];

    const int tid = threadIdx.x;
    const int tx = tid % TX;
    const int ty = tid / TX;
    const int row0 = blockIdx.x * TILE_M;
    const int arow = tid >> 2;
    const int acol = (tid & 3) * 8;

    float acc[RM][4];
    #pragma unroll
    for (int r = 0; r < RM; ++r)
        #pragma unroll
        for (int c = 0; c < 4; ++c) acc[r][c] = 0.f;

    for (int k0 = 0; k0 < K; k0 += BK) {
        {
            const float4* p = (const float4*)&A[(size_t)(row0 + arow) * K + k0 + acol];
            float4 x0 = p[0], x1 = p[1];
            As[arow][acol + 0] = x0.x; As[arow][acol + 1] = x0.y;
            As[arow][acol + 2] = x0.z; As[arow][acol + 3] = x0.w;
            As[arow][acol + 4] = x1.x; As[arow][acol + 5] = x1.y;
            As[arow][acol + 6] = x1.z; As[arow][acol + 7] = x1.w;
        }
        #pragma unroll
        for (int i = 0; i < (BK * N) / 256; ++i) {
            int e = i * 256 + tid;
            Ws[e / N][e % N] = W[(size_t)(k0 + e / N) * N + e % N];
        }
        __syncthreads();
        #pragma unroll
        for (int kk = 0; kk < BK; ++kk) {
            float4 wv = *(const float4*)&Ws[kk][tx * 4];
            #pragma unroll
            for (int r = 0; r < RM; ++r) {
                float a = As[ty * RM + r][kk];
                acc[r][0] = fmaf(a, wv.x, acc[r][0]);
                acc[r][1] = fmaf(a, wv.y, acc[r][1]);
                acc[r][2] = fmaf(a, wv.z, acc[r][2]);
                acc[r][3] = fmaf(a, wv.w, acc[r][3]);
            }
        }
        __syncthreads();
    }
    float4 bv = *(const float4*)&bias[tx * 4];
    #pragma unroll
    for (int r = 0; r < RM; ++r) {
        size_t off = (size_t)(row0 + ty * RM + r) * N + tx * 4;
        uint2 o;
        o.x = pack2(acc[r][0] + bv.x, acc[r][1] + bv.y);
        o.y = pack2(acc[r][2] + bv.z, acc[r][3] + bv.w);
        *(uint2*)&C[off] = o;
    }
}

// Zero a small fp32 region (graph-capture-safe memset)
__global__ void zero_k(float* __restrict__ p, int n) {
    int i = blockIdx.x * blockDim.x + threadIdx.x;
    if (i < n) p[i] = 0.f;
}

// fp32 W[K][N] -> bf16 WT[N][K] (tiny)
__global__ void transpose_w_k(const float* __restrict__ W, ushort_t* __restrict__ WT,
                              int K, int N) {
    int idx = blockIdx.x * 256 + threadIdx.x;
    if (idx < K * N) {
        int k = idx / N, n = idx % N;
        WT[(size_t)n * K + k] = f2b(W[idx]);
    }
}

// Per-column sum/sumsq over bf16 Y (M x 128) — layer 0 only.
__global__ __launch_bounds__(256) void stats_k(const ushort_t* __restrict__ Y,
                                               float* __restrict__ gsum,
                                               float* __restrict__ gsq) {
    const int tid = threadIdx.x;
    const int cp = tid & 63;
    const int rg = tid >> 6;
    const int rowStart = blockIdx.x * 512;
    float s0 = 0.f, q0 = 0.f, s1 = 0.f, q1 = 0.f;
    for (int i = 0; i < 128; ++i) {
        int row = rowStart + rg + i * 4;
        uint_t u = *(const uint_t*)&Y[(size_t)row * 128 + cp * 2];
        float a = b2f((ushort_t)(u & 0xffff));
        float b = b2f((ushort_t)(u >> 16));
        s0 += a; q0 = fmaf(a, a, q0);
        s1 += b; q1 = fmaf(b, b, q1);
    }
    __shared__ float red[4][64][4];
    red[rg][cp][0] = s0; red[rg][cp][1] = q0; red[rg][cp][2] = s1; red[rg][cp][3] = q1;
    __syncthreads();
    if (tid < 64) {
        float S0 = 0, Q0 = 0, S1 = 0, Q1 = 0;
        #pragma unroll
        for (int r = 0; r < 4; ++r) {
            S0 += red[r][tid][0]; Q0 += red[r][tid][1];
            S1 += red[r][tid][2]; Q1 += red[r][tid][3];
        }
        atomicAdd(&gsum[tid * 2], S0);     atomicAdd(&gsq[tid * 2], Q0);
        atomicAdd(&gsum[tid * 2 + 1], S1); atomicAdd(&gsq[tid * 2 + 1], Q1);
    }
}

// scale = g * rsqrt(var + eps); shift = be - mean*scale  (population var)
__global__ void finalize_k(const float* __restrict__ gsum, const float* __restrict__ gsq,
                           const float* __restrict__ g, const float* __restrict__ be,
                           float* __restrict__ scale, float* __restrict__ shift) {
    const int f = threadIdx.x;  // 128
    const float invM = 1.f / (float)M_ROWS;
    float mean = gsum[f] * invM;
    float var = gsq[f] * invM - mean * mean;
    float sc = g[f] * rsqrtf(var + 1e-5f);
    scale[f] = sc;
    shift[f] = fmaf(-mean, sc, be[f]);
}

// BN+ReLU in place (Y->X) + causal cummax -> P. 4 B coalesced per thread per t.
__global__ __launch_bounds__(256) void cummax_concat_k(ushort_t* __restrict__ Y,
                                                       const float* __restrict__ scale,
                                                       const float* __restrict__ shift,
                                                       ushort_t* __restrict__ P) {
    const int g = blockIdx.x * 256 + threadIdx.x;  // 1024*64 threads
    const int cp = g & 63;
    const size_t base = (size_t)(g >> 6) * 256 * 128 + cp * 2;
    const float sc0 = scale[cp * 2], sh0 = shift[cp * 2];
    const float sc1 = scale[cp * 2 + 1], sh1 = shift[cp * 2 + 1];
    float run0 = 0.f, run1 = 0.f;  // post-relu >= 0
    for (int t = 0; t < 256; ++t) {
        size_t idx = base + (size_t)t * 128;
        uint_t u = *(const uint_t*)&Y[idx];
        float v0 = fmaxf(fmaf(b2f((ushort_t)(u & 0xffff)), sc0, sh0), 0.f);
        float v1 = fmaxf(fmaf(b2f((ushort_t)(u >> 16)), sc1, sh1), 0.f);
        run0 = fmaxf(run0, v0);
        run1 = fmaxf(run1, v1);
        *(uint_t*)&Y[idx] = pack2(v0, v1);
        *(uint_t*)&P[idx] = pack2(run0, run1);
    }
}

// BN+ReLU + causal cummax, pooled-only, fully in place.
__global__ __launch_bounds__(256) void cummax_pool_k(ushort_t* __restrict__ Y,
                                                     const float* __restrict__ scale,
                                                     const float* __restrict__ shift) {
    const int g = blockIdx.x * 256 + threadIdx.x;
    const int cp = g & 63;
    const size_t base = (size_t)(g >> 6) * 256 * 128 + cp * 2;
    const float sc0 = scale[cp * 2], sh0 = shift[cp * 2];
    const float sc1 = scale[cp * 2 + 1], sh1 = shift[cp * 2 + 1];
    float run0 = 0.f, run1 = 0.f;
    for (int t = 0; t < 256; ++t) {
        size_t idx = base + (size_t)t * 128;
        uint_t u = *(const uint_t*)&Y[idx];
        float v0 = fmaxf(fmaf(b2f((ushort_t)(u & 0xffff)), sc0, sh0), 0.f);
        float v1 = fmaxf(fmaf(b2f((ushort_t)(u >> 16)), sc1, sh1), 0.f);
        run0 = fmaxf(run0, v0);
        run1 = fmaxf(run1, v1);
        *(uint_t*)&Y[idx] = pack2(run0, run1);
    }
}

extern "C" void kernel_launch(void* const* d_in, const int* in_sizes, int n_in,
                              void* d_out, int out_size, void* d_ws, size_t ws_size,
                              hipStream_t stream) {
    const float* poly = (const float*)d_in[0];
    const float* W0 = (const float*)d_in[1];
    const float* b0 = (const float*)d_in[2];
    const float* g0 = (const float*)d_in[3];
    const float* be0 = (const float*)d_in[4];
    const float* W1 = (const float*)d_in[5];
    const float* b1 = (const float*)d_in[6];
    const float* g1 = (const float*)d_in[7];
    const float* be1 = (const float*)d_in[8];
    const float* W2 = (const float*)d_in[9];
    const float* b2 = (const float*)d_in[10];
    const float* g2 = (const float*)d_in[11];
    const float* be2 = (const float*)d_in[12];
    const float* W3 = (const float*)d_in[13];
    const float* b3 = (const float*)d_in[14];
    const float* g3 = (const float*)d_in[15];
    const float* be3 = (const float*)d_in[16];
    const float* W4 = (const float*)d_in[17];
    const float* b4 = (const float*)d_in[18];
    float* out = (float*)d_out;

    // Workspace: stats (8 KB) | WT1..WT4 bf16 (144 KB) | h0 | h1 (M*128 bf16 each)
    float* st = (float*)d_ws;
    ushort_t* wt1 = (ushort_t*)((char*)d_ws + 8192);            // 128 x 256
    ushort_t* wt2 = wt1 + 128 * 256;                            // 128 x 128
    ushort_t* wt3 = wt2 + 128 * 128;                            // 128 x 128
    ushort_t* wt4 = wt3 + 128 * 128;                            // 64 x 128
    ushort_t* h0 = (ushort_t*)((char*)d_ws + 8192 + 147456);
    ushort_t* h1 = h0 + (size_t)M_ROWS * 128;

    const int G64 = M_ROWS / TILE_M;   // 4096 (fp32 gemm)
    const int G128 = M_ROWS / 128;     // 2048 (mfma gemm)

    zero_k<<<8, 256, 0, stream>>>(st, 2048);
    transpose_w_k<<<128, 256, 0, stream>>>(W1, wt1, 256, 128);
    transpose_w_k<<<64, 256, 0, stream>>>(W2, wt2, 128, 128);
    transpose_w_k<<<64, 256, 0, stream>>>(W3, wt3, 128, 128);
    transpose_w_k<<<32, 256, 0, stream>>>(W4, wt4, 128, 64);

    // Layer 0 (fp32 precision): y0 = poly @ W0 + b0 -> h0 (raw bf16)
    gemm_f32_k<32, 128><<<G64, 256, 0, stream>>>(poly, W0, b0, h0);
    stats_k<<<512, 256, 0, stream>>>(h0, st + 0, st + 128);
    finalize_k<<<1, 128, 0, stream>>>(st + 0, st + 128, g0, be0, st + 256, st + 384);

    // BN+ReLU (X in place in h0) + causal cummax -> P in h1
    cummax_concat_k<<<256, 256, 0, stream>>>(h0, st + 256, st + 384, h1);

    // Layer 1: y1 = [X,P] @ W1 + b1 -> h0 (in place), fused stats
    mfma_gemm_k<256, 128, 2, 1, ushort_t><<<G128, 256, 0, stream>>>(
        h0, h1, wt1, b1, nullptr, nullptr, h0, st + 512, st + 640);
    finalize_k<<<1, 128, 0, stream>>>(st + 512, st + 640, g1, be1, st + 768, st + 896);

    // Layer 2: y2 = bnrelu1(y1) @ W2 + b2 -> h0 (in place), fused stats
    mfma_gemm_k<128, 128, 1, 1, ushort_t><<<G128, 256, 0, stream>>>(
        h0, nullptr, wt2, b2, st + 768, st + 896, h0, st + 1024, st + 1152);
    finalize_k<<<1, 128, 0, stream>>>(st + 1024, st + 1152, g2, be2, st + 1280, st + 1408);

    // BN+ReLU + causal cummax, pooled-only, in place in h0
    cummax_pool_k<<<256, 256, 0, stream>>>(h0, st + 1280, st + 1408);

    // Layer 3: y3 = pooled @ W3 + b3 -> h0 (in place), fused stats
    mfma_gemm_k<128, 128, 0, 1, ushort_t><<<G128, 256, 0, stream>>>(
        h0, nullptr, wt3, b3, nullptr, nullptr, h0, st + 1536, st + 1664);
    finalize_k<<<1, 128, 0, stream>>>(st + 1536, st + 1664, g3, be3, st + 1792, st + 1920);

    // Layer 4: out = bnrelu3(y3) @ W4 + b4 -> d_out (fp32)
    mfma_gemm_k<128, 64, 1, 0, float><<<G128, 256, 0, stream>>>(
        h0, nullptr, wt4, b4, st + 1792, st + 1920, out, nullptr, nullptr);
}

// Round 5
// 482.360 us; speedup vs baseline: 1.8783x; 1.4010x over previous
//
#include <hip/hip_runtime.h>

// Problem constants (fixed by setup_inputs)
#define M_ROWS 262144   // B*A*T = 16*64*256
#define TILE_M 64
#define BK 32
#define REP 64          // stats accumulator replicas (breaks atomic same-address chains)

typedef unsigned short ushort_t;
typedef unsigned int uint_t;
typedef __attribute__((ext_vector_type(8))) short short8_t;   // 8 bf16 = 4 VGPRs
typedef __attribute__((ext_vector_type(4))) float float4_t;   // MFMA acc

// bf16 (stored as ushort) <-> fp32 helpers. Load is exact; store is RNE.
__device__ __forceinline__ float b2f(ushort_t u) {
    union { uint_t i; float f; } c; c.i = ((uint_t)u) << 16; return c.f;
}
__device__ __forceinline__ ushort_t f2b(float f) {
    union { float f; uint_t i; } c; c.f = f;
    uint_t u = c.i;
    return (ushort_t)((u + 0x7fffu + ((u >> 16) & 1u)) >> 16);
}
__device__ __forceinline__ uint_t pack2(float a, float b) {
    return (uint_t)f2b(a) | ((uint_t)f2b(b) << 16);
}

// ---------------------------------------------------------------------------
// MFMA bf16 GEMM: C = act(A) @ W + bias, fp32 accumulate, fused stats.
// A: bf16 (M x K). WT: bf16 TRANSPOSED (N x K). C: bf16 or fp32 (M x N).
// MODE 0: plain A. MODE 1: relu(a*scale[k]+shift[k]) on load. MODE 2: concat.
// STATS: per-column sum/sumsq -> LDS cross-wave reduce -> 1 atomic per
//        (col, qty) per block into 64-way replicated accumulators
//        sumRep[col*REP + blockIdx%REP] (atomic chain: 2048/64 = 32 deep).
// In-place safe when C==A (block reads only its own 128 rows before writing).
// ---------------------------------------------------------------------------
template<int K, int N, int MODE, int STATS, typename CT>
__launch_bounds__(256)
__global__ void mfma_gemm_k(const ushort_t* __restrict__ A, const ushort_t* __restrict__ A2,
                            const ushort_t* __restrict__ WT, const float* __restrict__ bias,
                            const float* __restrict__ scale, const float* __restrict__ shift,
                            CT* __restrict__ C, float* __restrict__ sumRep, float* __restrict__ sqRep) {
    constexpr int BM = 128;
    constexpr int BN = N;            // 128 or 64
    constexpr int WN = BN / 2;       // 64 or 32
    constexpr int MT = 4;            // 4 x 16 = 64 rows per wave
    constexpr int NT = WN / 16;      // 4 or 2
    constexpr int RS = (MODE == 2) ? 128 : K;  // A row stride
    constexpr int LDA = BK + 8;      // 40 elems = 80 B row: 16B-aligned
    constexpr int BPASS = BN / 64;   // B staging slots per thread (2 or 1)
    constexpr int LDC = (sizeof(CT) == 4) ? (BN + 4) : (BN + 8);
    constexpr size_t STAGE_B = (size_t)(BM + BN) * LDA * 2;
    constexpr size_t EPI_B = (size_t)64 * LDC * sizeof(CT);
    constexpr size_t SMEM_B = STAGE_B > EPI_B ? STAGE_B : EPI_B;

    __shared__ __attribute__((aligned(16))) char smem[SMEM_B];
    ushort_t* As = (ushort_t*)smem;
    ushort_t* Bs = As + BM * LDA;
    __shared__ float s_scale[MODE == 1 ? K : 1];
    __shared__ float s_shift[MODE == 1 ? K : 1];
    __shared__ float sred[STATS ? 4 * BN * 2 : 1];   // [wave][col][{sum,sq}]

    const int tid = threadIdx.x;
    const int lane = tid & 63;
    const int wave = tid >> 6;
    const int wm = wave & 1;         // wave row (0/1)
    const int wn = wave >> 1;        // wave col (0/1)
    const int quad = lane >> 4;
    const int l16 = lane & 15;
    const int row0 = blockIdx.x * BM;

    if (MODE == 1) {
        for (int i = tid; i < K; i += 256) { s_scale[i] = scale[i]; s_shift[i] = shift[i]; }
    }
    __syncthreads();

    // staging geometry (shared by load + LDS-write)
    const int a_row = tid >> 2;          // 0..63
    const int a_col8 = (tid & 3) * 8;    // 0,8,16,24

    float4_t acc[MT][NT];
    #pragma unroll
    for (int mt = 0; mt < MT; ++mt)
        #pragma unroll
        for (int nt = 0; nt < NT; ++nt)
            acc[mt][nt] = (float4_t)0.f;

    uint4 pa[2], pb[BPASS];
    auto load_tile = [&](int k0) {
        #pragma unroll
        for (int p = 0; p < 2; ++p) {
            int row = a_row + p * 64;
            int kc = k0 + a_col8;
            const ushort_t* src = A;
            int cc = kc;
            if (MODE == 2) { src = (kc < 128) ? A : A2; cc = kc & 127; }
            pa[p] = *(const uint4*)&src[(size_t)(row0 + row) * RS + cc];
        }
        #pragma unroll
        for (int p = 0; p < BPASS; ++p) {
            int n = a_row + p * 64;
            pb[p] = *(const uint4*)&WT[(size_t)n * K + k0 + a_col8];
        }
    };

    load_tile(0);
    for (int k0 = 0; k0 < K; k0 += BK) {
        // ---- commit prefetched regs to LDS (apply MODE1 act here) ----
        #pragma unroll
        for (int p = 0; p < 2; ++p) {
            uint4 raw = pa[p];
            if (MODE == 1) {
                int kc = k0 + a_col8;
                uint_t w[4] = {raw.x, raw.y, raw.z, raw.w};
                #pragma unroll
                for (int h = 0; h < 4; ++h) {
                    int kk = kc + h * 2;
                    float v0 = fmaxf(fmaf(b2f((ushort_t)(w[h] & 0xffff)), s_scale[kk],     s_shift[kk]),     0.f);
                    float v1 = fmaxf(fmaf(b2f((ushort_t)(w[h] >> 16)),    s_scale[kk + 1], s_shift[kk + 1]), 0.f);
                    w[h] = pack2(v0, v1);
                }
                raw.x = w[0]; raw.y = w[1]; raw.z = w[2]; raw.w = w[3];
            }
            *(uint4*)&As[(a_row + p * 64) * LDA + a_col8] = raw;
        }
        #pragma unroll
        for (int p = 0; p < BPASS; ++p)
            *(uint4*)&Bs[(a_row + p * 64) * LDA + a_col8] = pb[p];
        __syncthreads();

        // ---- prefetch next tile (overlaps with frag reads + MFMA) ----
        if (k0 + BK < K) load_tile(k0 + BK);

        // ---- fragments: 8 contiguous k per lane (ds_read_b128) ----
        short8_t a[MT], b[NT];
        #pragma unroll
        for (int mt = 0; mt < MT; ++mt)
            a[mt] = *(const short8_t*)&As[(wm * 64 + mt * 16 + l16) * LDA + quad * 8];
        #pragma unroll
        for (int nt = 0; nt < NT; ++nt)
            b[nt] = *(const short8_t*)&Bs[(wn * WN + nt * 16 + l16) * LDA + quad * 8];
        #pragma unroll
        for (int mt = 0; mt < MT; ++mt)
            #pragma unroll
            for (int nt = 0; nt < NT; ++nt)
                acc[mt][nt] = __builtin_amdgcn_mfma_f32_16x16x32_bf16(a[mt], b[nt], acc[mt][nt], 0, 0, 0);
        __syncthreads();
    }

    // ---- bias + per-wave stats partials (C/D layout: col=l16, row=quad*4+r) ----
    #pragma unroll
    for (int nt = 0; nt < NT; ++nt) {
        int col = wn * WN + nt * 16 + l16;
        float bv = bias[col];
        float s = 0.f, q = 0.f;
        #pragma unroll
        for (int mt = 0; mt < MT; ++mt) {
            #pragma unroll
            for (int r = 0; r < 4; ++r) {
                float v = acc[mt][nt][r] + bv;
                acc[mt][nt][r] = v;
                if (STATS) { s += v; q = fmaf(v, v, q); }
            }
        }
        if (STATS) {
            s += __shfl_xor(s, 16); q += __shfl_xor(q, 16);
            s += __shfl_xor(s, 32); q += __shfl_xor(q, 32);
            if (lane < 16) {
                sred[(wave * BN + col) * 2 + 0] = s;
                sred[(wave * BN + col) * 2 + 1] = q;
            }
        }
    }

    // ---- epilogue: LDS transpose halves -> coalesced stores; stats flush ----
    CT* Ct = (CT*)smem;
    #pragma unroll
    for (int h = 0; h < 2; ++h) {
        if (h) __syncthreads();   // prev half's reads before overwriting
        if (wm == h) {
            #pragma unroll
            for (int nt = 0; nt < NT; ++nt) {
                int col = wn * WN + nt * 16 + l16;
                #pragma unroll
                for (int mt = 0; mt < MT; ++mt) {
                    int rbase = mt * 16 + quad * 4;
                    #pragma unroll
                    for (int r = 0; r < 4; ++r) {
                        float v = acc[mt][nt][r];
                        if constexpr (sizeof(CT) == 4) Ct[(rbase + r) * LDC + col] = v;
                        else                           Ct[(rbase + r) * LDC + col] = (CT)f2b(v);
                    }
                }
            }
        }
        __syncthreads();
        if (STATS && h == 0 && tid < BN * 2) {
            // one atomic per (col, qty) per block, into replica blockIdx%REP
            int col = tid >> 1, qs = tid & 1;
            float v = sred[(0 * BN + col) * 2 + qs] + sred[(1 * BN + col) * 2 + qs]
                    + sred[(2 * BN + col) * 2 + qs] + sred[(3 * BN + col) * 2 + qs];
            float* dst = qs ? sqRep : sumRep;
            atomicAdd(&dst[col * REP + (blockIdx.x & (REP - 1))], v);
        }
        if constexpr (sizeof(CT) == 2) {
            constexpr int CPT = BN / 8;
            #pragma unroll
            for (int p = 0; p < (64 * CPT) / 256; ++p) {
                int s = p * 256 + tid;
                int row = s / CPT, col8 = (s % CPT) * 8;
                uint4 v = *(const uint4*)&((const ushort_t*)smem)[row * LDC + col8];
                *(uint4*)&C[(size_t)(row0 + h * 64 + row) * N + col8] = v;
            }
        } else {
            constexpr int CPT = BN / 4;
            #pragma unroll
            for (int p = 0; p < (64 * CPT) / 256; ++p) {
                int s = p * 256 + tid;
                int row = s / CPT, col4 = (s % CPT) * 4;
                float4 v = *(const float4*)&((const float*)smem)[row * LDC + col4];
                *(float4*)&C[(size_t)(row0 + h * 64 + row) * N + col4] = v;
            }
        }
    }
}

// ---------------------------------------------------------------------------
// fp32 vector GEMM (layer 0 only: K=32, fp32 input, keeps full input precision)
// ---------------------------------------------------------------------------
template<int K, int N>
__launch_bounds__(256)
__global__ void gemm_f32_k(const float* __restrict__ A, const float* __restrict__ W,
                           const float* __restrict__ bias, ushort_t* __restrict__ C) {
    constexpr int TX = N / 4;        // 32
    constexpr int TY = 256 / TX;     // 8
    constexpr int RM = TILE_M / TY;  // 8

    __shared__ float As[TILE_M][BK + 1];
    __shared__ float Ws[BK][N];

    const int tid = threadIdx.x;
    const int tx = tid % TX;
    const int ty = tid / TX;
    const int row0 = blockIdx.x * TILE_M;
    const int arow = tid >> 2;
    const int acol = (tid & 3) * 8;

    float acc[RM][4];
    #pragma unroll
    for (int r = 0; r < RM; ++r)
        #pragma unroll
        for (int c = 0; c < 4; ++c) acc[r][c] = 0.f;

    for (int k0 = 0; k0 < K; k0 += BK) {
        {
            const float4* p = (const float4*)&A[(size_t)(row0 + arow) * K + k0 + acol];
            float4 x0 = p[0], x1 = p[1];
            As[arow][acol + 0] = x0.x; As[arow][acol + 1] = x0.y;
            As[arow][acol + 2] = x0.z; As[arow][acol + 3] = x0.w;
            As[arow][acol + 4] = x1.x; As[arow][acol + 5] = x1.y;
            As[arow][acol + 6] = x1.z; As[arow][acol + 7] = x1.w;
        }
        #pragma unroll
        for (int i = 0; i < (BK * N) / 256; ++i) {
            int e = i * 256 + tid;
            Ws[e / N][e % N] = W[(size_t)(k0 + e / N) * N + e % N];
        }
        __syncthreads();
        #pragma unroll
        for (int kk = 0; kk < BK; ++kk) {
            float4 wv = *(const float4*)&Ws[kk][tx * 4];
            #pragma unroll
            for (int r = 0; r < RM; ++r) {
                float a = As[ty * RM + r][kk];
                acc[r][0] = fmaf(a, wv.x, acc[r][0]);
                acc[r][1] = fmaf(a, wv.y, acc[r][1]);
                acc[r][2] = fmaf(a, wv.z, acc[r][2]);
                acc[r][3] = fmaf(a, wv.w, acc[r][3]);
            }
        }
        __syncthreads();
    }
    float4 bv = *(const float4*)&bias[tx * 4];
    #pragma unroll
    for (int r = 0; r < RM; ++r) {
        size_t off = (size_t)(row0 + ty * RM + r) * N + tx * 4;
        uint2 o;
        o.x = pack2(acc[r][0] + bv.x, acc[r][1] + bv.y);
        o.y = pack2(acc[r][2] + bv.z, acc[r][3] + bv.w);
        *(uint2*)&C[off] = o;
    }
}

// Zero a small fp32 region (graph-capture-safe memset)
__global__ void zero_k(float* __restrict__ p, int n) {
    int i = blockIdx.x * blockDim.x + threadIdx.x;
    if (i < n) p[i] = 0.f;
}

// fp32 W[K][N] -> bf16 WT[N][K] (tiny)
__global__ void transpose_w_k(const float* __restrict__ W, ushort_t* __restrict__ WT,
                              int K, int N) {
    int idx = blockIdx.x * 256 + threadIdx.x;
    if (idx < K * N) {
        int k = idx / N, n = idx % N;
        WT[(size_t)n * K + k] = f2b(W[idx]);
    }
}

// Per-column sum/sumsq over bf16 Y (M x 128) — layer 0 only. Replicated atomics.
__global__ __launch_bounds__(256) void stats_k(const ushort_t* __restrict__ Y,
                                               float* __restrict__ sumRep,
                                               float* __restrict__ sqRep) {
    const int tid = threadIdx.x;
    const int cp = tid & 63;
    const int rg = tid >> 6;
    const int rowStart = blockIdx.x * 512;
    float s0 = 0.f, q0 = 0.f, s1 = 0.f, q1 = 0.f;
    for (int i = 0; i < 128; ++i) {
        int row = rowStart + rg + i * 4;
        uint_t u = *(const uint_t*)&Y[(size_t)row * 128 + cp * 2];
        float a = b2f((ushort_t)(u & 0xffff));
        float b = b2f((ushort_t)(u >> 16));
        s0 += a; q0 = fmaf(a, a, q0);
        s1 += b; q1 = fmaf(b, b, q1);
    }
    __shared__ float red[4][64][4];
    red[rg][cp][0] = s0; red[rg][cp][1] = q0; red[rg][cp][2] = s1; red[rg][cp][3] = q1;
    __syncthreads();
    if (tid < 64) {
        float S0 = 0, Q0 = 0, S1 = 0, Q1 = 0;
        #pragma unroll
        for (int r = 0; r < 4; ++r) {
            S0 += red[r][tid][0]; Q0 += red[r][tid][1];
            S1 += red[r][tid][2]; Q1 += red[r][tid][3];
        }
        int rep = blockIdx.x & (REP - 1);
        atomicAdd(&sumRep[(tid * 2) * REP + rep], S0);
        atomicAdd(&sqRep[(tid * 2) * REP + rep], Q0);
        atomicAdd(&sumRep[(tid * 2 + 1) * REP + rep], S1);
        atomicAdd(&sqRep[(tid * 2 + 1) * REP + rep], Q1);
    }
}

// Reduce replicas; scale = g*rsqrt(var+eps); shift = be - mean*scale
__global__ void finalize_k(const float* __restrict__ sumRep, const float* __restrict__ sqRep,
                           const float* __restrict__ g, const float* __restrict__ be,
                           float* __restrict__ scale, float* __restrict__ shift) {
    const int f = threadIdx.x;  // 128
    const float4* ps = (const float4*)&sumRep[f * REP];
    const float4* pq = (const float4*)&sqRep[f * REP];
    float s = 0.f, q = 0.f;
    #pragma unroll
    for (int i = 0; i < REP / 4; ++i) {
        float4 a = ps[i]; s += (a.x + a.y) + (a.z + a.w);
        float4 b = pq[i]; q += (b.x + b.y) + (b.z + b.w);
    }
    const float invM = 1.f / (float)M_ROWS;
    float mean = s * invM;
    float var = q * invM - mean * mean;
    float sc = g[f] * rsqrtf(var + 1e-5f);
    scale[f] = sc;
    shift[f] = fmaf(-mean, sc, be[f]);
}

// BN+ReLU in place (Y->X) + causal cummax -> P. 4 B coalesced per thread per t.
__global__ __launch_bounds__(256) void cummax_concat_k(ushort_t* __restrict__ Y,
                                                       const float* __restrict__ scale,
                                                       const float* __restrict__ shift,
                                                       ushort_t* __restrict__ P) {
    const int g = blockIdx.x * 256 + threadIdx.x;  // 1024*64 threads
    const int cp = g & 63;
    const size_t base = (size_t)(g >> 6) * 256 * 128 + cp * 2;
    const float sc0 = scale[cp * 2], sh0 = shift[cp * 2];
    const float sc1 = scale[cp * 2 + 1], sh1 = shift[cp * 2 + 1];
    float run0 = 0.f, run1 = 0.f;  // post-relu >= 0
    for (int t = 0; t < 256; ++t) {
        size_t idx = base + (size_t)t * 128;
        uint_t u = *(const uint_t*)&Y[idx];
        float v0 = fmaxf(fmaf(b2f((ushort_t)(u & 0xffff)), sc0, sh0), 0.f);
        float v1 = fmaxf(fmaf(b2f((ushort_t)(u >> 16)), sc1, sh1), 0.f);
        run0 = fmaxf(run0, v0);
        run1 = fmaxf(run1, v1);
        *(uint_t*)&Y[idx] = pack2(v0, v1);
        *(uint_t*)&P[idx] = pack2(run0, run1);
    }
}

// BN+ReLU + causal cummax, pooled-only, fully in place.
__global__ __launch_bounds__(256) void cummax_pool_k(ushort_t* __restrict__ Y,
                                                     const float* __restrict__ scale,
                                                     const float* __restrict__ shift) {
    const int g = blockIdx.x * 256 + threadIdx.x;
    const int cp = g & 63;
    const size_t base = (size_t)(g >> 6) * 256 * 128 + cp * 2;
    const float sc0 = scale[cp * 2], sh0 = shift[cp * 2];
    const float sc1 = scale[cp * 2 + 1], sh1 = shift[cp * 2 + 1];
    float run0 = 0.f, run1 = 0.f;
    for (int t = 0; t < 256; ++t) {
        size_t idx = base + (size_t)t * 128;
        uint_t u = *(const uint_t*)&Y[idx];
        float v0 = fmaxf(fmaf(b2f((ushort_t)(u & 0xffff)), sc0, sh0), 0.f);
        float v1 = fmaxf(fmaf(b2f((ushort_t)(u >> 16)), sc1, sh1), 0.f);
        run0 = fmaxf(run0, v0);
        run1 = fmaxf(run1, v1);
        *(uint_t*)&Y[idx] = pack2(run0, run1);
    }
}

extern "C" void kernel_launch(void* const* d_in, const int* in_sizes, int n_in,
                              void* d_out, int out_size, void* d_ws, size_t ws_size,
                              hipStream_t stream) {
    const float* poly = (const float*)d_in[0];
    const float* W0 = (const float*)d_in[1];
    const float* b0 = (const float*)d_in[2];
    const float* g0 = (const float*)d_in[3];
    const float* be0 = (const float*)d_in[4];
    const float* W1 = (const float*)d_in[5];
    const float* b1 = (const float*)d_in[6];
    const float* g1 = (const float*)d_in[7];
    const float* be1 = (const float*)d_in[8];
    const float* W2 = (const float*)d_in[9];
    const float* b2 = (const float*)d_in[10];
    const float* g2 = (const float*)d_in[11];
    const float* be2 = (const float*)d_in[12];
    const float* W3 = (const float*)d_in[13];
    const float* b3 = (const float*)d_in[14];
    const float* g3 = (const float*)d_in[15];
    const float* be3 = (const float*)d_in[16];
    const float* W4 = (const float*)d_in[17];
    const float* b4 = (const float*)d_in[18];
    float* out = (float*)d_out;

    // Workspace:
    //   replicated stats: 4 layers x {sumRep[128*REP], sqRep[128*REP]} = 65536 f
    //   scale/shift:      4 layers x 256 f                              = 1024 f
    //   WT1..WT4 bf16 (144 KB) | h0 | h1 (M*128 bf16 each)
    float* st = (float*)d_ws;
    auto sumR = [&](int i) { return st + i * 2 * 128 * REP; };
    auto sqR  = [&](int i) { return st + i * 2 * 128 * REP + 128 * REP; };
    auto scP  = [&](int i) { return st + 65536 + i * 256; };
    auto shP  = [&](int i) { return st + 65536 + i * 256 + 128; };
    ushort_t* wt1 = (ushort_t*)((char*)d_ws + 66560 * 4);       // 128 x 256
    ushort_t* wt2 = wt1 + 128 * 256;                            // 128 x 128
    ushort_t* wt3 = wt2 + 128 * 128;                            // 128 x 128
    ushort_t* wt4 = wt3 + 128 * 128;                            // 64 x 128
    ushort_t* h0 = (ushort_t*)((char*)d_ws + 66560 * 4 + 147456);
    ushort_t* h1 = h0 + (size_t)M_ROWS * 128;

    const int G64 = M_ROWS / TILE_M;   // 4096 (fp32 gemm)
    const int G128 = M_ROWS / 128;     // 2048 (mfma gemm)

    zero_k<<<256, 256, 0, stream>>>(st, 65536);
    transpose_w_k<<<128, 256, 0, stream>>>(W1, wt1, 256, 128);
    transpose_w_k<<<64, 256, 0, stream>>>(W2, wt2, 128, 128);
    transpose_w_k<<<64, 256, 0, stream>>>(W3, wt3, 128, 128);
    transpose_w_k<<<32, 256, 0, stream>>>(W4, wt4, 128, 64);

    // Layer 0 (fp32 precision): y0 = poly @ W0 + b0 -> h0 (raw bf16)
    gemm_f32_k<32, 128><<<G64, 256, 0, stream>>>(poly, W0, b0, h0);
    stats_k<<<512, 256, 0, stream>>>(h0, sumR(0), sqR(0));
    finalize_k<<<1, 128, 0, stream>>>(sumR(0), sqR(0), g0, be0, scP(0), shP(0));

    // BN+ReLU (X in place in h0) + causal cummax -> P in h1
    cummax_concat_k<<<256, 256, 0, stream>>>(h0, scP(0), shP(0), h1);

    // Layer 1: y1 = [X,P] @ W1 + b1 -> h0 (in place), fused stats
    mfma_gemm_k<256, 128, 2, 1, ushort_t><<<G128, 256, 0, stream>>>(
        h0, h1, wt1, b1, nullptr, nullptr, h0, sumR(1), sqR(1));
    finalize_k<<<1, 128, 0, stream>>>(sumR(1), sqR(1), g1, be1, scP(1), shP(1));

    // Layer 2: y2 = bnrelu1(y1) @ W2 + b2 -> h0 (in place), fused stats
    mfma_gemm_k<128, 128, 1, 1, ushort_t><<<G128, 256, 0, stream>>>(
        h0, nullptr, wt2, b2, scP(1), shP(1), h0, sumR(2), sqR(2));
    finalize_k<<<1, 128, 0, stream>>>(sumR(2), sqR(2), g2, be2, scP(2), shP(2));

    // BN+ReLU + causal cummax, pooled-only, in place in h0
    cummax_pool_k<<<256, 256, 0, stream>>>(h0, scP(2), shP(2));

    // Layer 3: y3 = pooled @ W3 + b3 -> h0 (in place), fused stats
    mfma_gemm_k<128, 128, 0, 1, ushort_t><<<G128, 256, 0, stream>>>(
        h0, nullptr, wt3, b3, nullptr, nullptr, h0, sumR(3), sqR(3));
    finalize_k<<<1, 128, 0, stream>>>(sumR(3), sqR(3), g3, be3, scP(3), shP(3));

    // Layer 4: out = bnrelu3(y3) @ W4 + b4 -> d_out (fp32)
    mfma_gemm_k<128, 64, 1, 0, float><<<G128, 256, 0, stream>>>(
        h0, nullptr, wt4, b4, scP(3), shP(3), out, nullptr, nullptr);
}

// Round 6
// 457.032 us; speedup vs baseline: 1.9824x; 1.0554x over previous
//
#include <hip/hip_runtime.h>

// Problem constants (fixed by setup_inputs)
#define M_ROWS 262144   // B*A*T = 16*64*256
#define TILE_M 64
#define BK 32
#define REP 64          // second-level stats partials (matches finalize_k layout)

typedef unsigned short ushort_t;
typedef unsigned int uint_t;
typedef __attribute__((ext_vector_type(8))) short short8_t;   // 8 bf16 = 4 VGPRs
typedef __attribute__((ext_vector_type(4))) float float4_t;   // MFMA acc

// bf16 (stored as ushort) <-> fp32 helpers. Load is exact; store is RNE.
__device__ __forceinline__ float b2f(ushort_t u) {
    union { uint_t i; float f; } c; c.i = ((uint_t)u) << 16; return c.f;
}
__device__ __forceinline__ ushort_t f2b(float f) {
    union { float f; uint_t i; } c; c.f = f;
    uint_t u = c.i;
    return (ushort_t)((u + 0x7fffu + ((u >> 16) & 1u)) >> 16);
}
__device__ __forceinline__ uint_t pack2(float a, float b) {
    return (uint_t)f2b(a) | ((uint_t)f2b(b) << 16);
}

// ---------------------------------------------------------------------------
// MFMA bf16 GEMM: C = act(A) @ W + bias, fp32 accumulate, fused stats partials.
// A: bf16 (M x K). WT: bf16 TRANSPOSED (N x K). C: bf16 or fp32 (M x N).
// MODE 0: plain A. MODE 1: relu(a*scale[k]+shift[k]) on load. MODE 2: concat.
// STATS: per-column sum/sumsq -> LDS cross-wave reduce -> ONE coalesced
//        partial-row store per block (sumP/sqP[blockIdx*128+col]). NO atomics.
// In-place safe when C==A (block reads only its own 128 rows before writing).
// ---------------------------------------------------------------------------
template<int K, int N, int MODE, int STATS, typename CT>
__launch_bounds__(256)
__global__ void mfma_gemm_k(const ushort_t* __restrict__ A, const ushort_t* __restrict__ A2,
                            const ushort_t* __restrict__ WT, const float* __restrict__ bias,
                            const float* __restrict__ scale, const float* __restrict__ shift,
                            CT* __restrict__ C, float* __restrict__ sumP, float* __restrict__ sqP) {
    constexpr int BM = 128;
    constexpr int BN = N;            // 128 or 64
    constexpr int WN = BN / 2;       // 64 or 32
    constexpr int MT = 4;            // 4 x 16 = 64 rows per wave
    constexpr int NT = WN / 16;      // 4 or 2
    constexpr int RS = (MODE == 2) ? 128 : K;  // A row stride
    constexpr int LDA = BK + 8;      // 40 elems = 80 B row: 16B-aligned
    constexpr int BPASS = BN / 64;   // B staging slots per thread (2 or 1)
    constexpr int LDC = (sizeof(CT) == 4) ? (BN + 4) : (BN + 8);
    constexpr size_t STAGE_B = (size_t)(BM + BN) * LDA * 2;
    constexpr size_t EPI_B = (size_t)64 * LDC * sizeof(CT);
    constexpr size_t SMEM_B = STAGE_B > EPI_B ? STAGE_B : EPI_B;

    __shared__ __attribute__((aligned(16))) char smem[SMEM_B];
    ushort_t* As = (ushort_t*)smem;
    ushort_t* Bs = As + BM * LDA;
    __shared__ float s_scale[MODE == 1 ? K : 1];
    __shared__ float s_shift[MODE == 1 ? K : 1];
    __shared__ float sred[STATS ? 4 * BN * 2 : 1];   // [wave][col][{sum,sq}]

    const int tid = threadIdx.x;
    const int lane = tid & 63;
    const int wave = tid >> 6;
    const int wm = wave & 1;         // wave row (0/1)
    const int wn = wave >> 1;        // wave col (0/1)
    const int quad = lane >> 4;
    const int l16 = lane & 15;
    const int row0 = blockIdx.x * BM;

    if (MODE == 1) {
        for (int i = tid; i < K; i += 256) { s_scale[i] = scale[i]; s_shift[i] = shift[i]; }
    }
    __syncthreads();

    // staging geometry (shared by load + LDS-write)
    const int a_row = tid >> 2;          // 0..63
    const int a_col8 = (tid & 3) * 8;    // 0,8,16,24

    float4_t acc[MT][NT];
    #pragma unroll
    for (int mt = 0; mt < MT; ++mt)
        #pragma unroll
        for (int nt = 0; nt < NT; ++nt)
            acc[mt][nt] = (float4_t)0.f;

    uint4 pa[2], pb[BPASS];
    auto load_tile = [&](int k0) {
        #pragma unroll
        for (int p = 0; p < 2; ++p) {
            int row = a_row + p * 64;
            int kc = k0 + a_col8;
            const ushort_t* src = A;
            int cc = kc;
            if (MODE == 2) { src = (kc < 128) ? A : A2; cc = kc & 127; }
            pa[p] = *(const uint4*)&src[(size_t)(row0 + row) * RS + cc];
        }
        #pragma unroll
        for (int p = 0; p < BPASS; ++p) {
            int n = a_row + p * 64;
            pb[p] = *(const uint4*)&WT[(size_t)n * K + k0 + a_col8];
        }
    };

    load_tile(0);
    for (int k0 = 0; k0 < K; k0 += BK) {
        // ---- commit prefetched regs to LDS (apply MODE1 act here) ----
        #pragma unroll
        for (int p = 0; p < 2; ++p) {
            uint4 raw = pa[p];
            if (MODE == 1) {
                int kc = k0 + a_col8;
                uint_t w[4] = {raw.x, raw.y, raw.z, raw.w};
                #pragma unroll
                for (int h = 0; h < 4; ++h) {
                    int kk = kc + h * 2;
                    float v0 = fmaxf(fmaf(b2f((ushort_t)(w[h] & 0xffff)), s_scale[kk],     s_shift[kk]),     0.f);
                    float v1 = fmaxf(fmaf(b2f((ushort_t)(w[h] >> 16)),    s_scale[kk + 1], s_shift[kk + 1]), 0.f);
                    w[h] = pack2(v0, v1);
                }
                raw.x = w[0]; raw.y = w[1]; raw.z = w[2]; raw.w = w[3];
            }
            *(uint4*)&As[(a_row + p * 64) * LDA + a_col8] = raw;
        }
        #pragma unroll
        for (int p = 0; p < BPASS; ++p)
            *(uint4*)&Bs[(a_row + p * 64) * LDA + a_col8] = pb[p];
        __syncthreads();

        // ---- prefetch next tile (overlaps with frag reads + MFMA) ----
        if (k0 + BK < K) load_tile(k0 + BK);

        // ---- fragments: 8 contiguous k per lane (ds_read_b128) ----
        short8_t a[MT], b[NT];
        #pragma unroll
        for (int mt = 0; mt < MT; ++mt)
            a[mt] = *(const short8_t*)&As[(wm * 64 + mt * 16 + l16) * LDA + quad * 8];
        #pragma unroll
        for (int nt = 0; nt < NT; ++nt)
            b[nt] = *(const short8_t*)&Bs[(wn * WN + nt * 16 + l16) * LDA + quad * 8];
        #pragma unroll
        for (int mt = 0; mt < MT; ++mt)
            #pragma unroll
            for (int nt = 0; nt < NT; ++nt)
                acc[mt][nt] = __builtin_amdgcn_mfma_f32_16x16x32_bf16(a[mt], b[nt], acc[mt][nt], 0, 0, 0);
        __syncthreads();
    }

    // ---- bias + per-wave stats partials (C/D layout: col=l16, row=quad*4+r) ----
    #pragma unroll
    for (int nt = 0; nt < NT; ++nt) {
        int col = wn * WN + nt * 16 + l16;
        float bv = bias[col];
        float s = 0.f, q = 0.f;
        #pragma unroll
        for (int mt = 0; mt < MT; ++mt) {
            #pragma unroll
            for (int r = 0; r < 4; ++r) {
                float v = acc[mt][nt][r] + bv;
                acc[mt][nt][r] = v;
                if (STATS) { s += v; q = fmaf(v, v, q); }
            }
        }
        if (STATS) {
            s += __shfl_xor(s, 16); q += __shfl_xor(q, 16);
            s += __shfl_xor(s, 32); q += __shfl_xor(q, 32);
            if (lane < 16) {
                sred[(wave * BN + col) * 2 + 0] = s;
                sred[(wave * BN + col) * 2 + 1] = q;
            }
        }
    }

    // ---- epilogue: LDS transpose halves -> coalesced stores; stats flush ----
    CT* Ct = (CT*)smem;
    #pragma unroll
    for (int h = 0; h < 2; ++h) {
        if (h) __syncthreads();   // prev half's reads before overwriting
        if (wm == h) {
            #pragma unroll
            for (int nt = 0; nt < NT; ++nt) {
                int col = wn * WN + nt * 16 + l16;
                #pragma unroll
                for (int mt = 0; mt < MT; ++mt) {
                    int rbase = mt * 16 + quad * 4;
                    #pragma unroll
                    for (int r = 0; r < 4; ++r) {
                        float v = acc[mt][nt][r];
                        if constexpr (sizeof(CT) == 4) Ct[(rbase + r) * LDC + col] = v;
                        else                           Ct[(rbase + r) * LDC + col] = (CT)f2b(v);
                    }
                }
            }
        }
        __syncthreads();
        if (STATS && h == 0 && tid < BN * 2) {
            // one coalesced partial-row store per block (sum row + sq row)
            int col = tid & (BN - 1), qs = tid / BN;
            int wbase = (col >> 6) * 2;   // the two waves (wm=0,1) owning this col
            float v = sred[((wbase + 0) * BN + col) * 2 + qs]
                    + sred[((wbase + 1) * BN + col) * 2 + qs];
            (qs ? sqP : sumP)[(size_t)blockIdx.x * BN + col] = v;
        }
        if constexpr (sizeof(CT) == 2) {
            constexpr int CPT = BN / 8;
            #pragma unroll
            for (int p = 0; p < (64 * CPT) / 256; ++p) {
                int s = p * 256 + tid;
                int row = s / CPT, col8 = (s % CPT) * 8;
                uint4 v = *(const uint4*)&((const ushort_t*)smem)[row * LDC + col8];
                *(uint4*)&C[(size_t)(row0 + h * 64 + row) * N + col8] = v;
            }
        } else {
            constexpr int CPT = BN / 4;
            #pragma unroll
            for (int p = 0; p < (64 * CPT) / 256; ++p) {
                int s = p * 256 + tid;
                int row = s / CPT, col4 = (s % CPT) * 4;
                float4 v = *(const float4*)&((const float*)smem)[row * LDC + col4];
                *(float4*)&C[(size_t)(row0 + h * 64 + row) * N + col4] = v;
            }
        }
    }
}

// ---------------------------------------------------------------------------
// fp32 vector GEMM (layer 0: K=32, fp32 input) with fused stats partials.
// ---------------------------------------------------------------------------
template<int K, int N>
__launch_bounds__(256)
__global__ void gemm_f32_k(const float* __restrict__ A, const float* __restrict__ W,
                           const float* __restrict__ bias, ushort_t* __restrict__ C,
                           float* __restrict__ sumP, float* __restrict__ sqP) {
    constexpr int TX = N / 4;        // 32
    constexpr int TY = 256 / TX;     // 8
    constexpr int RM = TILE_M / TY;  // 8

    __shared__ float As[TILE_M][BK + 1];
    __shared__ float Ws[BK][N];
    __shared__ float redst[2][TY][N];   // stats partial reduce (8 KB)

    const int tid = threadIdx.x;
    const int tx = tid % TX;
    const int ty = tid / TX;
    const int row0 = blockIdx.x * TILE_M;
    const int arow = tid >> 2;
    const int acol = (tid & 3) * 8;

    float acc[RM][4];
    #pragma unroll
    for (int r = 0; r < RM; ++r)
        #pragma unroll
        for (int c = 0; c < 4; ++c) acc[r][c] = 0.f;

    for (int k0 = 0; k0 < K; k0 += BK) {
        {
            const float4* p = (const float4*)&A[(size_t)(row0 + arow) * K + k0 + acol];
            float4 x0 = p[0], x1 = p[1];
            As[arow][acol + 0] = x0.x; As[arow][acol + 1] = x0.y;
            As[arow][acol + 2] = x0.z; As[arow][acol + 3] = x0.w;
            As[arow][acol + 4] = x1.x; As[arow][acol + 5] = x1.y;
            As[arow][acol + 6] = x1.z; As[arow][acol + 7] = x1.w;
        }
        #pragma unroll
        for (int i = 0; i < (BK * N) / 256; ++i) {
            int e = i * 256 + tid;
            Ws[e / N][e % N] = W[(size_t)(k0 + e / N) * N + e % N];
        }
        __syncthreads();
        #pragma unroll
        for (int kk = 0; kk < BK; ++kk) {
            float4 wv = *(const float4*)&Ws[kk][tx * 4];
            #pragma unroll
            for (int r = 0; r < RM; ++r) {
                float a = As[ty * RM + r][kk];
                acc[r][0] = fmaf(a, wv.x, acc[r][0]);
                acc[r][1] = fmaf(a, wv.y, acc[r][1]);
                acc[r][2] = fmaf(a, wv.z, acc[r][2]);
                acc[r][3] = fmaf(a, wv.w, acc[r][3]);
            }
        }
        __syncthreads();
    }
    float4 bv = *(const float4*)&bias[tx * 4];
    float s[4] = {0, 0, 0, 0}, q[4] = {0, 0, 0, 0};
    #pragma unroll
    for (int r = 0; r < RM; ++r) {
        float o[4];
        o[0] = acc[r][0] + bv.x; o[1] = acc[r][1] + bv.y;
        o[2] = acc[r][2] + bv.z; o[3] = acc[r][3] + bv.w;
        #pragma unroll
        for (int c = 0; c < 4; ++c) { s[c] += o[c]; q[c] = fmaf(o[c], o[c], q[c]); }
        size_t off = (size_t)(row0 + ty * RM + r) * N + tx * 4;
        uint2 ov;
        ov.x = pack2(o[0], o[1]);
        ov.y = pack2(o[2], o[3]);
        *(uint2*)&C[off] = ov;
    }
    #pragma unroll
    for (int c = 0; c < 4; ++c) {
        redst[0][ty][tx * 4 + c] = s[c];
        redst[1][ty][tx * 4 + c] = q[c];
    }
    __syncthreads();
    {
        int col = tid & (N - 1), qs = tid / N;   // 256 threads -> 2 x 128 outputs
        float v = 0.f;
        #pragma unroll
        for (int t = 0; t < TY; ++t) v += redst[qs][t][col];
        (qs ? sqP : sumP)[(size_t)blockIdx.x * N + col] = v;
    }
}

// ---------------------------------------------------------------------------
// Tree-reduce block partials: P[NBLK][128] -> R2[col*64 + chunk] (64 chunks).
// grid: 128 blocks x 256 thr; block b: qs = b&1 (sum/sq), chunk = b>>1.
// ---------------------------------------------------------------------------
template<int NBLK>
__global__ __launch_bounds__(256) void reduce1_k(const float* __restrict__ sumP,
                                                 const float* __restrict__ sqP,
                                                 float* __restrict__ sumR2,
                                                 float* __restrict__ sqR2) {
    constexpr int ROWS = NBLK / 64;
    const int tid = threadIdx.x;
    const int qs = blockIdx.x & 1;
    const int chunk = blockIdx.x >> 1;
    const float* src = qs ? sqP : sumP;
    float* dst = qs ? sqR2 : sumR2;
    const int col = tid & 127;
    const int half = tid >> 7;
    float s = 0.f;
    for (int r = half; r < ROWS; r += 2)
        s += src[(size_t)(chunk * ROWS + r) * 128 + col];
    __shared__ float red[256];
    red[tid] = s;
    __syncthreads();
    if (tid < 128) dst[col * 64 + chunk] = red[tid] + red[tid + 128];
}

// Reduce 64 chunks; scale = g*rsqrt(var+eps); shift = be - mean*scale
__global__ void finalize_k(const float* __restrict__ sumR2, const float* __restrict__ sqR2,
                           const float* __restrict__ g, const float* __restrict__ be,
                           float* __restrict__ scale, float* __restrict__ shift) {
    const int f = threadIdx.x;  // 128
    const float4* ps = (const float4*)&sumR2[f * REP];
    const float4* pq = (const float4*)&sqR2[f * REP];
    float s = 0.f, q = 0.f;
    #pragma unroll
    for (int i = 0; i < REP / 4; ++i) {
        float4 a = ps[i]; s += (a.x + a.y) + (a.z + a.w);
        float4 b = pq[i]; q += (b.x + b.y) + (b.z + b.w);
    }
    const float invM = 1.f / (float)M_ROWS;
    float mean = s * invM;
    float var = q * invM - mean * mean;
    float sc = g[f] * rsqrtf(var + 1e-5f);
    scale[f] = sc;
    shift[f] = fmaf(-mean, sc, be[f]);
}

// fp32 W[K][N] -> bf16 WT[N][K] (tiny)
__global__ void transpose_w_k(const float* __restrict__ W, ushort_t* __restrict__ WT,
                              int K, int N) {
    int idx = blockIdx.x * 256 + threadIdx.x;
    if (idx < K * N) {
        int k = idx / N, n = idx % N;
        WT[(size_t)n * K + k] = f2b(W[idx]);
    }
}

// BN+ReLU in place (Y->X) + causal cummax -> P. 4 B coalesced per thread per t.
__global__ __launch_bounds__(256) void cummax_concat_k(ushort_t* __restrict__ Y,
                                                       const float* __restrict__ scale,
                                                       const float* __restrict__ shift,
                                                       ushort_t* __restrict__ P) {
    const int g = blockIdx.x * 256 + threadIdx.x;  // 1024*64 threads
    const int cp = g & 63;
    const size_t base = (size_t)(g >> 6) * 256 * 128 + cp * 2;
    const float sc0 = scale[cp * 2], sh0 = shift[cp * 2];
    const float sc1 = scale[cp * 2 + 1], sh1 = shift[cp * 2 + 1];
    float run0 = 0.f, run1 = 0.f;  // post-relu >= 0
    for (int t = 0; t < 256; ++t) {
        size_t idx = base + (size_t)t * 128;
        uint_t u = *(const uint_t*)&Y[idx];
        float v0 = fmaxf(fmaf(b2f((ushort_t)(u & 0xffff)), sc0, sh0), 0.f);
        float v1 = fmaxf(fmaf(b2f((ushort_t)(u >> 16)), sc1, sh1), 0.f);
        run0 = fmaxf(run0, v0);
        run1 = fmaxf(run1, v1);
        *(uint_t*)&Y[idx] = pack2(v0, v1);
        *(uint_t*)&P[idx] = pack2(run0, run1);
    }
}

// BN+ReLU + causal cummax, pooled-only, fully in place.
__global__ __launch_bounds__(256) void cummax_pool_k(ushort_t* __restrict__ Y,
                                                     const float* __restrict__ scale,
                                                     const float* __restrict__ shift) {
    const int g = blockIdx.x * 256 + threadIdx.x;
    const int cp = g & 63;
    const size_t base = (size_t)(g >> 6) * 256 * 128 + cp * 2;
    const float sc0 = scale[cp * 2], sh0 = shift[cp * 2];
    const float sc1 = scale[cp * 2 + 1], sh1 = shift[cp * 2 + 1];
    float run0 = 0.f, run1 = 0.f;
    for (int t = 0; t < 256; ++t) {
        size_t idx = base + (size_t)t * 128;
        uint_t u = *(const uint_t*)&Y[idx];
        float v0 = fmaxf(fmaf(b2f((ushort_t)(u & 0xffff)), sc0, sh0), 0.f);
        float v1 = fmaxf(fmaf(b2f((ushort_t)(u >> 16)), sc1, sh1), 0.f);
        run0 = fmaxf(run0, v0);
        run1 = fmaxf(run1, v1);
        *(uint_t*)&Y[idx] = pack2(run0, run1);
    }
}

extern "C" void kernel_launch(void* const* d_in, const int* in_sizes, int n_in,
                              void* d_out, int out_size, void* d_ws, size_t ws_size,
                              hipStream_t stream) {
    const float* poly = (const float*)d_in[0];
    const float* W0 = (const float*)d_in[1];
    const float* b0 = (const float*)d_in[2];
    const float* g0 = (const float*)d_in[3];
    const float* be0 = (const float*)d_in[4];
    const float* W1 = (const float*)d_in[5];
    const float* b1 = (const float*)d_in[6];
    const float* g1 = (const float*)d_in[7];
    const float* be1 = (const float*)d_in[8];
    const float* W2 = (const float*)d_in[9];
    const float* b2 = (const float*)d_in[10];
    const float* g2 = (const float*)d_in[11];
    const float* be2 = (const float*)d_in[12];
    const float* W3 = (const float*)d_in[13];
    const float* b3 = (const float*)d_in[14];
    const float* g3 = (const float*)d_in[15];
    const float* be3 = (const float*)d_in[16];
    const float* W4 = (const float*)d_in[17];
    const float* b4 = (const float*)d_in[18];
    float* out = (float*)d_out;

    // Workspace (floats unless noted):
    //   sumP[4096*128] | sqP[4096*128]          (block partials, reused per layer)
    //   sumR2[128*64]  | sqR2[128*64]           (chunk partials)
    //   scale/shift: 4 layers x 256
    //   WT1..WT4 bf16 (144 KB) | h0 | h1 (M*128 bf16 each)
    float* st = (float*)d_ws;
    float* sumP = st;
    float* sqP = st + 524288;
    float* sumR2 = st + 1048576;
    float* sqR2 = sumR2 + 8192;
    float* scsh = st + 1064960;
    auto scP = [&](int i) { return scsh + i * 256; };
    auto shP = [&](int i) { return scsh + i * 256 + 128; };
    ushort_t* wt1 = (ushort_t*)((char*)d_ws + 4263936);         // 128 x 256
    ushort_t* wt2 = wt1 + 128 * 256;                            // 128 x 128
    ushort_t* wt3 = wt2 + 128 * 128;                            // 128 x 128
    ushort_t* wt4 = wt3 + 128 * 128;                            // 64 x 128
    ushort_t* h0 = (ushort_t*)((char*)d_ws + 4263936 + 147456);
    ushort_t* h1 = h0 + (size_t)M_ROWS * 128;

    const int G64 = M_ROWS / TILE_M;   // 4096 (fp32 gemm)
    const int G128 = M_ROWS / 128;     // 2048 (mfma gemm)

    transpose_w_k<<<128, 256, 0, stream>>>(W1, wt1, 256, 128);
    transpose_w_k<<<64, 256, 0, stream>>>(W2, wt2, 128, 128);
    transpose_w_k<<<64, 256, 0, stream>>>(W3, wt3, 128, 128);
    transpose_w_k<<<32, 256, 0, stream>>>(W4, wt4, 128, 64);

    // Layer 0 (fp32 precision): y0 = poly @ W0 + b0 -> h0 (raw bf16) + partials
    gemm_f32_k<32, 128><<<G64, 256, 0, stream>>>(poly, W0, b0, h0, sumP, sqP);
    reduce1_k<4096><<<128, 256, 0, stream>>>(sumP, sqP, sumR2, sqR2);
    finalize_k<<<1, 128, 0, stream>>>(sumR2, sqR2, g0, be0, scP(0), shP(0));

    // BN+ReLU (X in place in h0) + causal cummax -> P in h1
    cummax_concat_k<<<256, 256, 0, stream>>>(h0, scP(0), shP(0), h1);

    // Layer 1: y1 = [X,P] @ W1 + b1 -> h0 (in place), fused stats partials
    mfma_gemm_k<256, 128, 2, 1, ushort_t><<<G128, 256, 0, stream>>>(
        h0, h1, wt1, b1, nullptr, nullptr, h0, sumP, sqP);
    reduce1_k<2048><<<128, 256, 0, stream>>>(sumP, sqP, sumR2, sqR2);
    finalize_k<<<1, 128, 0, stream>>>(sumR2, sqR2, g1, be1, scP(1), shP(1));

    // Layer 2: y2 = bnrelu1(y1) @ W2 + b2 -> h0 (in place), fused stats partials
    mfma_gemm_k<128, 128, 1, 1, ushort_t><<<G128, 256, 0, stream>>>(
        h0, nullptr, wt2, b2, scP(1), shP(1), h0, sumP, sqP);
    reduce1_k<2048><<<128, 256, 0, stream>>>(sumP, sqP, sumR2, sqR2);
    finalize_k<<<1, 128, 0, stream>>>(sumR2, sqR2, g2, be2, scP(2), shP(2));

    // BN+ReLU + causal cummax, pooled-only, in place in h0
    cummax_pool_k<<<256, 256, 0, stream>>>(h0, scP(2), shP(2));

    // Layer 3: y3 = pooled @ W3 + b3 -> h0 (in place), fused stats partials
    mfma_gemm_k<128, 128, 0, 1, ushort_t><<<G128, 256, 0, stream>>>(
        h0, nullptr, wt3, b3, nullptr, nullptr, h0, sumP, sqP);
    reduce1_k<2048><<<128, 256, 0, stream>>>(sumP, sqP, sumR2, sqR2);
    finalize_k<<<1, 128, 0, stream>>>(sumR2, sqR2, g3, be3, scP(3), shP(3));

    // Layer 4: out = bnrelu3(y3) @ W4 + b4 -> d_out (fp32)
    mfma_gemm_k<128, 64, 1, 0, float><<<G128, 256, 0, stream>>>(
        h0, nullptr, wt4, b4, scP(3), shP(3), out, nullptr, nullptr);
}

// Round 7
// 441.450 us; speedup vs baseline: 2.0523x; 1.0353x over previous
//
#include <hip/hip_runtime.h>

// Problem constants (fixed by setup_inputs)
#define M_ROWS 262144   // B*A*T = 16*64*256
#define TILE_M 64
#define BK 32
#define REP 64          // second-level stats partials (matches finalize_k layout)

typedef unsigned short ushort_t;
typedef unsigned int uint_t;
typedef __attribute__((ext_vector_type(8))) short short8_t;   // 8 bf16 = 4 VGPRs
typedef __attribute__((ext_vector_type(4))) float float4_t;   // MFMA acc

// bf16 (stored as ushort) <-> fp32 helpers. Load is exact; store is RNE.
__device__ __forceinline__ float b2f(ushort_t u) {
    union { uint_t i; float f; } c; c.i = ((uint_t)u) << 16; return c.f;
}
__device__ __forceinline__ ushort_t f2b(float f) {
    union { float f; uint_t i; } c; c.f = f;
    uint_t u = c.i;
    return (ushort_t)((u + 0x7fffu + ((u >> 16) & 1u)) >> 16);
}
__device__ __forceinline__ uint_t pack2(float a, float b) {
    return (uint_t)f2b(a) | ((uint_t)f2b(b) << 16);
}

// async global->LDS DMA, 16 B per lane; data lands at ldsbase + lane*16
__device__ __forceinline__ void gld_lds16(const ushort_t* g, ushort_t* l) {
    __builtin_amdgcn_global_load_lds((const __attribute__((address_space(1))) void*)g,
                                     (__attribute__((address_space(3))) void*)l, 16, 0, 0);
}

// ---------------------------------------------------------------------------
// One-shot-K MFMA GEMM: C = act(A) @ W + bias, fp32 acc, fused stats partials.
// BM=64 rows/block, BK=128 (full K per tile), KT tiles (KT=2 only for layer 1).
// A bf16 (M x K), WT bf16 transposed (N x K), C bf16 or fp32.
// MODE 0: plain A. MODE 1: relu(a*sc[k]+sh[k]) applied to A-fragments in regs.
// MODE 2 (KT=2): tile 0 = A (X), tile 1 = A2 (P), both row-stride 128.
// Staging via global_load_lds w/ source-slot XOR swizzle (slot^row&15) so
// frag ds_read_b128 lands 2 lanes/bank-group (free). One barrier per tile.
// In-place safe when C==A: all staging reads complete before epilogue stores.
// ---------------------------------------------------------------------------
template<int KT, int N, int MODE, int STATS, typename CT>
__launch_bounds__(256)
__global__ void mfma_gemm2_k(const ushort_t* __restrict__ A, const ushort_t* __restrict__ A2,
                             const ushort_t* __restrict__ WT, const float* __restrict__ bias,
                             const float* __restrict__ scale, const float* __restrict__ shift,
                             CT* __restrict__ C, float* __restrict__ sumP, float* __restrict__ sqP) {
    constexpr int NT = N / 16;                 // 8 (N=128) or 4 (N=64)
    constexpr int AELEMS = 64 * 128;           // bf16 elems per A tile
    constexpr int BELEMS = N * 128;
    constexpr int LDC = (sizeof(CT) == 4) ? (N + 4) : (N + 8);  // 16B-aligned rows
    constexpr size_t STAGE_B = (size_t)(AELEMS + BELEMS) * 2;
    constexpr size_t EPI_B = (size_t)64 * LDC * sizeof(CT);
    constexpr size_t SMEM_B = STAGE_B > EPI_B ? STAGE_B : EPI_B;

    __shared__ __attribute__((aligned(16))) char smem[SMEM_B];
    __shared__ float sred[STATS ? 4 * 128 * 2 : 1];   // [wave][col][{sum,sq}]
    __shared__ float s_sc[MODE == 1 ? 128 : 1];
    __shared__ float s_sh[MODE == 1 ? 128 : 1];

    ushort_t* As = (ushort_t*)smem;
    ushort_t* Bs = As + AELEMS;

    const int tid = threadIdx.x;
    const int lane = tid & 63;
    const int wave = tid >> 6;
    const int quad = lane >> 4;
    const int l16 = lane & 15;
    const int row0 = blockIdx.x * 64;
    const int srow = lane >> 4;      // row-in-group for staging
    const int sp16 = lane & 15;      // slot-in-row for staging

    if (MODE == 1 && tid < 128) { s_sc[tid] = scale[tid]; s_sh[tid] = shift[tid]; }

    float4_t acc[NT];
    #pragma unroll
    for (int nt = 0; nt < NT; ++nt) acc[nt] = (float4_t)0.f;

    for (int kt = 0; kt < KT; ++kt) {
        if (kt) __syncthreads();   // prior tile's ds_reads done before overwrite
        // ---- stage A tile (64 rows x 256 B payload): 4 DMA insts per wave ----
        #pragma unroll
        for (int i = 0; i < 4; ++i) {
            int t = i * 4 + wave;          // instruction id: LDS bytes [t*1024, +1024)
            int r = t * 4 + srow;          // tile row 0..63
            int sp = sp16 ^ (r & 15);      // swizzled source slot
            const ushort_t* src;
            if (MODE == 2) src = (kt == 0 ? A : A2) + (size_t)(row0 + r) * 128 + sp * 8;
            else           src = A + (size_t)(row0 + r) * (KT * 128) + kt * 128 + sp * 8;
            gld_lds16(src, As + t * 512);
        }
        // ---- stage B tile (N rows x 256 B): N/16 DMA insts per wave ----
        #pragma unroll
        for (int i = 0; i < N / 16; ++i) {
            int t = i * 4 + wave;
            int r = t * 4 + srow;
            int sp = sp16 ^ (r & 15);
            gld_lds16(WT + (size_t)r * (KT * 128) + kt * 128 + sp * 8, Bs + t * 512);
        }
        __syncthreads();   // drains the DMA (vmcnt) + orders s_sc/s_sh

        // ---- compute: wave owns rows [wave*16, wave*16+16) x all N cols ----
        #pragma unroll
        for (int kk = 0; kk < 4; ++kk) {
            int j = kk * 4 + quad;         // 16B k-slot index
            short8_t af = *(const short8_t*)&As[(wave * 16 + l16) * 128 + ((j ^ l16) * 8)];
            if (MODE == 1) {
                int kb = kk * 32 + quad * 8;
                float4 c0 = *(const float4*)&s_sc[kb], c1 = *(const float4*)&s_sc[kb + 4];
                float4 hh0 = *(const float4*)&s_sh[kb], hh1 = *(const float4*)&s_sh[kb + 4];
                ushort_t u[8];
                *(short8_t*)u = af;
                u[0] = f2b(fmaxf(fmaf(b2f(u[0]), c0.x, hh0.x), 0.f));
                u[1] = f2b(fmaxf(fmaf(b2f(u[1]), c0.y, hh0.y), 0.f));
                u[2] = f2b(fmaxf(fmaf(b2f(u[2]), c0.z, hh0.z), 0.f));
                u[3] = f2b(fmaxf(fmaf(b2f(u[3]), c0.w, hh0.w), 0.f));
                u[4] = f2b(fmaxf(fmaf(b2f(u[4]), c1.x, hh1.x), 0.f));
                u[5] = f2b(fmaxf(fmaf(b2f(u[5]), c1.y, hh1.y), 0.f));
                u[6] = f2b(fmaxf(fmaf(b2f(u[6]), c1.z, hh1.z), 0.f));
                u[7] = f2b(fmaxf(fmaf(b2f(u[7]), c1.w, hh1.w), 0.f));
                af = *(const short8_t*)u;
            }
            #pragma unroll
            for (int nt = 0; nt < NT; ++nt) {
                short8_t bf = *(const short8_t*)&Bs[(nt * 16 + l16) * 128 + ((j ^ l16) * 8)];
                acc[nt] = __builtin_amdgcn_mfma_f32_16x16x32_bf16(af, bf, acc[nt], 0, 0, 0);
            }
        }
    }

    // ---- bias + per-wave stats (C/D layout: col=l16, row=quad*4+r) ----
    #pragma unroll
    for (int nt = 0; nt < NT; ++nt) {
        int col = nt * 16 + l16;
        float bv = bias[col];
        float s = 0.f, q = 0.f;
        #pragma unroll
        for (int r = 0; r < 4; ++r) {
            float v = acc[nt][r] + bv;
            acc[nt][r] = v;
            if (STATS) { s += v; q = fmaf(v, v, q); }
        }
        if (STATS) {
            s += __shfl_xor(s, 16); q += __shfl_xor(q, 16);
            s += __shfl_xor(s, 32); q += __shfl_xor(q, 32);
            if (lane < 16) {
                sred[(wave * 128 + col) * 2 + 0] = s;
                sred[(wave * 128 + col) * 2 + 1] = q;
            }
        }
    }
    __syncthreads();   // staging reads done; sred visible

    // ---- LDS transpose (all 64 rows at once) ----
    CT* Ct = (CT*)smem;
    #pragma unroll
    for (int nt = 0; nt < NT; ++nt) {
        int col = nt * 16 + l16;
        #pragma unroll
        for (int r = 0; r < 4; ++r) {
            int row = wave * 16 + quad * 4 + r;
            if constexpr (sizeof(CT) == 4) Ct[row * LDC + col] = acc[nt][r];
            else                           Ct[row * LDC + col] = (CT)f2b(acc[nt][r]);
        }
    }
    __syncthreads();

    // ---- stats flush: one coalesced partial row per block (no atomics) ----
    if (STATS) {
        int col = tid & 127, qs = tid >> 7;
        float v = sred[(0 * 128 + col) * 2 + qs] + sred[(1 * 128 + col) * 2 + qs]
                + sred[(2 * 128 + col) * 2 + qs] + sred[(3 * 128 + col) * 2 + qs];
        (qs ? sqP : sumP)[(size_t)blockIdx.x * 128 + col] = v;
    }
    // ---- coalesced 16 B stores ----
    if constexpr (sizeof(CT) == 2) {
        constexpr int G = N / 8;
        #pragma unroll
        for (int p = 0; p < (64 * G) / 256; ++p) {
            int s = p * 256 + tid;
            int row = s / G, c8 = (s % G) * 8;
            *(uint4*)&C[(size_t)(row0 + row) * N + c8] =
                *(const uint4*)&((const ushort_t*)smem)[row * LDC + c8];
        }
    } else {
        constexpr int G = N / 4;
        #pragma unroll
        for (int p = 0; p < (64 * G) / 256; ++p) {
            int s = p * 256 + tid;
            int row = s / G, c4 = (s % G) * 4;
            *(float4*)&C[(size_t)(row0 + row) * N + c4] =
                *(const float4*)&((const float*)smem)[row * LDC + c4];
        }
    }
}

// ---------------------------------------------------------------------------
// fp32 vector GEMM (layer 0: K=32, fp32 input) with fused stats partials.
// ---------------------------------------------------------------------------
template<int K, int N>
__launch_bounds__(256)
__global__ void gemm_f32_k(const float* __restrict__ A, const float* __restrict__ W,
                           const float* __restrict__ bias, ushort_t* __restrict__ C,
                           float* __restrict__ sumP, float* __restrict__ sqP) {
    constexpr int TX = N / 4;        // 32
    constexpr int TY = 256 / TX;     // 8
    constexpr int RM = TILE_M / TY;  // 8

    __shared__ float As[TILE_M][BK + 1];
    __shared__ float Ws[BK][N];
    __shared__ float redst[2][TY][N];   // stats partial reduce (8 KB)

    const int tid = threadIdx.x;
    const int tx = tid % TX;
    const int ty = tid / TX;
    const int row0 = blockIdx.x * TILE_M;
    const int arow = tid >> 2;
    const int acol = (tid & 3) * 8;

    float acc[RM][4];
    #pragma unroll
    for (int r = 0; r < RM; ++r)
        #pragma unroll
        for (int c = 0; c < 4; ++c) acc[r][c] = 0.f;

    for (int k0 = 0; k0 < K; k0 += BK) {
        {
            const float4* p = (const float4*)&A[(size_t)(row0 + arow) * K + k0 + acol];
            float4 x0 = p[0], x1 = p[1];
            As[arow][acol + 0] = x0.x; As[arow][acol + 1] = x0.y;
            As[arow][acol + 2] = x0.z; As[arow][acol + 3] = x0.w;
            As[arow][acol + 4] = x1.x; As[arow][acol + 5] = x1.y;
            As[arow][acol + 6] = x1.z; As[arow][acol + 7] = x1.w;
        }
        #pragma unroll
        for (int i = 0; i < (BK * N) / 256; ++i) {
            int e = i * 256 + tid;
            Ws[e / N][e % N] = W[(size_t)(k0 + e / N) * N + e % N];
        }
        __syncthreads();
        #pragma unroll
        for (int kk = 0; kk < BK; ++kk) {
            float4 wv = *(const float4*)&Ws[kk][tx * 4];
            #pragma unroll
            for (int r = 0; r < RM; ++r) {
                float a = As[ty * RM + r][kk];
                acc[r][0] = fmaf(a, wv.x, acc[r][0]);
                acc[r][1] = fmaf(a, wv.y, acc[r][1]);
                acc[r][2] = fmaf(a, wv.z, acc[r][2]);
                acc[r][3] = fmaf(a, wv.w, acc[r][3]);
            }
        }
        __syncthreads();
    }
    float4 bv = *(const float4*)&bias[tx * 4];
    float s[4] = {0, 0, 0, 0}, q[4] = {0, 0, 0, 0};
    #pragma unroll
    for (int r = 0; r < RM; ++r) {
        float o[4];
        o[0] = acc[r][0] + bv.x; o[1] = acc[r][1] + bv.y;
        o[2] = acc[r][2] + bv.z; o[3] = acc[r][3] + bv.w;
        #pragma unroll
        for (int c = 0; c < 4; ++c) { s[c] += o[c]; q[c] = fmaf(o[c], o[c], q[c]); }
        size_t off = (size_t)(row0 + ty * RM + r) * N + tx * 4;
        uint2 ov;
        ov.x = pack2(o[0], o[1]);
        ov.y = pack2(o[2], o[3]);
        *(uint2*)&C[off] = ov;
    }
    #pragma unroll
    for (int c = 0; c < 4; ++c) {
        redst[0][ty][tx * 4 + c] = s[c];
        redst[1][ty][tx * 4 + c] = q[c];
    }
    __syncthreads();
    {
        int col = tid & (N - 1), qs = tid / N;   // 256 threads -> 2 x 128 outputs
        float v = 0.f;
        #pragma unroll
        for (int t = 0; t < TY; ++t) v += redst[qs][t][col];
        (qs ? sqP : sumP)[(size_t)blockIdx.x * N + col] = v;
    }
}

// ---------------------------------------------------------------------------
// Tree-reduce block partials: P[NBLK][128] -> R2[col*64 + chunk] (64 chunks).
// ---------------------------------------------------------------------------
template<int NBLK>
__global__ __launch_bounds__(256) void reduce1_k(const float* __restrict__ sumP,
                                                 const float* __restrict__ sqP,
                                                 float* __restrict__ sumR2,
                                                 float* __restrict__ sqR2) {
    constexpr int ROWS = NBLK / 64;
    const int tid = threadIdx.x;
    const int qs = blockIdx.x & 1;
    const int chunk = blockIdx.x >> 1;
    const float* src = qs ? sqP : sumP;
    float* dst = qs ? sqR2 : sumR2;
    const int col = tid & 127;
    const int half = tid >> 7;
    float s = 0.f;
    for (int r = half; r < ROWS; r += 2)
        s += src[(size_t)(chunk * ROWS + r) * 128 + col];
    __shared__ float red[256];
    red[tid] = s;
    __syncthreads();
    if (tid < 128) dst[col * 64 + chunk] = red[tid] + red[tid + 128];
}

// Reduce 64 chunks; scale = g*rsqrt(var+eps); shift = be - mean*scale
__global__ void finalize_k(const float* __restrict__ sumR2, const float* __restrict__ sqR2,
                           const float* __restrict__ g, const float* __restrict__ be,
                           float* __restrict__ scale, float* __restrict__ shift) {
    const int f = threadIdx.x;  // 128
    const float4* ps = (const float4*)&sumR2[f * REP];
    const float4* pq = (const float4*)&sqR2[f * REP];
    float s = 0.f, q = 0.f;
    #pragma unroll
    for (int i = 0; i < REP / 4; ++i) {
        float4 a = ps[i]; s += (a.x + a.y) + (a.z + a.w);
        float4 b = pq[i]; q += (b.x + b.y) + (b.z + b.w);
    }
    const float invM = 1.f / (float)M_ROWS;
    float mean = s * invM;
    float var = q * invM - mean * mean;
    float sc = g[f] * rsqrtf(var + 1e-5f);
    scale[f] = sc;
    shift[f] = fmaf(-mean, sc, be[f]);
}

// fp32 W[K][N] -> bf16 WT[N][K] (tiny)
__global__ void transpose_w_k(const float* __restrict__ W, ushort_t* __restrict__ WT,
                              int K, int N) {
    int idx = blockIdx.x * 256 + threadIdx.x;
    if (idx < K * N) {
        int k = idx / N, n = idx % N;
        WT[(size_t)n * K + k] = f2b(W[idx]);
    }
}

// BN+ReLU in place (Y->X) + causal cummax -> P. 4 B coalesced per thread per t.
__global__ __launch_bounds__(256) void cummax_concat_k(ushort_t* __restrict__ Y,
                                                       const float* __restrict__ scale,
                                                       const float* __restrict__ shift,
                                                       ushort_t* __restrict__ P) {
    const int g = blockIdx.x * 256 + threadIdx.x;  // 1024*64 threads
    const int cp = g & 63;
    const size_t base = (size_t)(g >> 6) * 256 * 128 + cp * 2;
    const float sc0 = scale[cp * 2], sh0 = shift[cp * 2];
    const float sc1 = scale[cp * 2 + 1], sh1 = shift[cp * 2 + 1];
    float run0 = 0.f, run1 = 0.f;  // post-relu >= 0
    for (int t = 0; t < 256; ++t) {
        size_t idx = base + (size_t)t * 128;
        uint_t u = *(const uint_t*)&Y[idx];
        float v0 = fmaxf(fmaf(b2f((ushort_t)(u & 0xffff)), sc0, sh0), 0.f);
        float v1 = fmaxf(fmaf(b2f((ushort_t)(u >> 16)), sc1, sh1), 0.f);
        run0 = fmaxf(run0, v0);
        run1 = fmaxf(run1, v1);
        *(uint_t*)&Y[idx] = pack2(v0, v1);
        *(uint_t*)&P[idx] = pack2(run0, run1);
    }
}

// BN+ReLU + causal cummax, pooled-only, fully in place.
__global__ __launch_bounds__(256) void cummax_pool_k(ushort_t* __restrict__ Y,
                                                     const float* __restrict__ scale,
                                                     const float* __restrict__ shift) {
    const int g = blockIdx.x * 256 + threadIdx.x;
    const int cp = g & 63;
    const size_t base = (size_t)(g >> 6) * 256 * 128 + cp * 2;
    const float sc0 = scale[cp * 2], sh0 = shift[cp * 2];
    const float sc1 = scale[cp * 2 + 1], sh1 = shift[cp * 2 + 1];
    float run0 = 0.f, run1 = 0.f;
    for (int t = 0; t < 256; ++t) {
        size_t idx = base + (size_t)t * 128;
        uint_t u = *(const uint_t*)&Y[idx];
        float v0 = fmaxf(fmaf(b2f((ushort_t)(u & 0xffff)), sc0, sh0), 0.f);
        float v1 = fmaxf(fmaf(b2f((ushort_t)(u >> 16)), sc1, sh1), 0.f);
        run0 = fmaxf(run0, v0);
        run1 = fmaxf(run1, v1);
        *(uint_t*)&Y[idx] = pack2(run0, run1);
    }
}

extern "C" void kernel_launch(void* const* d_in, const int* in_sizes, int n_in,
                              void* d_out, int out_size, void* d_ws, size_t ws_size,
                              hipStream_t stream) {
    const float* poly = (const float*)d_in[0];
    const float* W0 = (const float*)d_in[1];
    const float* b0 = (const float*)d_in[2];
    const float* g0 = (const float*)d_in[3];
    const float* be0 = (const float*)d_in[4];
    const float* W1 = (const float*)d_in[5];
    const float* b1 = (const float*)d_in[6];
    const float* g1 = (const float*)d_in[7];
    const float* be1 = (const float*)d_in[8];
    const float* W2 = (const float*)d_in[9];
    const float* b2 = (const float*)d_in[10];
    const float* g2 = (const float*)d_in[11];
    const float* be2 = (const float*)d_in[12];
    const float* W3 = (const float*)d_in[13];
    const float* b3 = (const float*)d_in[14];
    const float* g3 = (const float*)d_in[15];
    const float* be3 = (const float*)d_in[16];
    const float* W4 = (const float*)d_in[17];
    const float* b4 = (const float*)d_in[18];
    float* out = (float*)d_out;

    // Workspace (floats unless noted):
    //   sumP[4096*128] | sqP[4096*128] | sumR2[8192] | sqR2[8192] | scale/shift
    //   WT1..WT4 bf16 (144 KB) | h0 | h1 (M*128 bf16 each)
    float* st = (float*)d_ws;
    float* sumP = st;
    float* sqP = st + 524288;
    float* sumR2 = st + 1048576;
    float* sqR2 = sumR2 + 8192;
    float* scsh = st + 1064960;
    auto scP = [&](int i) { return scsh + i * 256; };
    auto shP = [&](int i) { return scsh + i * 256 + 128; };
    ushort_t* wt1 = (ushort_t*)((char*)d_ws + 4263936);         // 128 x 256
    ushort_t* wt2 = wt1 + 128 * 256;                            // 128 x 128
    ushort_t* wt3 = wt2 + 128 * 128;                            // 128 x 128
    ushort_t* wt4 = wt3 + 128 * 128;                            // 64 x 128
    ushort_t* h0 = (ushort_t*)((char*)d_ws + 4263936 + 147456);
    ushort_t* h1 = h0 + (size_t)M_ROWS * 128;

    const int G64 = M_ROWS / TILE_M;   // 4096 blocks (both GEMM flavors now)

    transpose_w_k<<<128, 256, 0, stream>>>(W1, wt1, 256, 128);
    transpose_w_k<<<64, 256, 0, stream>>>(W2, wt2, 128, 128);
    transpose_w_k<<<64, 256, 0, stream>>>(W3, wt3, 128, 128);
    transpose_w_k<<<32, 256, 0, stream>>>(W4, wt4, 128, 64);

    // Layer 0 (fp32 precision): y0 = poly @ W0 + b0 -> h0 (raw bf16) + partials
    gemm_f32_k<32, 128><<<G64, 256, 0, stream>>>(poly, W0, b0, h0, sumP, sqP);
    reduce1_k<4096><<<128, 256, 0, stream>>>(sumP, sqP, sumR2, sqR2);
    finalize_k<<<1, 128, 0, stream>>>(sumR2, sqR2, g0, be0, scP(0), shP(0));

    // BN+ReLU (X in place in h0) + causal cummax -> P in h1
    cummax_concat_k<<<256, 256, 0, stream>>>(h0, scP(0), shP(0), h1);

    // Layer 1: y1 = [X,P] @ W1 + b1 -> h0 (in place), KT=2 (tile0=X, tile1=P)
    mfma_gemm2_k<2, 128, 2, 1, ushort_t><<<G64, 256, 0, stream>>>(
        h0, h1, wt1, b1, nullptr, nullptr, h0, sumP, sqP);
    reduce1_k<4096><<<128, 256, 0, stream>>>(sumP, sqP, sumR2, sqR2);
    finalize_k<<<1, 128, 0, stream>>>(sumR2, sqR2, g1, be1, scP(1), shP(1));

    // Layer 2: y2 = bnrelu1(y1) @ W2 + b2 -> h0 (in place), act-on-frag
    mfma_gemm2_k<1, 128, 1, 1, ushort_t><<<G64, 256, 0, stream>>>(
        h0, nullptr, wt2, b2, scP(1), shP(1), h0, sumP, sqP);
    reduce1_k<4096><<<128, 256, 0, stream>>>(sumP, sqP, sumR2, sqR2);
    finalize_k<<<1, 128, 0, stream>>>(sumR2, sqR2, g2, be2, scP(2), shP(2));

    // BN+ReLU + causal cummax, pooled-only, in place in h0
    cummax_pool_k<<<256, 256, 0, stream>>>(h0, scP(2), shP(2));

    // Layer 3: y3 = pooled @ W3 + b3 -> h0 (in place)
    mfma_gemm2_k<1, 128, 0, 1, ushort_t><<<G64, 256, 0, stream>>>(
        h0, nullptr, wt3, b3, nullptr, nullptr, h0, sumP, sqP);
    reduce1_k<4096><<<128, 256, 0, stream>>>(sumP, sqP, sumR2, sqR2);
    finalize_k<<<1, 128, 0, stream>>>(sumR2, sqR2, g3, be3, scP(3), shP(3));

    // Layer 4: out = bnrelu3(y3) @ W4 + b4 -> d_out (fp32), act-on-frag
    mfma_gemm2_k<1, 64, 1, 0, float><<<G64, 256, 0, stream>>>(
        h0, nullptr, wt4, b4, scP(3), shP(3), out, nullptr, nullptr);
}

// Round 8
// 410.610 us; speedup vs baseline: 2.2065x; 1.0751x over previous
//
#include <hip/hip_runtime.h>

// Problem constants (fixed by setup_inputs)
#define M_ROWS 262144   // B*A*T = 16*64*256
#define TILE_M 64
#define BK 32
#define REP 64          // second-level stats partials (matches finalize_k layout)

typedef unsigned short ushort_t;
typedef unsigned int uint_t;
typedef __attribute__((ext_vector_type(8))) short short8_t;   // 8 bf16 = 4 VGPRs
typedef __attribute__((ext_vector_type(4))) float float4_t;   // MFMA acc

// bf16 (stored as ushort) <-> fp32 helpers. Load is exact; store is RNE.
__device__ __forceinline__ float b2f(ushort_t u) {
    union { uint_t i; float f; } c; c.i = ((uint_t)u) << 16; return c.f;
}
__device__ __forceinline__ ushort_t f2b(float f) {
    union { float f; uint_t i; } c; c.f = f;
    uint_t u = c.i;
    return (ushort_t)((u + 0x7fffu + ((u >> 16) & 1u)) >> 16);
}
__device__ __forceinline__ uint_t pack2(float a, float b) {
    return (uint_t)f2b(a) | ((uint_t)f2b(b) << 16);
}

// async global->LDS DMA, 16 B per lane; data lands at ldsbase + lane*16
__device__ __forceinline__ void gld_lds16(const ushort_t* g, ushort_t* l) {
    __builtin_amdgcn_global_load_lds((const __attribute__((address_space(1))) void*)g,
                                     (__attribute__((address_space(3))) void*)l, 16, 0, 0);
}

// ---------------------------------------------------------------------------
// One-shot-K MFMA GEMM: C = act(A) @ W + bias, fp32 acc, fused stats partials.
// BM=64 rows/block, BK=128 (full K per tile), KT tiles (KT=2 only for layer 1).
// MODE 0: plain A. MODE 1: relu(a*sc+sh) on A-fragments. MODE 2: concat plain.
// MODE 3: concat, relu(a*sc+sh) applied to tile-0 fragments only (raw y0 + P).
// Staging via global_load_lds w/ source-slot XOR swizzle (slot^row&15).
// In-place safe when C==A: all staging reads complete before epilogue stores.
// ---------------------------------------------------------------------------
template<int KT, int N, int MODE, int STATS, typename CT>
__launch_bounds__(256)
__global__ void mfma_gemm2_k(const ushort_t* __restrict__ A, const ushort_t* __restrict__ A2,
                             const ushort_t* __restrict__ WT, const float* __restrict__ bias,
                             const float* __restrict__ scale, const float* __restrict__ shift,
                             CT* __restrict__ C, float* __restrict__ sumP, float* __restrict__ sqP) {
    constexpr bool HASACT = (MODE == 1 || MODE == 3);
    constexpr int NT = N / 16;                 // 8 (N=128) or 4 (N=64)
    constexpr int AELEMS = 64 * 128;           // bf16 elems per A tile
    constexpr int BELEMS = N * 128;
    constexpr int LDC = (sizeof(CT) == 4) ? (N + 4) : (N + 8);  // 16B-aligned rows
    constexpr size_t STAGE_B = (size_t)(AELEMS + BELEMS) * 2;
    constexpr size_t EPI_B = (size_t)64 * LDC * sizeof(CT);
    constexpr size_t SMEM_B = STAGE_B > EPI_B ? STAGE_B : EPI_B;

    __shared__ __attribute__((aligned(16))) char smem[SMEM_B];
    __shared__ float sred[STATS ? 4 * 128 * 2 : 1];   // [wave][col][{sum,sq}]
    __shared__ float s_sc[HASACT ? 128 : 1];
    __shared__ float s_sh[HASACT ? 128 : 1];

    ushort_t* As = (ushort_t*)smem;
    ushort_t* Bs = As + AELEMS;

    const int tid = threadIdx.x;
    const int lane = tid & 63;
    const int wave = tid >> 6;
    const int quad = lane >> 4;
    const int l16 = lane & 15;
    const int row0 = blockIdx.x * 64;
    const int srow = lane >> 4;      // row-in-group for staging
    const int sp16 = lane & 15;      // slot-in-row for staging

    if (HASACT && tid < 128) { s_sc[tid] = scale[tid]; s_sh[tid] = shift[tid]; }

    float4_t acc[NT];
    #pragma unroll
    for (int nt = 0; nt < NT; ++nt) acc[nt] = (float4_t)0.f;

    for (int kt = 0; kt < KT; ++kt) {
        if (kt) __syncthreads();   // prior tile's ds_reads done before overwrite
        // ---- stage A tile (64 rows x 256 B payload): 4 DMA insts per wave ----
        #pragma unroll
        for (int i = 0; i < 4; ++i) {
            int t = i * 4 + wave;          // instruction id: LDS bytes [t*1024, +1024)
            int r = t * 4 + srow;          // tile row 0..63
            int sp = sp16 ^ (r & 15);      // swizzled source slot
            const ushort_t* src;
            if (MODE >= 2) src = (kt == 0 ? A : A2) + (size_t)(row0 + r) * 128 + sp * 8;
            else           src = A + (size_t)(row0 + r) * (KT * 128) + kt * 128 + sp * 8;
            gld_lds16(src, As + t * 512);
        }
        // ---- stage B tile (N rows x 256 B): N/16 DMA insts per wave ----
        #pragma unroll
        for (int i = 0; i < N / 16; ++i) {
            int t = i * 4 + wave;
            int r = t * 4 + srow;
            int sp = sp16 ^ (r & 15);
            gld_lds16(WT + (size_t)r * (KT * 128) + kt * 128 + sp * 8, Bs + t * 512);
        }
        __syncthreads();   // drains the DMA (vmcnt) + orders s_sc/s_sh

        // ---- compute: wave owns rows [wave*16, wave*16+16) x all N cols ----
        #pragma unroll
        for (int kk = 0; kk < 4; ++kk) {
            int j = kk * 4 + quad;         // 16B k-slot index
            short8_t af = *(const short8_t*)&As[(wave * 16 + l16) * 128 + ((j ^ l16) * 8)];
            if (MODE == 1 || (MODE == 3 && kt == 0)) {
                int kb = kk * 32 + quad * 8;
                float4 c0 = *(const float4*)&s_sc[kb], c1 = *(const float4*)&s_sc[kb + 4];
                float4 hh0 = *(const float4*)&s_sh[kb], hh1 = *(const float4*)&s_sh[kb + 4];
                ushort_t u[8];
                *(short8_t*)u = af;
                u[0] = f2b(fmaxf(fmaf(b2f(u[0]), c0.x, hh0.x), 0.f));
                u[1] = f2b(fmaxf(fmaf(b2f(u[1]), c0.y, hh0.y), 0.f));
                u[2] = f2b(fmaxf(fmaf(b2f(u[2]), c0.z, hh0.z), 0.f));
                u[3] = f2b(fmaxf(fmaf(b2f(u[3]), c0.w, hh0.w), 0.f));
                u[4] = f2b(fmaxf(fmaf(b2f(u[4]), c1.x, hh1.x), 0.f));
                u[5] = f2b(fmaxf(fmaf(b2f(u[5]), c1.y, hh1.y), 0.f));
                u[6] = f2b(fmaxf(fmaf(b2f(u[6]), c1.z, hh1.z), 0.f));
                u[7] = f2b(fmaxf(fmaf(b2f(u[7]), c1.w, hh1.w), 0.f));
                af = *(const short8_t*)u;
            }
            #pragma unroll
            for (int nt = 0; nt < NT; ++nt) {
                short8_t bf = *(const short8_t*)&Bs[(nt * 16 + l16) * 128 + ((j ^ l16) * 8)];
                acc[nt] = __builtin_amdgcn_mfma_f32_16x16x32_bf16(af, bf, acc[nt], 0, 0, 0);
            }
        }
    }

    // ---- bias + per-wave stats (C/D layout: col=l16, row=quad*4+r) ----
    #pragma unroll
    for (int nt = 0; nt < NT; ++nt) {
        int col = nt * 16 + l16;
        float bv = bias[col];
        float s = 0.f, q = 0.f;
        #pragma unroll
        for (int r = 0; r < 4; ++r) {
            float v = acc[nt][r] + bv;
            acc[nt][r] = v;
            if (STATS) { s += v; q = fmaf(v, v, q); }
        }
        if (STATS) {
            s += __shfl_xor(s, 16); q += __shfl_xor(q, 16);
            s += __shfl_xor(s, 32); q += __shfl_xor(q, 32);
            if (lane < 16) {
                sred[(wave * 128 + col) * 2 + 0] = s;
                sred[(wave * 128 + col) * 2 + 1] = q;
            }
        }
    }
    __syncthreads();   // staging reads done; sred visible

    // ---- LDS transpose (all 64 rows at once) ----
    CT* Ct = (CT*)smem;
    #pragma unroll
    for (int nt = 0; nt < NT; ++nt) {
        int col = nt * 16 + l16;
        #pragma unroll
        for (int r = 0; r < 4; ++r) {
            int row = wave * 16 + quad * 4 + r;
            if constexpr (sizeof(CT) == 4) Ct[row * LDC + col] = acc[nt][r];
            else                           Ct[row * LDC + col] = (CT)f2b(acc[nt][r]);
        }
    }
    __syncthreads();

    // ---- stats flush: one coalesced partial row per block (no atomics) ----
    if (STATS) {
        int col = tid & 127, qs = tid >> 7;
        float v = sred[(0 * 128 + col) * 2 + qs] + sred[(1 * 128 + col) * 2 + qs]
                + sred[(2 * 128 + col) * 2 + qs] + sred[(3 * 128 + col) * 2 + qs];
        (qs ? sqP : sumP)[(size_t)blockIdx.x * 128 + col] = v;
    }
    // ---- coalesced 16 B stores ----
    if constexpr (sizeof(CT) == 2) {
        constexpr int G = N / 8;
        #pragma unroll
        for (int p = 0; p < (64 * G) / 256; ++p) {
            int s = p * 256 + tid;
            int row = s / G, c8 = (s % G) * 8;
            *(uint4*)&C[(size_t)(row0 + row) * N + c8] =
                *(const uint4*)&((const ushort_t*)smem)[row * LDC + c8];
        }
    } else {
        constexpr int G = N / 4;
        #pragma unroll
        for (int p = 0; p < (64 * G) / 256; ++p) {
            int s = p * 256 + tid;
            int row = s / G, c4 = (s % G) * 4;
            *(float4*)&C[(size_t)(row0 + row) * N + c4] =
                *(const float4*)&((const float*)smem)[row * LDC + c4];
        }
    }
}

// ---------------------------------------------------------------------------
// fp32 vector GEMM (layer 0: K=32, fp32 input) with fused stats partials.
// ---------------------------------------------------------------------------
template<int K, int N>
__launch_bounds__(256)
__global__ void gemm_f32_k(const float* __restrict__ A, const float* __restrict__ W,
                           const float* __restrict__ bias, ushort_t* __restrict__ C,
                           float* __restrict__ sumP, float* __restrict__ sqP) {
    constexpr int TX = N / 4;        // 32
    constexpr int TY = 256 / TX;     // 8
    constexpr int RM = TILE_M / TY;  // 8

    __shared__ float As[TILE_M][BK + 1];
    __shared__ float Ws[BK][N];
    __shared__ float redst[2][TY][N];   // stats partial reduce (8 KB)

    const int tid = threadIdx.x;
    const int tx = tid % TX;
    const int ty = tid / TX;
    const int row0 = blockIdx.x * TILE_M;
    const int arow = tid >> 2;
    const int acol = (tid & 3) * 8;

    float acc[RM][4];
    #pragma unroll
    for (int r = 0; r < RM; ++r)
        #pragma unroll
        for (int c = 0; c < 4; ++c) acc[r][c] = 0.f;

    for (int k0 = 0; k0 < K; k0 += BK) {
        {
            const float4* p = (const float4*)&A[(size_t)(row0 + arow) * K + k0 + acol];
            float4 x0 = p[0], x1 = p[1];
            As[arow][acol + 0] = x0.x; As[arow][acol + 1] = x0.y;
            As[arow][acol + 2] = x0.z; As[arow][acol + 3] = x0.w;
            As[arow][acol + 4] = x1.x; As[arow][acol + 5] = x1.y;
            As[arow][acol + 6] = x1.z; As[arow][acol + 7] = x1.w;
        }
        #pragma unroll
        for (int i = 0; i < (BK * N) / 256; ++i) {
            int e = i * 256 + tid;
            Ws[e / N][e % N] = W[(size_t)(k0 + e / N) * N + e % N];
        }
        __syncthreads();
        #pragma unroll
        for (int kk = 0; kk < BK; ++kk) {
            float4 wv = *(const float4*)&Ws[kk][tx * 4];
            #pragma unroll
            for (int r = 0; r < RM; ++r) {
                float a = As[ty * RM + r][kk];
                acc[r][0] = fmaf(a, wv.x, acc[r][0]);
                acc[r][1] = fmaf(a, wv.y, acc[r][1]);
                acc[r][2] = fmaf(a, wv.z, acc[r][2]);
                acc[r][3] = fmaf(a, wv.w, acc[r][3]);
            }
        }
        __syncthreads();
    }
    float4 bv = *(const float4*)&bias[tx * 4];
    float s[4] = {0, 0, 0, 0}, q[4] = {0, 0, 0, 0};
    #pragma unroll
    for (int r = 0; r < RM; ++r) {
        float o[4];
        o[0] = acc[r][0] + bv.x; o[1] = acc[r][1] + bv.y;
        o[2] = acc[r][2] + bv.z; o[3] = acc[r][3] + bv.w;
        #pragma unroll
        for (int c = 0; c < 4; ++c) { s[c] += o[c]; q[c] = fmaf(o[c], o[c], q[c]); }
        size_t off = (size_t)(row0 + ty * RM + r) * N + tx * 4;
        uint2 ov;
        ov.x = pack2(o[0], o[1]);
        ov.y = pack2(o[2], o[3]);
        *(uint2*)&C[off] = ov;
    }
    #pragma unroll
    for (int c = 0; c < 4; ++c) {
        redst[0][ty][tx * 4 + c] = s[c];
        redst[1][ty][tx * 4 + c] = q[c];
    }
    __syncthreads();
    {
        int col = tid & (N - 1), qs = tid / N;   // 256 threads -> 2 x 128 outputs
        float v = 0.f;
        #pragma unroll
        for (int t = 0; t < TY; ++t) v += redst[qs][t][col];
        (qs ? sqP : sumP)[(size_t)blockIdx.x * N + col] = v;
    }
}

// ---------------------------------------------------------------------------
// Tree-reduce block partials: P[NBLK][128] -> R2[col*64 + chunk] (64 chunks).
// ---------------------------------------------------------------------------
template<int NBLK>
__global__ __launch_bounds__(256) void reduce1_k(const float* __restrict__ sumP,
                                                 const float* __restrict__ sqP,
                                                 float* __restrict__ sumR2,
                                                 float* __restrict__ sqR2) {
    constexpr int ROWS = NBLK / 64;
    const int tid = threadIdx.x;
    const int qs = blockIdx.x & 1;
    const int chunk = blockIdx.x >> 1;
    const float* src = qs ? sqP : sumP;
    float* dst = qs ? sqR2 : sumR2;
    const int col = tid & 127;
    const int half = tid >> 7;
    float s = 0.f;
    for (int r = half; r < ROWS; r += 2)
        s += src[(size_t)(chunk * ROWS + r) * 128 + col];
    __shared__ float red[256];
    red[tid] = s;
    __syncthreads();
    if (tid < 128) dst[col * 64 + chunk] = red[tid] + red[tid + 128];
}

// Reduce 64 chunks; scale = g*rsqrt(var+eps); shift = be - mean*scale
__global__ void finalize_k(const float* __restrict__ sumR2, const float* __restrict__ sqR2,
                           const float* __restrict__ g, const float* __restrict__ be,
                           float* __restrict__ scale, float* __restrict__ shift) {
    const int f = threadIdx.x;  // 128
    const float4* ps = (const float4*)&sumR2[f * REP];
    const float4* pq = (const float4*)&sqR2[f * REP];
    float s = 0.f, q = 0.f;
    #pragma unroll
    for (int i = 0; i < REP / 4; ++i) {
        float4 a = ps[i]; s += (a.x + a.y) + (a.z + a.w);
        float4 b = pq[i]; q += (b.x + b.y) + (b.z + b.w);
    }
    const float invM = 1.f / (float)M_ROWS;
    float mean = s * invM;
    float var = q * invM - mean * mean;
    float sc = g[f] * rsqrtf(var + 1e-5f);
    scale[f] = sc;
    shift[f] = fmaf(-mean, sc, be[f]);
}

// fp32 W[K][N] -> bf16 WT[N][K] (tiny)
__global__ void transpose_w_k(const float* __restrict__ W, ushort_t* __restrict__ WT,
                              int K, int N) {
    int idx = blockIdx.x * 256 + threadIdx.x;
    if (idx < K * N) {
        int k = idx / N, n = idx % N;
        WT[(size_t)n * K + k] = f2b(W[idx]);
    }
}

// ---------------------------------------------------------------------------
// Chunked causal cummax, one block per (ba) sequence (T=256, 128 feats).
// 512 thr: fp = tid&63 (feature pair), chunk = wave = tid>>6 (32 t-steps).
// Pass 1: bnrelu + local scan, values in regs, chunk max -> LDS.
// Pass 2: wave-uniform prefix over earlier chunks, replay, store cummax.
// scan_p_k: reads raw Y, writes P only (X stays raw; consumer GEMM applies act).
// scan_inplace_k: reads raw Y, writes cummax(bnrelu(Y)) in place.
// ---------------------------------------------------------------------------
template<int INPLACE>
__global__ __launch_bounds__(512) void scan_k(const ushort_t* __restrict__ Y,
                                              const float* __restrict__ scale,
                                              const float* __restrict__ shift,
                                              ushort_t* __restrict__ P) {
    const int tid = threadIdx.x;
    const int fp = tid & 63;
    const int chunk = tid >> 6;    // == wave id, 0..7
    const size_t base = (size_t)blockIdx.x * 256 * 128 + fp * 2;
    const float sc0 = scale[fp * 2], sh0 = shift[fp * 2];
    const float sc1 = scale[fp * 2 + 1], sh1 = shift[fp * 2 + 1];

    __shared__ float cmax[8][128];

    uint_t vals[32];
    float run0 = 0.f, run1 = 0.f;   // post-relu >= 0
    #pragma unroll
    for (int i = 0; i < 32; ++i) {
        size_t idx = base + (size_t)(chunk * 32 + i) * 128;
        uint_t u = *(const uint_t*)&Y[idx];
        float v0 = fmaxf(fmaf(b2f((ushort_t)(u & 0xffff)), sc0, sh0), 0.f);
        float v1 = fmaxf(fmaf(b2f((ushort_t)(u >> 16)), sc1, sh1), 0.f);
        run0 = fmaxf(run0, v0);
        run1 = fmaxf(run1, v1);
        vals[i] = pack2(v0, v1);
    }
    cmax[chunk][fp * 2] = run0;
    cmax[chunk][fp * 2 + 1] = run1;
    __syncthreads();
    float p0 = 0.f, p1 = 0.f;
    for (int c = 0; c < chunk; ++c) {   // wave-uniform trip count
        p0 = fmaxf(p0, cmax[c][fp * 2]);
        p1 = fmaxf(p1, cmax[c][fp * 2 + 1]);
    }
    run0 = p0; run1 = p1;
    ushort_t* dst = INPLACE ? (ushort_t*)Y : P;
    #pragma unroll
    for (int i = 0; i < 32; ++i) {
        uint_t u = vals[i];
        run0 = fmaxf(run0, b2f((ushort_t)(u & 0xffff)));
        run1 = fmaxf(run1, b2f((ushort_t)(u >> 16)));
        *(uint_t*)&dst[base + (size_t)(chunk * 32 + i) * 128] = pack2(run0, run1);
    }
}

extern "C" void kernel_launch(void* const* d_in, const int* in_sizes, int n_in,
                              void* d_out, int out_size, void* d_ws, size_t ws_size,
                              hipStream_t stream) {
    const float* poly = (const float*)d_in[0];
    const float* W0 = (const float*)d_in[1];
    const float* b0 = (const float*)d_in[2];
    const float* g0 = (const float*)d_in[3];
    const float* be0 = (const float*)d_in[4];
    const float* W1 = (const float*)d_in[5];
    const float* b1 = (const float*)d_in[6];
    const float* g1 = (const float*)d_in[7];
    const float* be1 = (const float*)d_in[8];
    const float* W2 = (const float*)d_in[9];
    const float* b2 = (const float*)d_in[10];
    const float* g2 = (const float*)d_in[11];
    const float* be2 = (const float*)d_in[12];
    const float* W3 = (const float*)d_in[13];
    const float* b3 = (const float*)d_in[14];
    const float* g3 = (const float*)d_in[15];
    const float* be3 = (const float*)d_in[16];
    const float* W4 = (const float*)d_in[17];
    const float* b4 = (const float*)d_in[18];
    float* out = (float*)d_out;

    // Workspace (floats unless noted):
    //   sumP[4096*128] | sqP[4096*128] | sumR2[8192] | sqR2[8192] | scale/shift
    //   WT1..WT4 bf16 (144 KB) | h0 | h1 (M*128 bf16 each)
    float* st = (float*)d_ws;
    float* sumP = st;
    float* sqP = st + 524288;
    float* sumR2 = st + 1048576;
    float* sqR2 = sumR2 + 8192;
    float* scsh = st + 1064960;
    auto scP = [&](int i) { return scsh + i * 256; };
    auto shP = [&](int i) { return scsh + i * 256 + 128; };
    ushort_t* wt1 = (ushort_t*)((char*)d_ws + 4263936);         // 128 x 256
    ushort_t* wt2 = wt1 + 128 * 256;                            // 128 x 128
    ushort_t* wt3 = wt2 + 128 * 128;                            // 128 x 128
    ushort_t* wt4 = wt3 + 128 * 128;                            // 64 x 128
    ushort_t* h0 = (ushort_t*)((char*)d_ws + 4263936 + 147456);
    ushort_t* h1 = h0 + (size_t)M_ROWS * 128;

    const int G64 = M_ROWS / TILE_M;   // 4096 blocks (both GEMM flavors)
    const int GBA = 1024;              // one block per (b,a) sequence

    transpose_w_k<<<128, 256, 0, stream>>>(W1, wt1, 256, 128);
    transpose_w_k<<<64, 256, 0, stream>>>(W2, wt2, 128, 128);
    transpose_w_k<<<64, 256, 0, stream>>>(W3, wt3, 128, 128);
    transpose_w_k<<<32, 256, 0, stream>>>(W4, wt4, 128, 64);

    // Layer 0 (fp32 precision): y0 = poly @ W0 + b0 -> h0 (raw bf16) + partials
    gemm_f32_k<32, 128><<<G64, 256, 0, stream>>>(poly, W0, b0, h0, sumP, sqP);
    reduce1_k<4096><<<128, 256, 0, stream>>>(sumP, sqP, sumR2, sqR2);
    finalize_k<<<1, 128, 0, stream>>>(sumR2, sqR2, g0, be0, scP(0), shP(0));

    // P = cummax(bnrelu0(y0)) -> h1 ; h0 stays RAW y0
    scan_k<0><<<GBA, 512, 0, stream>>>(h0, scP(0), shP(0), h1);

    // Layer 1: y1 = [bnrelu0(y0), P] @ W1 + b1 -> h0 (in place), MODE3
    mfma_gemm2_k<2, 128, 3, 1, ushort_t><<<G64, 256, 0, stream>>>(
        h0, h1, wt1, b1, scP(0), shP(0), h0, sumP, sqP);
    reduce1_k<4096><<<128, 256, 0, stream>>>(sumP, sqP, sumR2, sqR2);
    finalize_k<<<1, 128, 0, stream>>>(sumR2, sqR2, g1, be1, scP(1), shP(1));

    // Layer 2: y2 = bnrelu1(y1) @ W2 + b2 -> h0 (in place), act-on-frag
    mfma_gemm2_k<1, 128, 1, 1, ushort_t><<<G64, 256, 0, stream>>>(
        h0, nullptr, wt2, b2, scP(1), shP(1), h0, sumP, sqP);
    reduce1_k<4096><<<128, 256, 0, stream>>>(sumP, sqP, sumR2, sqR2);
    finalize_k<<<1, 128, 0, stream>>>(sumR2, sqR2, g2, be2, scP(2), shP(2));

    // pooled = cummax(bnrelu2(y2)) in place in h0
    scan_k<1><<<GBA, 512, 0, stream>>>(h0, scP(2), shP(2), nullptr);

    // Layer 3: y3 = pooled @ W3 + b3 -> h0 (in place)
    mfma_gemm2_k<1, 128, 0, 1, ushort_t><<<G64, 256, 0, stream>>>(
        h0, nullptr, wt3, b3, nullptr, nullptr, h0, sumP, sqP);
    reduce1_k<4096><<<128, 256, 0, stream>>>(sumP, sqP, sumR2, sqR2);
    finalize_k<<<1, 128, 0, stream>>>(sumR2, sqR2, g3, be3, scP(3), shP(3));

    // Layer 4: out = bnrelu3(y3) @ W4 + b4 -> d_out (fp32), act-on-frag
    mfma_gemm2_k<1, 64, 1, 0, float><<<G64, 256, 0, stream>>>(
        h0, nullptr, wt4, b4, scP(3), shP(3), out, nullptr, nullptr);
}

// Round 9
// 384.521 us; speedup vs baseline: 2.3562x; 1.0679x over previous
//
#include <hip/hip_runtime.h>
#include <hip/hip_bf16.h>

// Problem constants (fixed by setup_inputs)
#define M_ROWS 262144   // B*A*T = 16*64*256
#define TILE_M 64
#define BK 32
#define REP 64          // second-level stats partials (matches finalize_k layout)

typedef unsigned short ushort_t;
typedef unsigned int uint_t;
typedef __attribute__((ext_vector_type(8))) short short8_t;   // 8 bf16 = 4 VGPRs
typedef __attribute__((ext_vector_type(4))) float float4_t;   // MFMA acc

// bf16 (stored as ushort) <-> fp32 helpers. Load is exact; store is RNE.
__device__ __forceinline__ float b2f(ushort_t u) {
    union { uint_t i; float f; } c; c.i = ((uint_t)u) << 16; return c.f;
}
__device__ __forceinline__ ushort_t f2b(float f) {
    union { float f; uint_t i; } c; c.f = f;
    uint_t u = c.i;
    return (ushort_t)((u + 0x7fffu + ((u >> 16) & 1u)) >> 16);
}
// packed 2xfp32 -> 2xbf16 (v_cvt_pk_bf16_f32 on gfx950, RNE)
__device__ __forceinline__ uint_t pack2(float a, float b) {
    union { __hip_bfloat162 h; uint_t u; } c;
    c.h = __float22bfloat162_rn(make_float2(a, b));
    return c.u;
}

// async global->LDS DMA, 16 B per lane; data lands at ldsbase + lane*16
__device__ __forceinline__ void gld_lds16(const ushort_t* g, ushort_t* l) {
    __builtin_amdgcn_global_load_lds((const __attribute__((address_space(1))) void*)g,
                                     (__attribute__((address_space(3))) void*)l, 16, 0, 0);
}

// ---------------------------------------------------------------------------
// Persistent pipelined MFMA GEMM for K=128 layers: C = act(A)@W + bias.
// Grid = M/(64*RPT) blocks; each block: stage B ONCE (resident 32/16 KB),
// then RPT row-tiles of 64 rows with DOUBLE-BUFFERED A via global_load_lds:
// DMA for tile i+1 issues right after the tile-i barrier and overlaps tile-i
// compute + epilogue, so the vmcnt drain at the next barrier is ~free.
// Waves 2x2: wave(wm,wn) owns rows wm*32+mt*16, cols wn*(N/2)+nt*16.
// Epilogue transposes into the CURRENT A buffer (free after compute) using a
// 16B-granule XOR swizzle (conflict-light), then 16 B coalesced stores.
// Stats (sum/sumsq per col) accumulate in regs across tiles; 1 flush/block.
// In-place safe (C==A): tile i's rows are stored before nothing that reads
// them again; prefetch of tile i+1 touches disjoint rows.
// ---------------------------------------------------------------------------
template<int N, int MODE, int STATS, int RPT, typename CT>
__launch_bounds__(256)
__global__ void mfma_gemm3_k(const ushort_t* __restrict__ A, const ushort_t* __restrict__ WT,
                             const float* __restrict__ bias,
                             const float* __restrict__ scale, const float* __restrict__ shift,
                             CT* __restrict__ C, float* __restrict__ sumP, float* __restrict__ sqP) {
    constexpr int WN = N / 2;        // cols per wave-column (64 or 32)
    constexpr int NT = WN / 16;      // 4 (N=128) or 2 (N=64)

    __shared__ __attribute__((aligned(16))) ushort_t Bs[N * 128];
    __shared__ __attribute__((aligned(16))) ushort_t Abuf[2][64 * 128];
    __shared__ float sred[STATS ? 4 * N * 2 : 1];
    __shared__ float s_sc[MODE == 1 ? 128 : 1];
    __shared__ float s_sh[MODE == 1 ? 128 : 1];

    const int tid = threadIdx.x;
    const int lane = tid & 63;
    const int wave = tid >> 6;
    const int wm = wave & 1;
    const int wn = wave >> 1;
    const int quad = lane >> 4;
    const int l16 = lane & 15;
    const int srow = lane >> 4;      // staging: row-in-group
    const int sp16 = lane & 15;      // staging: slot-in-row

    if (MODE == 1 && tid < 128) { s_sc[tid] = scale[tid]; s_sh[tid] = shift[tid]; }

    // ---- stage B once (N rows x 256 B), XOR-swizzled source slots ----
    #pragma unroll
    for (int i = 0; i < N / 16; ++i) {
        int t = i * 4 + wave;
        int r = t * 4 + srow;
        int sp = sp16 ^ (r & 15);
        gld_lds16(WT + (size_t)r * 128 + sp * 8, Bs + t * 512);
    }
    // ---- stage A tile 0 ----
    {
        int r0 = blockIdx.x * (RPT * 64);
        #pragma unroll
        for (int i = 0; i < 4; ++i) {
            int t = i * 4 + wave;
            int r = t * 4 + srow;
            int sp = sp16 ^ (r & 15);
            gld_lds16(A + (size_t)(r0 + r) * 128 + sp * 8, Abuf[0] + t * 512);
        }
    }

    float bvs[NT];
    #pragma unroll
    for (int nt = 0; nt < NT; ++nt) bvs[nt] = bias[wn * WN + nt * 16 + l16];
    float sSum[STATS ? NT : 1] = {0.f}, sSq[STATS ? NT : 1] = {0.f};

    for (int it = 0; it < RPT; ++it) {
        __syncthreads();   // A(it) [+B on it=0] resident; prior epi reads done
        // ---- prefetch A(it+1): overlaps compute+epilogue of tile it ----
        if (it + 1 < RPT) {
            int r0 = blockIdx.x * (RPT * 64) + (it + 1) * 64;
            #pragma unroll
            for (int i = 0; i < 4; ++i) {
                int t = i * 4 + wave;
                int r = t * 4 + srow;
                int sp = sp16 ^ (r & 15);
                gld_lds16(A + (size_t)(r0 + r) * 128 + sp * 8, Abuf[(it + 1) & 1] + t * 512);
            }
        }
        const ushort_t* As = Abuf[it & 1];

        float4_t acc[2][NT];
        #pragma unroll
        for (int mt = 0; mt < 2; ++mt)
            #pragma unroll
            for (int nt = 0; nt < NT; ++nt) acc[mt][nt] = (float4_t)0.f;

        #pragma unroll
        for (int kk = 0; kk < 4; ++kk) {
            int j = kk * 4 + quad;     // 16B k-slot; frag k = kk*32 + quad*8 + i
            short8_t a0 = *(const short8_t*)&As[(wm * 32 + l16) * 128 + ((j ^ l16) * 8)];
            short8_t a1 = *(const short8_t*)&As[(wm * 32 + 16 + l16) * 128 + ((j ^ l16) * 8)];
            if (MODE == 1) {
                int kb = kk * 32 + quad * 8;
                float4 c0 = *(const float4*)&s_sc[kb], c1 = *(const float4*)&s_sc[kb + 4];
                float4 h0 = *(const float4*)&s_sh[kb], h1 = *(const float4*)&s_sh[kb + 4];
                #pragma unroll
                for (int z = 0; z < 2; ++z) {
                    ushort_t u[8];
                    *(short8_t*)u = z ? a1 : a0;
                    uint_t w[4];
                    w[0] = pack2(fmaxf(fmaf(b2f(u[0]), c0.x, h0.x), 0.f),
                                 fmaxf(fmaf(b2f(u[1]), c0.y, h0.y), 0.f));
                    w[1] = pack2(fmaxf(fmaf(b2f(u[2]), c0.z, h0.z), 0.f),
                                 fmaxf(fmaf(b2f(u[3]), c0.w, h0.w), 0.f));
                    w[2] = pack2(fmaxf(fmaf(b2f(u[4]), c1.x, h1.x), 0.f),
                                 fmaxf(fmaf(b2f(u[5]), c1.y, h1.y), 0.f));
                    w[3] = pack2(fmaxf(fmaf(b2f(u[6]), c1.z, h1.z), 0.f),
                                 fmaxf(fmaf(b2f(u[7]), c1.w, h1.w), 0.f));
                    short8_t rr;
                    *(uint4*)&rr = *(const uint4*)w;
                    if (z) a1 = rr; else a0 = rr;
                }
            }
            #pragma unroll
            for (int nt = 0; nt < NT; ++nt) {
                short8_t bf = *(const short8_t*)&Bs[(wn * WN + nt * 16 + l16) * 128 + ((j ^ l16) * 8)];
                acc[0][nt] = __builtin_amdgcn_mfma_f32_16x16x32_bf16(a0, bf, acc[0][nt], 0, 0, 0);
                acc[1][nt] = __builtin_amdgcn_mfma_f32_16x16x32_bf16(a1, bf, acc[1][nt], 0, 0, 0);
            }
        }

        // ---- bias + stats accumulate (C/D layout: col=l16, row=quad*4+r) ----
        #pragma unroll
        for (int mt = 0; mt < 2; ++mt)
            #pragma unroll
            for (int nt = 0; nt < NT; ++nt)
                #pragma unroll
                for (int r = 0; r < 4; ++r) {
                    float v = acc[mt][nt][r] + bvs[nt];
                    acc[mt][nt][r] = v;
                    if (STATS) { sSum[nt] += v; sSq[nt] = fmaf(v, v, sSq[nt]); }
                }
        if (STATS && it == RPT - 1) {
            #pragma unroll
            for (int nt = 0; nt < NT; ++nt) {
                float s = sSum[nt], q = sSq[nt];
                s += __shfl_xor(s, 16); q += __shfl_xor(q, 16);
                s += __shfl_xor(s, 32); q += __shfl_xor(q, 32);
                if (lane < 16) {
                    int col = wn * WN + nt * 16 + l16;
                    sred[(wave * N + col) * 2 + 0] = s;
                    sred[(wave * N + col) * 2 + 1] = q;
                }
            }
        }
        __syncthreads();   // all ds_reads of Abuf[it&1] done; sred visible

        // ---- transpose into the now-free A buffer (16B-granule XOR swizzle) ----
        char* eb = (char*)Abuf[it & 1];
        #pragma unroll
        for (int mt = 0; mt < 2; ++mt)
            #pragma unroll
            for (int nt = 0; nt < NT; ++nt) {
                int col = wn * WN + nt * 16 + l16;
                int bc = col * (int)sizeof(CT);
                #pragma unroll
                for (int r = 0; r < 4; ++r) {
                    int row = wm * 32 + mt * 16 + quad * 4 + r;
                    int addr = row * 256 + ((((bc >> 4) ^ (row & 15)) << 4) | (bc & 15));
                    if constexpr (sizeof(CT) == 4) *(float*)(eb + addr) = acc[mt][nt][r];
                    else                           *(ushort_t*)(eb + addr) = f2b(acc[mt][nt][r]);
                }
            }
        if (STATS && it == RPT - 1) {
            // one coalesced partial row per block (no atomics)
            int col = tid & (N - 1), qs = tid / N;   // 2N == 256 threads
            int wb = (col / WN) * 2;                 // the two waves owning this col
            float v = sred[(wb * N + col) * 2 + qs] + sred[((wb + 1) * N + col) * 2 + qs];
            (qs ? sqP : sumP)[(size_t)blockIdx.x * N + col] = v;
        }
        __syncthreads();

        // ---- coalesced 16 B stores (row = 256 B for both CT flavors) ----
        int r0 = blockIdx.x * (RPT * 64) + it * 64;
        #pragma unroll
        for (int p = 0; p < 4; ++p) {
            int s = p * 256 + tid;
            int row = s >> 4, g = s & 15;
            uint4 v = *(const uint4*)(eb + row * 256 + ((g ^ (row & 15)) << 4));
            *(uint4*)((char*)(C + (size_t)(r0 + row) * N) + g * 16) = v;
        }
    }
}

// ---------------------------------------------------------------------------
// One-shot-K MFMA GEMM (layer 1 only now): KT=2, MODE3 concat w/ act on tile0.
// ---------------------------------------------------------------------------
template<int KT, int N, int MODE, int STATS, typename CT>
__launch_bounds__(256)
__global__ void mfma_gemm2_k(const ushort_t* __restrict__ A, const ushort_t* __restrict__ A2,
                             const ushort_t* __restrict__ WT, const float* __restrict__ bias,
                             const float* __restrict__ scale, const float* __restrict__ shift,
                             CT* __restrict__ C, float* __restrict__ sumP, float* __restrict__ sqP) {
    constexpr bool HASACT = (MODE == 1 || MODE == 3);
    constexpr int NT = N / 16;
    constexpr int AELEMS = 64 * 128;
    constexpr int BELEMS = N * 128;
    constexpr int LDC = (sizeof(CT) == 4) ? (N + 4) : (N + 8);
    constexpr size_t STAGE_B = (size_t)(AELEMS + BELEMS) * 2;
    constexpr size_t EPI_B = (size_t)64 * LDC * sizeof(CT);
    constexpr size_t SMEM_B = STAGE_B > EPI_B ? STAGE_B : EPI_B;

    __shared__ __attribute__((aligned(16))) char smem[SMEM_B];
    __shared__ float sred[STATS ? 4 * 128 * 2 : 1];
    __shared__ float s_sc[HASACT ? 128 : 1];
    __shared__ float s_sh[HASACT ? 128 : 1];

    ushort_t* As = (ushort_t*)smem;
    ushort_t* Bs = As + AELEMS;

    const int tid = threadIdx.x;
    const int lane = tid & 63;
    const int wave = tid >> 6;
    const int quad = lane >> 4;
    const int l16 = lane & 15;
    const int row0 = blockIdx.x * 64;
    const int srow = lane >> 4;
    const int sp16 = lane & 15;

    if (HASACT && tid < 128) { s_sc[tid] = scale[tid]; s_sh[tid] = shift[tid]; }

    float4_t acc[NT];
    #pragma unroll
    for (int nt = 0; nt < NT; ++nt) acc[nt] = (float4_t)0.f;

    for (int kt = 0; kt < KT; ++kt) {
        if (kt) __syncthreads();
        #pragma unroll
        for (int i = 0; i < 4; ++i) {
            int t = i * 4 + wave;
            int r = t * 4 + srow;
            int sp = sp16 ^ (r & 15);
            const ushort_t* src;
            if (MODE >= 2) src = (kt == 0 ? A : A2) + (size_t)(row0 + r) * 128 + sp * 8;
            else           src = A + (size_t)(row0 + r) * (KT * 128) + kt * 128 + sp * 8;
            gld_lds16(src, As + t * 512);
        }
        #pragma unroll
        for (int i = 0; i < N / 16; ++i) {
            int t = i * 4 + wave;
            int r = t * 4 + srow;
            int sp = sp16 ^ (r & 15);
            gld_lds16(WT + (size_t)r * (KT * 128) + kt * 128 + sp * 8, Bs + t * 512);
        }
        __syncthreads();

        #pragma unroll
        for (int kk = 0; kk < 4; ++kk) {
            int j = kk * 4 + quad;
            short8_t af = *(const short8_t*)&As[(wave * 16 + l16) * 128 + ((j ^ l16) * 8)];
            if (MODE == 1 || (MODE == 3 && kt == 0)) {
                int kb = kk * 32 + quad * 8;
                float4 c0 = *(const float4*)&s_sc[kb], c1 = *(const float4*)&s_sc[kb + 4];
                float4 hh0 = *(const float4*)&s_sh[kb], hh1 = *(const float4*)&s_sh[kb + 4];
                ushort_t u[8];
                *(short8_t*)u = af;
                uint_t w[4];
                w[0] = pack2(fmaxf(fmaf(b2f(u[0]), c0.x, hh0.x), 0.f),
                             fmaxf(fmaf(b2f(u[1]), c0.y, hh0.y), 0.f));
                w[1] = pack2(fmaxf(fmaf(b2f(u[2]), c0.z, hh0.z), 0.f),
                             fmaxf(fmaf(b2f(u[3]), c0.w, hh0.w), 0.f));
                w[2] = pack2(fmaxf(fmaf(b2f(u[4]), c1.x, hh1.x), 0.f),
                             fmaxf(fmaf(b2f(u[5]), c1.y, hh1.y), 0.f));
                w[3] = pack2(fmaxf(fmaf(b2f(u[6]), c1.z, hh1.z), 0.f),
                             fmaxf(fmaf(b2f(u[7]), c1.w, hh1.w), 0.f));
                *(uint4*)&af = *(const uint4*)w;
            }
            #pragma unroll
            for (int nt = 0; nt < NT; ++nt) {
                short8_t bf = *(const short8_t*)&Bs[(nt * 16 + l16) * 128 + ((j ^ l16) * 8)];
                acc[nt] = __builtin_amdgcn_mfma_f32_16x16x32_bf16(af, bf, acc[nt], 0, 0, 0);
            }
        }
    }

    #pragma unroll
    for (int nt = 0; nt < NT; ++nt) {
        int col = nt * 16 + l16;
        float bv = bias[col];
        float s = 0.f, q = 0.f;
        #pragma unroll
        for (int r = 0; r < 4; ++r) {
            float v = acc[nt][r] + bv;
            acc[nt][r] = v;
            if (STATS) { s += v; q = fmaf(v, v, q); }
        }
        if (STATS) {
            s += __shfl_xor(s, 16); q += __shfl_xor(q, 16);
            s += __shfl_xor(s, 32); q += __shfl_xor(q, 32);
            if (lane < 16) {
                sred[(wave * 128 + col) * 2 + 0] = s;
                sred[(wave * 128 + col) * 2 + 1] = q;
            }
        }
    }
    __syncthreads();

    CT* Ct = (CT*)smem;
    #pragma unroll
    for (int nt = 0; nt < NT; ++nt) {
        int col = nt * 16 + l16;
        #pragma unroll
        for (int r = 0; r < 4; ++r) {
            int row = wave * 16 + quad * 4 + r;
            if constexpr (sizeof(CT) == 4) Ct[row * LDC + col] = acc[nt][r];
            else                           Ct[row * LDC + col] = (CT)f2b(acc[nt][r]);
        }
    }
    __syncthreads();

    if (STATS) {
        int col = tid & 127, qs = tid >> 7;
        float v = sred[(0 * 128 + col) * 2 + qs] + sred[(1 * 128 + col) * 2 + qs]
                + sred[(2 * 128 + col) * 2 + qs] + sred[(3 * 128 + col) * 2 + qs];
        (qs ? sqP : sumP)[(size_t)blockIdx.x * 128 + col] = v;
    }
    if constexpr (sizeof(CT) == 2) {
        constexpr int G = N / 8;
        #pragma unroll
        for (int p = 0; p < (64 * G) / 256; ++p) {
            int s = p * 256 + tid;
            int row = s / G, c8 = (s % G) * 8;
            *(uint4*)&C[(size_t)(row0 + row) * N + c8] =
                *(const uint4*)&((const ushort_t*)smem)[row * LDC + c8];
        }
    } else {
        constexpr int G = N / 4;
        #pragma unroll
        for (int p = 0; p < (64 * G) / 256; ++p) {
            int s = p * 256 + tid;
            int row = s / G, c4 = (s % G) * 4;
            *(float4*)&C[(size_t)(row0 + row) * N + c4] =
                *(const float4*)&((const float*)smem)[row * LDC + c4];
        }
    }
}

// ---------------------------------------------------------------------------
// fp32 vector GEMM (layer 0: K=32, fp32 input) with fused stats partials.
// ---------------------------------------------------------------------------
template<int K, int N>
__launch_bounds__(256)
__global__ void gemm_f32_k(const float* __restrict__ A, const float* __restrict__ W,
                           const float* __restrict__ bias, ushort_t* __restrict__ C,
                           float* __restrict__ sumP, float* __restrict__ sqP) {
    constexpr int TX = N / 4;        // 32
    constexpr int TY = 256 / TX;     // 8
    constexpr int RM = TILE_M / TY;  // 8

    __shared__ float As[TILE_M][BK + 1];
    __shared__ float Ws[BK][N];
    __shared__ float redst[2][TY][N];

    const int tid = threadIdx.x;
    const int tx = tid % TX;
    const int ty = tid / TX;
    const int row0 = blockIdx.x * TILE_M;
    const int arow = tid >> 2;
    const int acol = (tid & 3) * 8;

    float acc[RM][4];
    #pragma unroll
    for (int r = 0; r < RM; ++r)
        #pragma unroll
        for (int c = 0; c < 4; ++c) acc[r][c] = 0.f;

    for (int k0 = 0; k0 < K; k0 += BK) {
        {
            const float4* p = (const float4*)&A[(size_t)(row0 + arow) * K + k0 + acol];
            float4 x0 = p[0], x1 = p[1];
            As[arow][acol + 0] = x0.x; As[arow][acol + 1] = x0.y;
            As[arow][acol + 2] = x0.z; As[arow][acol + 3] = x0.w;
            As[arow][acol + 4] = x1.x; As[arow][acol + 5] = x1.y;
            As[arow][acol + 6] = x1.z; As[arow][acol + 7] = x1.w;
        }
        #pragma unroll
        for (int i = 0; i < (BK * N) / 256; ++i) {
            int e = i * 256 + tid;
            Ws[e / N][e % N] = W[(size_t)(k0 + e / N) * N + e % N];
        }
        __syncthreads();
        #pragma unroll
        for (int kk = 0; kk < BK; ++kk) {
            float4 wv = *(const float4*)&Ws[kk][tx * 4];
            #pragma unroll
            for (int r = 0; r < RM; ++r) {
                float a = As[ty * RM + r][kk];
                acc[r][0] = fmaf(a, wv.x, acc[r][0]);
                acc[r][1] = fmaf(a, wv.y, acc[r][1]);
                acc[r][2] = fmaf(a, wv.z, acc[r][2]);
                acc[r][3] = fmaf(a, wv.w, acc[r][3]);
            }
        }
        __syncthreads();
    }
    float4 bv = *(const float4*)&bias[tx * 4];
    float s[4] = {0, 0, 0, 0}, q[4] = {0, 0, 0, 0};
    #pragma unroll
    for (int r = 0; r < RM; ++r) {
        float o[4];
        o[0] = acc[r][0] + bv.x; o[1] = acc[r][1] + bv.y;
        o[2] = acc[r][2] + bv.z; o[3] = acc[r][3] + bv.w;
        #pragma unroll
        for (int c = 0; c < 4; ++c) { s[c] += o[c]; q[c] = fmaf(o[c], o[c], q[c]); }
        size_t off = (size_t)(row0 + ty * RM + r) * N + tx * 4;
        uint2 ov;
        ov.x = pack2(o[0], o[1]);
        ov.y = pack2(o[2], o[3]);
        *(uint2*)&C[off] = ov;
    }
    #pragma unroll
    for (int c = 0; c < 4; ++c) {
        redst[0][ty][tx * 4 + c] = s[c];
        redst[1][ty][tx * 4 + c] = q[c];
    }
    __syncthreads();
    {
        int col = tid & (N - 1), qs = tid / N;
        float v = 0.f;
        #pragma unroll
        for (int t = 0; t < TY; ++t) v += redst[qs][t][col];
        (qs ? sqP : sumP)[(size_t)blockIdx.x * N + col] = v;
    }
}

// ---------------------------------------------------------------------------
// Tree-reduce block partials: P[NBLK][128] -> R2[col*64 + chunk] (64 chunks).
// ---------------------------------------------------------------------------
template<int NBLK>
__global__ __launch_bounds__(256) void reduce1_k(const float* __restrict__ sumP,
                                                 const float* __restrict__ sqP,
                                                 float* __restrict__ sumR2,
                                                 float* __restrict__ sqR2) {
    constexpr int ROWS = NBLK / 64;
    const int tid = threadIdx.x;
    const int qs = blockIdx.x & 1;
    const int chunk = blockIdx.x >> 1;
    const float* src = qs ? sqP : sumP;
    float* dst = qs ? sqR2 : sumR2;
    const int col = tid & 127;
    const int half = tid >> 7;
    float s = 0.f;
    for (int r = half; r < ROWS; r += 2)
        s += src[(size_t)(chunk * ROWS + r) * 128 + col];
    __shared__ float red[256];
    red[tid] = s;
    __syncthreads();
    if (tid < 128) dst[col * 64 + chunk] = red[tid] + red[tid + 128];
}

// Reduce 64 chunks; scale = g*rsqrt(var+eps); shift = be - mean*scale
__global__ void finalize_k(const float* __restrict__ sumR2, const float* __restrict__ sqR2,
                           const float* __restrict__ g, const float* __restrict__ be,
                           float* __restrict__ scale, float* __restrict__ shift) {
    const int f = threadIdx.x;  // 128
    const float4* ps = (const float4*)&sumR2[f * REP];
    const float4* pq = (const float4*)&sqR2[f * REP];
    float s = 0.f, q = 0.f;
    #pragma unroll
    for (int i = 0; i < REP / 4; ++i) {
        float4 a = ps[i]; s += (a.x + a.y) + (a.z + a.w);
        float4 b = pq[i]; q += (b.x + b.y) + (b.z + b.w);
    }
    const float invM = 1.f / (float)M_ROWS;
    float mean = s * invM;
    float var = q * invM - mean * mean;
    float sc = g[f] * rsqrtf(var + 1e-5f);
    scale[f] = sc;
    shift[f] = fmaf(-mean, sc, be[f]);
}

// fp32 W[K][N] -> bf16 WT[N][K] (tiny)
__global__ void transpose_w_k(const float* __restrict__ W, ushort_t* __restrict__ WT,
                              int K, int N) {
    int idx = blockIdx.x * 256 + threadIdx.x;
    if (idx < K * N) {
        int k = idx / N, n = idx % N;
        WT[(size_t)n * K + k] = f2b(W[idx]);
    }
}

// ---------------------------------------------------------------------------
// Chunked causal cummax, one block per (ba) sequence (T=256, 128 feats).
// ---------------------------------------------------------------------------
template<int INPLACE>
__global__ __launch_bounds__(512) void scan_k(const ushort_t* __restrict__ Y,
                                              const float* __restrict__ scale,
                                              const float* __restrict__ shift,
                                              ushort_t* __restrict__ P) {
    const int tid = threadIdx.x;
    const int fp = tid & 63;
    const int chunk = tid >> 6;
    const size_t base = (size_t)blockIdx.x * 256 * 128 + fp * 2;
    const float sc0 = scale[fp * 2], sh0 = shift[fp * 2];
    const float sc1 = scale[fp * 2 + 1], sh1 = shift[fp * 2 + 1];

    __shared__ float cmax[8][128];

    uint_t vals[32];
    float run0 = 0.f, run1 = 0.f;
    #pragma unroll
    for (int i = 0; i < 32; ++i) {
        size_t idx = base + (size_t)(chunk * 32 + i) * 128;
        uint_t u = *(const uint_t*)&Y[idx];
        float v0 = fmaxf(fmaf(b2f((ushort_t)(u & 0xffff)), sc0, sh0), 0.f);
        float v1 = fmaxf(fmaf(b2f((ushort_t)(u >> 16)), sc1, sh1), 0.f);
        run0 = fmaxf(run0, v0);
        run1 = fmaxf(run1, v1);
        vals[i] = pack2(v0, v1);
    }
    cmax[chunk][fp * 2] = run0;
    cmax[chunk][fp * 2 + 1] = run1;
    __syncthreads();
    float p0 = 0.f, p1 = 0.f;
    for (int c = 0; c < chunk; ++c) {
        p0 = fmaxf(p0, cmax[c][fp * 2]);
        p1 = fmaxf(p1, cmax[c][fp * 2 + 1]);
    }
    run0 = p0; run1 = p1;
    ushort_t* dst = INPLACE ? (ushort_t*)Y : P;
    #pragma unroll
    for (int i = 0; i < 32; ++i) {
        uint_t u = vals[i];
        run0 = fmaxf(run0, b2f((ushort_t)(u & 0xffff)));
        run1 = fmaxf(run1, b2f((ushort_t)(u >> 16)));
        *(uint_t*)&dst[base + (size_t)(chunk * 32 + i) * 128] = pack2(run0, run1);
    }
}

extern "C" void kernel_launch(void* const* d_in, const int* in_sizes, int n_in,
                              void* d_out, int out_size, void* d_ws, size_t ws_size,
                              hipStream_t stream) {
    const float* poly = (const float*)d_in[0];
    const float* W0 = (const float*)d_in[1];
    const float* b0 = (const float*)d_in[2];
    const float* g0 = (const float*)d_in[3];
    const float* be0 = (const float*)d_in[4];
    const float* W1 = (const float*)d_in[5];
    const float* b1 = (const float*)d_in[6];
    const float* g1 = (const float*)d_in[7];
    const float* be1 = (const float*)d_in[8];
    const float* W2 = (const float*)d_in[9];
    const float* b2 = (const float*)d_in[10];
    const float* g2 = (const float*)d_in[11];
    const float* be2 = (const float*)d_in[12];
    const float* W3 = (const float*)d_in[13];
    const float* b3 = (const float*)d_in[14];
    const float* g3 = (const float*)d_in[15];
    const float* be3 = (const float*)d_in[16];
    const float* W4 = (const float*)d_in[17];
    const float* b4 = (const float*)d_in[18];
    float* out = (float*)d_out;

    float* st = (float*)d_ws;
    float* sumP = st;
    float* sqP = st + 524288;
    float* sumR2 = st + 1048576;
    float* sqR2 = sumR2 + 8192;
    float* scsh = st + 1064960;
    auto scP = [&](int i) { return scsh + i * 256; };
    auto shP = [&](int i) { return scsh + i * 256 + 128; };
    ushort_t* wt1 = (ushort_t*)((char*)d_ws + 4263936);         // 128 x 256
    ushort_t* wt2 = wt1 + 128 * 256;                            // 128 x 128
    ushort_t* wt3 = wt2 + 128 * 128;                            // 128 x 128
    ushort_t* wt4 = wt3 + 128 * 128;                            // 64 x 128
    ushort_t* h0 = (ushort_t*)((char*)d_ws + 4263936 + 147456);
    ushort_t* h1 = h0 + (size_t)M_ROWS * 128;

    const int G64 = M_ROWS / TILE_M;    // 4096 (L0, L1)
    const int GP = M_ROWS / (64 * 4);   // 1024 (persistent gemm3, RPT=4)
    const int GBA = 1024;               // one block per (b,a) sequence

    transpose_w_k<<<128, 256, 0, stream>>>(W1, wt1, 256, 128);
    transpose_w_k<<<64, 256, 0, stream>>>(W2, wt2, 128, 128);
    transpose_w_k<<<64, 256, 0, stream>>>(W3, wt3, 128, 128);
    transpose_w_k<<<32, 256, 0, stream>>>(W4, wt4, 128, 64);

    // Layer 0 (fp32 precision): y0 = poly @ W0 + b0 -> h0 (raw bf16) + partials
    gemm_f32_k<32, 128><<<G64, 256, 0, stream>>>(poly, W0, b0, h0, sumP, sqP);
    reduce1_k<4096><<<128, 256, 0, stream>>>(sumP, sqP, sumR2, sqR2);
    finalize_k<<<1, 128, 0, stream>>>(sumR2, sqR2, g0, be0, scP(0), shP(0));

    // P = cummax(bnrelu0(y0)) -> h1 ; h0 stays RAW y0
    scan_k<0><<<GBA, 512, 0, stream>>>(h0, scP(0), shP(0), h1);

    // Layer 1: y1 = [bnrelu0(y0), P] @ W1 + b1 -> h0 (in place), MODE3
    mfma_gemm2_k<2, 128, 3, 1, ushort_t><<<G64, 256, 0, stream>>>(
        h0, h1, wt1, b1, scP(0), shP(0), h0, sumP, sqP);
    reduce1_k<4096><<<128, 256, 0, stream>>>(sumP, sqP, sumR2, sqR2);
    finalize_k<<<1, 128, 0, stream>>>(sumR2, sqR2, g1, be1, scP(1), shP(1));

    // Layer 2: y2 = bnrelu1(y1) @ W2 + b2 -> h0 (in place), persistent pipeline
    mfma_gemm3_k<128, 1, 1, 4, ushort_t><<<GP, 256, 0, stream>>>(
        h0, wt2, b2, scP(1), shP(1), h0, sumP, sqP);
    reduce1_k<1024><<<128, 256, 0, stream>>>(sumP, sqP, sumR2, sqR2);
    finalize_k<<<1, 128, 0, stream>>>(sumR2, sqR2, g2, be2, scP(2), shP(2));

    // pooled = cummax(bnrelu2(y2)) in place in h0
    scan_k<1><<<GBA, 512, 0, stream>>>(h0, scP(2), shP(2), nullptr);

    // Layer 3: y3 = pooled @ W3 + b3 -> h0 (in place), persistent pipeline
    mfma_gemm3_k<128, 0, 1, 4, ushort_t><<<GP, 256, 0, stream>>>(
        h0, wt3, b3, nullptr, nullptr, h0, sumP, sqP);
    reduce1_k<1024><<<128, 256, 0, stream>>>(sumP, sqP, sumR2, sqR2);
    finalize_k<<<1, 128, 0, stream>>>(sumR2, sqR2, g3, be3, scP(3), shP(3));

    // Layer 4: out = bnrelu3(y3) @ W4 + b4 -> d_out (fp32), persistent pipeline
    mfma_gemm3_k<64, 1, 0, 4, float><<<GP, 256, 0, stream>>>(
        h0, wt4, b4, scP(3), shP(3), out, nullptr, nullptr);
}

// Round 10
// 375.859 us; speedup vs baseline: 2.4105x; 1.0230x over previous
//
#include <hip/hip_runtime.h>
#include <hip/hip_bf16.h>

// Problem constants (fixed by setup_inputs)
#define M_ROWS 262144   // B*A*T = 16*64*256
#define TILE_M 64
#define BK 32
#define REP 64          // second-level stats partials (matches finalize_k layout)

typedef unsigned short ushort_t;
typedef unsigned int uint_t;
typedef __attribute__((ext_vector_type(8))) short short8_t;   // 8 bf16 = 4 VGPRs
typedef __attribute__((ext_vector_type(4))) float float4_t;   // MFMA acc

// bf16 (stored as ushort) <-> fp32 helpers. Load is exact; store is RNE.
__device__ __forceinline__ float b2f(ushort_t u) {
    union { uint_t i; float f; } c; c.i = ((uint_t)u) << 16; return c.f;
}
__device__ __forceinline__ ushort_t f2b(float f) {
    union { float f; uint_t i; } c; c.f = f;
    uint_t u = c.i;
    return (ushort_t)((u + 0x7fffu + ((u >> 16) & 1u)) >> 16);
}
// packed 2xfp32 -> 2xbf16 (v_cvt_pk_bf16_f32 on gfx950, RNE)
__device__ __forceinline__ uint_t pack2(float a, float b) {
    union { __hip_bfloat162 h; uint_t u; } c;
    c.h = __float22bfloat162_rn(make_float2(a, b));
    return c.u;
}

// async global->LDS DMA, 16 B per lane; data lands at ldsbase + lane*16
__device__ __forceinline__ void gld_lds16(const ushort_t* g, ushort_t* l) {
    __builtin_amdgcn_global_load_lds((const __attribute__((address_space(1))) void*)g,
                                     (__attribute__((address_space(3))) void*)l, 16, 0, 0);
}

// ---------------------------------------------------------------------------
// Layer-1 pipelined persistent GEMM: C = [bnrelu0(X), P] @ W1 + b1 (K=256).
// Grid 512 x RPT=8 row-tiles. B (128x256, 64 KB) resident, staged once.
// A double-buffered over (tile, kt) steps: DMA for step s+1 issues right after
// the step-s barrier, overlapping that step's MFMA. Dedicated 16 KB epilogue
// buffer (swizzled transpose -> 16 B coalesced stores). Act on kt=0 frags.
// Stats accumulate in regs across tiles; one flush per block (no atomics).
// In-place safe (C==X): tile stores happen after its reads; prefetch reads
// disjoint rows owned by this block only.
// ---------------------------------------------------------------------------
template<int RPT>
__launch_bounds__(256)
__global__ void gemm1p_k(const ushort_t* __restrict__ X, const ushort_t* __restrict__ P,
                         const ushort_t* __restrict__ WT, const float* __restrict__ bias,
                         const float* __restrict__ scale, const float* __restrict__ shift,
                         ushort_t* __restrict__ C, float* __restrict__ sumP, float* __restrict__ sqP) {
    __shared__ __attribute__((aligned(16))) ushort_t Bs[128 * 256];      // 64 KB
    __shared__ __attribute__((aligned(16))) ushort_t Abuf[2][64 * 128];  // 2x16 KB
    __shared__ __attribute__((aligned(16))) ushort_t Epi[64 * 128];      // 16 KB
    __shared__ float sred[4 * 128 * 2];
    __shared__ float s_sc[128], s_sh[128];

    const int tid = threadIdx.x;
    const int lane = tid & 63;
    const int wave = tid >> 6;
    const int wm = wave & 1, wn = wave >> 1;
    const int quad = lane >> 4, l16 = lane & 15;
    const int srow = lane >> 4, sp16 = lane & 15;   // A staging
    const int brow = lane >> 5, bs32 = lane & 31;   // B staging (512 B rows)
    const int row0 = blockIdx.x * (RPT * 64);

    if (tid < 128) { s_sc[tid] = scale[tid]; s_sh[tid] = shift[tid]; }

    // ---- stage B once (128 rows x 512 B), half-preserving XOR swizzle ----
    #pragma unroll
    for (int i = 0; i < 16; ++i) {
        int t = i * 4 + wave;            // 1 KB chunk id: rows 2t, 2t+1
        int r = t * 2 + brow;
        int sp = (bs32 & 16) | ((bs32 ^ r) & 15);
        gld_lds16(WT + (size_t)r * 256 + sp * 8, Bs + t * 512);
    }

    auto stageA = [&](int it, int kt, int buf) {
        const ushort_t* src0 = kt ? P : X;
        int r0 = row0 + it * 64;
        #pragma unroll
        for (int i = 0; i < 4; ++i) {
            int t = i * 4 + wave;
            int r = t * 4 + srow;
            int sp = sp16 ^ (r & 15);
            gld_lds16(src0 + (size_t)(r0 + r) * 128 + sp * 8, Abuf[buf] + t * 512);
        }
    };
    stageA(0, 0, 0);

    float bvs[4];
    #pragma unroll
    for (int nt = 0; nt < 4; ++nt) bvs[nt] = bias[wn * 64 + nt * 16 + l16];
    float sSum[4] = {0.f, 0.f, 0.f, 0.f}, sSq[4] = {0.f, 0.f, 0.f, 0.f};

    int step = 0;
    for (int it = 0; it < RPT; ++it) {
        float4_t acc[2][4];
        #pragma unroll
        for (int mt = 0; mt < 2; ++mt)
            #pragma unroll
            for (int nt = 0; nt < 4; ++nt) acc[mt][nt] = (float4_t)0.f;

        #pragma unroll
        for (int kt = 0; kt < 2; ++kt) {
            __syncthreads();   // Abuf[step&1] (+Bs on step 0) resident; prior Epi reads done
            if (step + 1 < 2 * RPT) {
                int ns = step + 1;
                stageA(ns >> 1, ns & 1, ns & 1);
            }
            const ushort_t* As = Abuf[step & 1];
            #pragma unroll
            for (int kk = 0; kk < 4; ++kk) {
                int j = kk * 4 + quad;
                short8_t a0 = *(const short8_t*)&As[(wm * 32 + l16) * 128 + ((j ^ l16) * 8)];
                short8_t a1 = *(const short8_t*)&As[(wm * 32 + 16 + l16) * 128 + ((j ^ l16) * 8)];
                if (kt == 0) {   // bnrelu0 on X fragments
                    int kb = kk * 32 + quad * 8;
                    float4 c0 = *(const float4*)&s_sc[kb], c1 = *(const float4*)&s_sc[kb + 4];
                    float4 h0 = *(const float4*)&s_sh[kb], h1 = *(const float4*)&s_sh[kb + 4];
                    #pragma unroll
                    for (int z = 0; z < 2; ++z) {
                        ushort_t u[8];
                        *(short8_t*)u = z ? a1 : a0;
                        uint_t w[4];
                        w[0] = pack2(fmaxf(fmaf(b2f(u[0]), c0.x, h0.x), 0.f),
                                     fmaxf(fmaf(b2f(u[1]), c0.y, h0.y), 0.f));
                        w[1] = pack2(fmaxf(fmaf(b2f(u[2]), c0.z, h0.z), 0.f),
                                     fmaxf(fmaf(b2f(u[3]), c0.w, h0.w), 0.f));
                        w[2] = pack2(fmaxf(fmaf(b2f(u[4]), c1.x, h1.x), 0.f),
                                     fmaxf(fmaf(b2f(u[5]), c1.y, h1.y), 0.f));
                        w[3] = pack2(fmaxf(fmaf(b2f(u[6]), c1.z, h1.z), 0.f),
                                     fmaxf(fmaf(b2f(u[7]), c1.w, h1.w), 0.f));
                        short8_t rr;
                        *(uint4*)&rr = *(const uint4*)w;
                        if (z) a1 = rr; else a0 = rr;
                    }
                }
                #pragma unroll
                for (int nt = 0; nt < 4; ++nt) {
                    int br = wn * 64 + nt * 16 + l16;
                    short8_t bf = *(const short8_t*)&Bs[br * 256 + kt * 128 + ((j ^ l16) * 8)];
                    acc[0][nt] = __builtin_amdgcn_mfma_f32_16x16x32_bf16(a0, bf, acc[0][nt], 0, 0, 0);
                    acc[1][nt] = __builtin_amdgcn_mfma_f32_16x16x32_bf16(a1, bf, acc[1][nt], 0, 0, 0);
                }
            }
            ++step;
        }

        // ---- bias + stats accumulate ----
        #pragma unroll
        for (int mt = 0; mt < 2; ++mt)
            #pragma unroll
            for (int nt = 0; nt < 4; ++nt)
                #pragma unroll
                for (int r = 0; r < 4; ++r) {
                    float v = acc[mt][nt][r] + bvs[nt];
                    acc[mt][nt][r] = v;
                    sSum[nt] += v; sSq[nt] = fmaf(v, v, sSq[nt]);
                }
        if (it == RPT - 1) {
            #pragma unroll
            for (int nt = 0; nt < 4; ++nt) {
                float s = sSum[nt], q = sSq[nt];
                s += __shfl_xor(s, 16); q += __shfl_xor(q, 16);
                s += __shfl_xor(s, 32); q += __shfl_xor(q, 32);
                if (lane < 16) {
                    int col = wn * 64 + nt * 16 + l16;
                    sred[(wave * 128 + col) * 2 + 0] = s;
                    sred[(wave * 128 + col) * 2 + 1] = q;
                }
            }
        }

        // ---- swizzled transpose into Epi ----
        char* eb = (char*)Epi;
        #pragma unroll
        for (int mt = 0; mt < 2; ++mt)
            #pragma unroll
            for (int nt = 0; nt < 4; ++nt) {
                int col = wn * 64 + nt * 16 + l16;
                int bc = col * 2;
                #pragma unroll
                for (int r = 0; r < 4; ++r) {
                    int row = wm * 32 + mt * 16 + quad * 4 + r;
                    int addr = row * 256 + ((((bc >> 4) ^ (row & 15)) << 4) | (bc & 15));
                    *(ushort_t*)(eb + addr) = f2b(acc[mt][nt][r]);
                }
            }
        __syncthreads();
        if (it == RPT - 1) {
            int col = tid & 127, qs = tid >> 7;
            int wb = (col >> 6) * 2;
            float v = sred[(wb * 128 + col) * 2 + qs] + sred[((wb + 1) * 128 + col) * 2 + qs];
            (qs ? sqP : sumP)[(size_t)blockIdx.x * 128 + col] = v;
        }
        // ---- coalesced 16 B stores ----
        int r0s = row0 + it * 64;
        #pragma unroll
        for (int p = 0; p < 4; ++p) {
            int s = p * 256 + tid;
            int row = s >> 4, g = s & 15;
            uint4 v = *(const uint4*)(eb + row * 256 + ((g ^ (row & 15)) << 4));
            *(uint4*)((char*)(C + (size_t)(r0s + row) * 128) + g * 16) = v;
        }
    }
}

// ---------------------------------------------------------------------------
// Persistent pipelined MFMA GEMM for K=128 layers: C = act(A)@W + bias.
// ---------------------------------------------------------------------------
template<int N, int MODE, int STATS, int RPT, typename CT>
__launch_bounds__(256)
__global__ void mfma_gemm3_k(const ushort_t* __restrict__ A, const ushort_t* __restrict__ WT,
                             const float* __restrict__ bias,
                             const float* __restrict__ scale, const float* __restrict__ shift,
                             CT* __restrict__ C, float* __restrict__ sumP, float* __restrict__ sqP) {
    constexpr int WN = N / 2;        // cols per wave-column (64 or 32)
    constexpr int NT = WN / 16;      // 4 (N=128) or 2 (N=64)

    __shared__ __attribute__((aligned(16))) ushort_t Bs[N * 128];
    __shared__ __attribute__((aligned(16))) ushort_t Abuf[2][64 * 128];
    __shared__ float sred[STATS ? 4 * N * 2 : 1];
    __shared__ float s_sc[MODE == 1 ? 128 : 1];
    __shared__ float s_sh[MODE == 1 ? 128 : 1];

    const int tid = threadIdx.x;
    const int lane = tid & 63;
    const int wave = tid >> 6;
    const int wm = wave & 1;
    const int wn = wave >> 1;
    const int quad = lane >> 4;
    const int l16 = lane & 15;
    const int srow = lane >> 4;
    const int sp16 = lane & 15;

    if (MODE == 1 && tid < 128) { s_sc[tid] = scale[tid]; s_sh[tid] = shift[tid]; }

    #pragma unroll
    for (int i = 0; i < N / 16; ++i) {
        int t = i * 4 + wave;
        int r = t * 4 + srow;
        int sp = sp16 ^ (r & 15);
        gld_lds16(WT + (size_t)r * 128 + sp * 8, Bs + t * 512);
    }
    {
        int r0 = blockIdx.x * (RPT * 64);
        #pragma unroll
        for (int i = 0; i < 4; ++i) {
            int t = i * 4 + wave;
            int r = t * 4 + srow;
            int sp = sp16 ^ (r & 15);
            gld_lds16(A + (size_t)(r0 + r) * 128 + sp * 8, Abuf[0] + t * 512);
        }
    }

    float bvs[NT];
    #pragma unroll
    for (int nt = 0; nt < NT; ++nt) bvs[nt] = bias[wn * WN + nt * 16 + l16];
    float sSum[STATS ? NT : 1] = {0.f}, sSq[STATS ? NT : 1] = {0.f};

    for (int it = 0; it < RPT; ++it) {
        __syncthreads();
        if (it + 1 < RPT) {
            int r0 = blockIdx.x * (RPT * 64) + (it + 1) * 64;
            #pragma unroll
            for (int i = 0; i < 4; ++i) {
                int t = i * 4 + wave;
                int r = t * 4 + srow;
                int sp = sp16 ^ (r & 15);
                gld_lds16(A + (size_t)(r0 + r) * 128 + sp * 8, Abuf[(it + 1) & 1] + t * 512);
            }
        }
        const ushort_t* As = Abuf[it & 1];

        float4_t acc[2][NT];
        #pragma unroll
        for (int mt = 0; mt < 2; ++mt)
            #pragma unroll
            for (int nt = 0; nt < NT; ++nt) acc[mt][nt] = (float4_t)0.f;

        #pragma unroll
        for (int kk = 0; kk < 4; ++kk) {
            int j = kk * 4 + quad;
            short8_t a0 = *(const short8_t*)&As[(wm * 32 + l16) * 128 + ((j ^ l16) * 8)];
            short8_t a1 = *(const short8_t*)&As[(wm * 32 + 16 + l16) * 128 + ((j ^ l16) * 8)];
            if (MODE == 1) {
                int kb = kk * 32 + quad * 8;
                float4 c0 = *(const float4*)&s_sc[kb], c1 = *(const float4*)&s_sc[kb + 4];
                float4 h0 = *(const float4*)&s_sh[kb], h1 = *(const float4*)&s_sh[kb + 4];
                #pragma unroll
                for (int z = 0; z < 2; ++z) {
                    ushort_t u[8];
                    *(short8_t*)u = z ? a1 : a0;
                    uint_t w[4];
                    w[0] = pack2(fmaxf(fmaf(b2f(u[0]), c0.x, h0.x), 0.f),
                                 fmaxf(fmaf(b2f(u[1]), c0.y, h0.y), 0.f));
                    w[1] = pack2(fmaxf(fmaf(b2f(u[2]), c0.z, h0.z), 0.f),
                                 fmaxf(fmaf(b2f(u[3]), c0.w, h0.w), 0.f));
                    w[2] = pack2(fmaxf(fmaf(b2f(u[4]), c1.x, h1.x), 0.f),
                                 fmaxf(fmaf(b2f(u[5]), c1.y, h1.y), 0.f));
                    w[3] = pack2(fmaxf(fmaf(b2f(u[6]), c1.z, h1.z), 0.f),
                                 fmaxf(fmaf(b2f(u[7]), c1.w, h1.w), 0.f));
                    short8_t rr;
                    *(uint4*)&rr = *(const uint4*)w;
                    if (z) a1 = rr; else a0 = rr;
                }
            }
            #pragma unroll
            for (int nt = 0; nt < NT; ++nt) {
                short8_t bf = *(const short8_t*)&Bs[(wn * WN + nt * 16 + l16) * 128 + ((j ^ l16) * 8)];
                acc[0][nt] = __builtin_amdgcn_mfma_f32_16x16x32_bf16(a0, bf, acc[0][nt], 0, 0, 0);
                acc[1][nt] = __builtin_amdgcn_mfma_f32_16x16x32_bf16(a1, bf, acc[1][nt], 0, 0, 0);
            }
        }

        #pragma unroll
        for (int mt = 0; mt < 2; ++mt)
            #pragma unroll
            for (int nt = 0; nt < NT; ++nt)
                #pragma unroll
                for (int r = 0; r < 4; ++r) {
                    float v = acc[mt][nt][r] + bvs[nt];
                    acc[mt][nt][r] = v;
                    if (STATS) { sSum[nt] += v; sSq[nt] = fmaf(v, v, sSq[nt]); }
                }
        if (STATS && it == RPT - 1) {
            #pragma unroll
            for (int nt = 0; nt < NT; ++nt) {
                float s = sSum[nt], q = sSq[nt];
                s += __shfl_xor(s, 16); q += __shfl_xor(q, 16);
                s += __shfl_xor(s, 32); q += __shfl_xor(q, 32);
                if (lane < 16) {
                    int col = wn * WN + nt * 16 + l16;
                    sred[(wave * N + col) * 2 + 0] = s;
                    sred[(wave * N + col) * 2 + 1] = q;
                }
            }
        }
        __syncthreads();

        char* eb = (char*)Abuf[it & 1];
        #pragma unroll
        for (int mt = 0; mt < 2; ++mt)
            #pragma unroll
            for (int nt = 0; nt < NT; ++nt) {
                int col = wn * WN + nt * 16 + l16;
                int bc = col * (int)sizeof(CT);
                #pragma unroll
                for (int r = 0; r < 4; ++r) {
                    int row = wm * 32 + mt * 16 + quad * 4 + r;
                    int addr = row * 256 + ((((bc >> 4) ^ (row & 15)) << 4) | (bc & 15));
                    if constexpr (sizeof(CT) == 4) *(float*)(eb + addr) = acc[mt][nt][r];
                    else                           *(ushort_t*)(eb + addr) = f2b(acc[mt][nt][r]);
                }
            }
        if (STATS && it == RPT - 1) {
            int col = tid & (N - 1), qs = tid / N;
            int wb = (col / WN) * 2;
            float v = sred[(wb * N + col) * 2 + qs] + sred[((wb + 1) * N + col) * 2 + qs];
            (qs ? sqP : sumP)[(size_t)blockIdx.x * N + col] = v;
        }
        __syncthreads();

        int r0 = blockIdx.x * (RPT * 64) + it * 64;
        #pragma unroll
        for (int p = 0; p < 4; ++p) {
            int s = p * 256 + tid;
            int row = s >> 4, g = s & 15;
            uint4 v = *(const uint4*)(eb + row * 256 + ((g ^ (row & 15)) << 4));
            *(uint4*)((char*)(C + (size_t)(r0 + row) * N) + g * 16) = v;
        }
    }
}

// ---------------------------------------------------------------------------
// fp32 vector GEMM (layer 0: K=32, fp32 input) with fused stats partials.
// ---------------------------------------------------------------------------
template<int K, int N>
__launch_bounds__(256)
__global__ void gemm_f32_k(const float* __restrict__ A, const float* __restrict__ W,
                           const float* __restrict__ bias, ushort_t* __restrict__ C,
                           float* __restrict__ sumP, float* __restrict__ sqP) {
    constexpr int TX = N / 4;        // 32
    constexpr int TY = 256 / TX;     // 8
    constexpr int RM = TILE_M / TY;  // 8

    __shared__ float As[TILE_M][BK + 1];
    __shared__ float Ws[BK][N];
    __shared__ float redst[2][TY][N];

    const int tid = threadIdx.x;
    const int tx = tid % TX;
    const int ty = tid / TX;
    const int row0 = blockIdx.x * TILE_M;
    const int arow = tid >> 2;
    const int acol = (tid & 3) * 8;

    float acc[RM][4];
    #pragma unroll
    for (int r = 0; r < RM; ++r)
        #pragma unroll
        for (int c = 0; c < 4; ++c) acc[r][c] = 0.f;

    for (int k0 = 0; k0 < K; k0 += BK) {
        {
            const float4* p = (const float4*)&A[(size_t)(row0 + arow) * K + k0 + acol];
            float4 x0 = p[0], x1 = p[1];
            As[arow][acol + 0] = x0.x; As[arow][acol + 1] = x0.y;
            As[arow][acol + 2] = x0.z; As[arow][acol + 3] = x0.w;
            As[arow][acol + 4] = x1.x; As[arow][acol + 5] = x1.y;
            As[arow][acol + 6] = x1.z; As[arow][acol + 7] = x1.w;
        }
        #pragma unroll
        for (int i = 0; i < (BK * N) / 256; ++i) {
            int e = i * 256 + tid;
            Ws[e / N][e % N] = W[(size_t)(k0 + e / N) * N + e % N];
        }
        __syncthreads();
        #pragma unroll
        for (int kk = 0; kk < BK; ++kk) {
            float4 wv = *(const float4*)&Ws[kk][tx * 4];
            #pragma unroll
            for (int r = 0; r < RM; ++r) {
                float a = As[ty * RM + r][kk];
                acc[r][0] = fmaf(a, wv.x, acc[r][0]);
                acc[r][1] = fmaf(a, wv.y, acc[r][1]);
                acc[r][2] = fmaf(a, wv.z, acc[r][2]);
                acc[r][3] = fmaf(a, wv.w, acc[r][3]);
            }
        }
        __syncthreads();
    }
    float4 bv = *(const float4*)&bias[tx * 4];
    float s[4] = {0, 0, 0, 0}, q[4] = {0, 0, 0, 0};
    #pragma unroll
    for (int r = 0; r < RM; ++r) {
        float o[4];
        o[0] = acc[r][0] + bv.x; o[1] = acc[r][1] + bv.y;
        o[2] = acc[r][2] + bv.z; o[3] = acc[r][3] + bv.w;
        #pragma unroll
        for (int c = 0; c < 4; ++c) { s[c] += o[c]; q[c] = fmaf(o[c], o[c], q[c]); }
        size_t off = (size_t)(row0 + ty * RM + r) * N + tx * 4;
        uint2 ov;
        ov.x = pack2(o[0], o[1]);
        ov.y = pack2(o[2], o[3]);
        *(uint2*)&C[off] = ov;
    }
    #pragma unroll
    for (int c = 0; c < 4; ++c) {
        redst[0][ty][tx * 4 + c] = s[c];
        redst[1][ty][tx * 4 + c] = q[c];
    }
    __syncthreads();
    {
        int col = tid & (N - 1), qs = tid / N;
        float v = 0.f;
        #pragma unroll
        for (int t = 0; t < TY; ++t) v += redst[qs][t][col];
        (qs ? sqP : sumP)[(size_t)blockIdx.x * N + col] = v;
    }
}

// ---------------------------------------------------------------------------
// Tree-reduce block partials: P[NBLK][128] -> R2[col*64 + chunk] (64 chunks).
// ---------------------------------------------------------------------------
template<int NBLK>
__global__ __launch_bounds__(256) void reduce1_k(const float* __restrict__ sumP,
                                                 const float* __restrict__ sqP,
                                                 float* __restrict__ sumR2,
                                                 float* __restrict__ sqR2) {
    constexpr int ROWS = NBLK / 64;
    const int tid = threadIdx.x;
    const int qs = blockIdx.x & 1;
    const int chunk = blockIdx.x >> 1;
    const float* src = qs ? sqP : sumP;
    float* dst = qs ? sqR2 : sumR2;
    const int col = tid & 127;
    const int half = tid >> 7;
    float s = 0.f;
    for (int r = half; r < ROWS; r += 2)
        s += src[(size_t)(chunk * ROWS + r) * 128 + col];
    __shared__ float red[256];
    red[tid] = s;
    __syncthreads();
    if (tid < 128) dst[col * 64 + chunk] = red[tid] + red[tid + 128];
}

// Reduce 64 chunks; scale = g*rsqrt(var+eps); shift = be - mean*scale
__global__ void finalize_k(const float* __restrict__ sumR2, const float* __restrict__ sqR2,
                           const float* __restrict__ g, const float* __restrict__ be,
                           float* __restrict__ scale, float* __restrict__ shift) {
    const int f = threadIdx.x;  // 128
    const float4* ps = (const float4*)&sumR2[f * REP];
    const float4* pq = (const float4*)&sqR2[f * REP];
    float s = 0.f, q = 0.f;
    #pragma unroll
    for (int i = 0; i < REP / 4; ++i) {
        float4 a = ps[i]; s += (a.x + a.y) + (a.z + a.w);
        float4 b = pq[i]; q += (b.x + b.y) + (b.z + b.w);
    }
    const float invM = 1.f / (float)M_ROWS;
    float mean = s * invM;
    float var = q * invM - mean * mean;
    float sc = g[f] * rsqrtf(var + 1e-5f);
    scale[f] = sc;
    shift[f] = fmaf(-mean, sc, be[f]);
}

// fp32 W[K][N] -> bf16 WT[N][K] (tiny)
__global__ void transpose_w_k(const float* __restrict__ W, ushort_t* __restrict__ WT,
                              int K, int N) {
    int idx = blockIdx.x * 256 + threadIdx.x;
    if (idx < K * N) {
        int k = idx / N, n = idx % N;
        WT[(size_t)n * K + k] = f2b(W[idx]);
    }
}

// ---------------------------------------------------------------------------
// Chunked causal cummax, one block per (ba) sequence (T=256, 128 feats).
// ---------------------------------------------------------------------------
template<int INPLACE>
__global__ __launch_bounds__(512) void scan_k(const ushort_t* __restrict__ Y,
                                              const float* __restrict__ scale,
                                              const float* __restrict__ shift,
                                              ushort_t* __restrict__ P) {
    const int tid = threadIdx.x;
    const int fp = tid & 63;
    const int chunk = tid >> 6;
    const size_t base = (size_t)blockIdx.x * 256 * 128 + fp * 2;
    const float sc0 = scale[fp * 2], sh0 = shift[fp * 2];
    const float sc1 = scale[fp * 2 + 1], sh1 = shift[fp * 2 + 1];

    __shared__ float cmax[8][128];

    uint_t vals[32];
    float run0 = 0.f, run1 = 0.f;
    #pragma unroll
    for (int i = 0; i < 32; ++i) {
        size_t idx = base + (size_t)(chunk * 32 + i) * 128;
        uint_t u = *(const uint_t*)&Y[idx];
        float v0 = fmaxf(fmaf(b2f((ushort_t)(u & 0xffff)), sc0, sh0), 0.f);
        float v1 = fmaxf(fmaf(b2f((ushort_t)(u >> 16)), sc1, sh1), 0.f);
        run0 = fmaxf(run0, v0);
        run1 = fmaxf(run1, v1);
        vals[i] = pack2(v0, v1);
    }
    cmax[chunk][fp * 2] = run0;
    cmax[chunk][fp * 2 + 1] = run1;
    __syncthreads();
    float p0 = 0.f, p1 = 0.f;
    for (int c = 0; c < chunk; ++c) {
        p0 = fmaxf(p0, cmax[c][fp * 2]);
        p1 = fmaxf(p1, cmax[c][fp * 2 + 1]);
    }
    run0 = p0; run1 = p1;
    ushort_t* dst = INPLACE ? (ushort_t*)Y : P;
    #pragma unroll
    for (int i = 0; i < 32; ++i) {
        uint_t u = vals[i];
        run0 = fmaxf(run0, b2f((ushort_t)(u & 0xffff)));
        run1 = fmaxf(run1, b2f((ushort_t)(u >> 16)));
        *(uint_t*)&dst[base + (size_t)(chunk * 32 + i) * 128] = pack2(run0, run1);
    }
}

extern "C" void kernel_launch(void* const* d_in, const int* in_sizes, int n_in,
                              void* d_out, int out_size, void* d_ws, size_t ws_size,
                              hipStream_t stream) {
    const float* poly = (const float*)d_in[0];
    const float* W0 = (const float*)d_in[1];
    const float* b0 = (const float*)d_in[2];
    const float* g0 = (const float*)d_in[3];
    const float* be0 = (const float*)d_in[4];
    const float* W1 = (const float*)d_in[5];
    const float* b1 = (const float*)d_in[6];
    const float* g1 = (const float*)d_in[7];
    const float* be1 = (const float*)d_in[8];
    const float* W2 = (const float*)d_in[9];
    const float* b2 = (const float*)d_in[10];
    const float* g2 = (const float*)d_in[11];
    const float* be2 = (const float*)d_in[12];
    const float* W3 = (const float*)d_in[13];
    const float* b3 = (const float*)d_in[14];
    const float* g3 = (const float*)d_in[15];
    const float* be3 = (const float*)d_in[16];
    const float* W4 = (const float*)d_in[17];
    const float* b4 = (const float*)d_in[18];
    float* out = (float*)d_out;

    float* st = (float*)d_ws;
    float* sumP = st;
    float* sqP = st + 524288;
    float* sumR2 = st + 1048576;
    float* sqR2 = sumR2 + 8192;
    float* scsh = st + 1064960;
    auto scP = [&](int i) { return scsh + i * 256; };
    auto shP = [&](int i) { return scsh + i * 256 + 128; };
    ushort_t* wt1 = (ushort_t*)((char*)d_ws + 4263936);         // 128 x 256
    ushort_t* wt2 = wt1 + 128 * 256;                            // 128 x 128
    ushort_t* wt3 = wt2 + 128 * 128;                            // 128 x 128
    ushort_t* wt4 = wt3 + 128 * 128;                            // 64 x 128
    ushort_t* h0 = (ushort_t*)((char*)d_ws + 4263936 + 147456);
    ushort_t* h1 = h0 + (size_t)M_ROWS * 128;

    const int G64 = M_ROWS / TILE_M;    // 4096 (L0)
    const int GP = M_ROWS / (64 * 8);   // 512 (persistent kernels, RPT=8)
    const int GBA = 1024;               // one block per (b,a) sequence

    transpose_w_k<<<128, 256, 0, stream>>>(W1, wt1, 256, 128);
    transpose_w_k<<<64, 256, 0, stream>>>(W2, wt2, 128, 128);
    transpose_w_k<<<64, 256, 0, stream>>>(W3, wt3, 128, 128);
    transpose_w_k<<<32, 256, 0, stream>>>(W4, wt4, 128, 64);

    // Layer 0 (fp32 precision): y0 = poly @ W0 + b0 -> h0 (raw bf16) + partials
    gemm_f32_k<32, 128><<<G64, 256, 0, stream>>>(poly, W0, b0, h0, sumP, sqP);
    reduce1_k<4096><<<128, 256, 0, stream>>>(sumP, sqP, sumR2, sqR2);
    finalize_k<<<1, 128, 0, stream>>>(sumR2, sqR2, g0, be0, scP(0), shP(0));

    // P = cummax(bnrelu0(y0)) -> h1 ; h0 stays RAW y0
    scan_k<0><<<GBA, 512, 0, stream>>>(h0, scP(0), shP(0), h1);

    // Layer 1: y1 = [bnrelu0(y0), P] @ W1 + b1 -> h0 (in place), pipelined
    gemm1p_k<8><<<GP, 256, 0, stream>>>(h0, h1, wt1, b1, scP(0), shP(0), h0, sumP, sqP);
    reduce1_k<512><<<128, 256, 0, stream>>>(sumP, sqP, sumR2, sqR2);
    finalize_k<<<1, 128, 0, stream>>>(sumR2, sqR2, g1, be1, scP(1), shP(1));

    // Layer 2: y2 = bnrelu1(y1) @ W2 + b2 -> h0 (in place), persistent pipeline
    mfma_gemm3_k<128, 1, 1, 8, ushort_t><<<GP, 256, 0, stream>>>(
        h0, wt2, b2, scP(1), shP(1), h0, sumP, sqP);
    reduce1_k<512><<<128, 256, 0, stream>>>(sumP, sqP, sumR2, sqR2);
    finalize_k<<<1, 128, 0, stream>>>(sumR2, sqR2, g2, be2, scP(2), shP(2));

    // pooled = cummax(bnrelu2(y2)) in place in h0
    scan_k<1><<<GBA, 512, 0, stream>>>(h0, scP(2), shP(2), nullptr);

    // Layer 3: y3 = pooled @ W3 + b3 -> h0 (in place), persistent pipeline
    mfma_gemm3_k<128, 0, 1, 8, ushort_t><<<GP, 256, 0, stream>>>(
        h0, wt3, b3, nullptr, nullptr, h0, sumP, sqP);
    reduce1_k<512><<<128, 256, 0, stream>>>(sumP, sqP, sumR2, sqR2);
    finalize_k<<<1, 128, 0, stream>>>(sumR2, sqR2, g3, be3, scP(3), shP(3));

    // Layer 4: out = bnrelu3(y3) @ W4 + b4 -> d_out (fp32), persistent pipeline
    mfma_gemm3_k<64, 1, 0, 8, float><<<GP, 256, 0, stream>>>(
        h0, wt4, b4, scP(3), shP(3), out, nullptr, nullptr);
}

// Round 11
// 364.913 us; speedup vs baseline: 2.4828x; 1.0300x over previous
//
#include <hip/hip_runtime.h>
#include <hip/hip_bf16.h>

// Problem constants (fixed by setup_inputs)
#define M_ROWS 262144   // B*A*T = 16*64*256
#define TILE_M 64
#define BK 32
#define REP 64          // second-level stats partials (matches finalize_k layout)

typedef unsigned short ushort_t;
typedef unsigned int uint_t;
typedef __attribute__((ext_vector_type(8))) short short8_t;   // 8 bf16 = 4 VGPRs
typedef __attribute__((ext_vector_type(4))) float float4_t;   // MFMA acc

// bf16 (stored as ushort) <-> fp32 helpers. Load is exact; store is RNE.
__device__ __forceinline__ float b2f(ushort_t u) {
    union { uint_t i; float f; } c; c.i = ((uint_t)u) << 16; return c.f;
}
__device__ __forceinline__ ushort_t f2b(float f) {
    union { float f; uint_t i; } c; c.f = f;
    uint_t u = c.i;
    return (ushort_t)((u + 0x7fffu + ((u >> 16) & 1u)) >> 16);
}
// packed 2xfp32 -> 2xbf16 (v_cvt_pk_bf16_f32 on gfx950, RNE)
__device__ __forceinline__ uint_t pack2(float a, float b) {
    union { __hip_bfloat162 h; uint_t u; } c;
    c.h = __float22bfloat162_rn(make_float2(a, b));
    return c.u;
}

// async global->LDS DMA, 16 B per lane; data lands at ldsbase + lane*16
__device__ __forceinline__ void gld_lds16(const ushort_t* g, ushort_t* l) {
    __builtin_amdgcn_global_load_lds((const __attribute__((address_space(1))) void*)g,
                                     (__attribute__((address_space(3))) void*)l, 16, 0, 0);
}

// ---------------------------------------------------------------------------
// Layer-1 N-SPLIT pipelined GEMM: C = [bnrelu0(X), P] @ W1 + b1 (K=256).
// Grid = 1024 blocks: blockIdx = tile*2 + nhalf; each block computes a 64-col
// half of N=128 for RPT=8 row-tiles. B half (64 rows x 256 K = 32 KB) resident;
// A double-buffered over (tile, kt) steps with DMA prefetch one step ahead.
// LDS ~67 KB -> 2 blocks/CU (8 waves/CU). Output C must NOT alias X or P
// (sibling blocks read full rows) -> C = d_out scratch.
// Waves 2x2 over the 64x64 sub-tile. Epilogue into Abuf[1] (free after kt=1).
// ---------------------------------------------------------------------------
template<int RPT>
__launch_bounds__(256)
__global__ void gemm1s_k(const ushort_t* __restrict__ X, const ushort_t* __restrict__ P,
                         const ushort_t* __restrict__ WT, const float* __restrict__ bias,
                         const float* __restrict__ scale, const float* __restrict__ shift,
                         ushort_t* __restrict__ C, float* __restrict__ sumP, float* __restrict__ sqP) {
    __shared__ __attribute__((aligned(16))) ushort_t Bs[64 * 256];       // 32 KB
    __shared__ __attribute__((aligned(16))) ushort_t Abuf[2][64 * 128];  // 2x16 KB
    __shared__ float sred[4 * 64 * 2];
    __shared__ float s_sc[128], s_sh[128];

    const int tid = threadIdx.x;
    const int lane = tid & 63;
    const int wave = tid >> 6;
    const int wm = wave & 1, wn = wave >> 1;
    const int quad = lane >> 4, l16 = lane & 15;
    const int srow = lane >> 4, sp16 = lane & 15;   // A staging
    const int brow = lane >> 5, bs32 = lane & 31;   // B staging (512 B rows)
    const int tileId = blockIdx.x >> 1;
    const int n0 = (blockIdx.x & 1) * 64;           // column-half offset
    const int row0 = tileId * (RPT * 64);

    if (tid < 128) { s_sc[tid] = scale[tid]; s_sh[tid] = shift[tid]; }

    // ---- stage B half (rows n0..n0+63 of WT, 512 B each): 32 chunks x 1 KB ----
    #pragma unroll
    for (int i = 0; i < 8; ++i) {
        int t = i * 4 + wave;
        int r = t * 2 + brow;                        // local B row 0..63
        int sp = (bs32 & 16) | ((bs32 ^ r) & 15);    // half-preserving XOR swizzle
        gld_lds16(WT + (size_t)(n0 + r) * 256 + sp * 8, Bs + t * 512);
    }

    auto stageA = [&](int it, int kt, int buf) {
        const ushort_t* src = kt ? P : X;
        int r0 = row0 + it * 64;
        #pragma unroll
        for (int i = 0; i < 4; ++i) {
            int t = i * 4 + wave;
            int r = t * 4 + srow;
            int sp = sp16 ^ (r & 15);
            gld_lds16(src + (size_t)(r0 + r) * 128 + sp * 8, Abuf[buf] + t * 512);
        }
    };
    stageA(0, 0, 0);

    float bvs[2];
    #pragma unroll
    for (int nt = 0; nt < 2; ++nt) bvs[nt] = bias[n0 + wn * 32 + nt * 16 + l16];
    float sSum[2] = {0.f, 0.f}, sSq[2] = {0.f, 0.f};

    int step = 0;
    for (int it = 0; it < RPT; ++it) {
        float4_t acc[2][2];
        #pragma unroll
        for (int mt = 0; mt < 2; ++mt)
            #pragma unroll
            for (int nt = 0; nt < 2; ++nt) acc[mt][nt] = (float4_t)0.f;

        #pragma unroll
        for (int kt = 0; kt < 2; ++kt) {
            __syncthreads();   // A(step) [+Bs on step 0] resident; prior epi reads done
            if (step + 1 < 2 * RPT) {
                int ns = step + 1;
                stageA(ns >> 1, ns & 1, ns & 1);
            }
            const ushort_t* As = Abuf[step & 1];
            #pragma unroll
            for (int kk = 0; kk < 4; ++kk) {
                int j = kk * 4 + quad;
                short8_t a0 = *(const short8_t*)&As[(wm * 32 + l16) * 128 + ((j ^ l16) * 8)];
                short8_t a1 = *(const short8_t*)&As[(wm * 32 + 16 + l16) * 128 + ((j ^ l16) * 8)];
                if (kt == 0) {   // bnrelu0 on X fragments
                    int kb = kk * 32 + quad * 8;
                    float4 c0 = *(const float4*)&s_sc[kb], c1 = *(const float4*)&s_sc[kb + 4];
                    float4 h0 = *(const float4*)&s_sh[kb], h1 = *(const float4*)&s_sh[kb + 4];
                    #pragma unroll
                    for (int z = 0; z < 2; ++z) {
                        ushort_t u[8];
                        *(short8_t*)u = z ? a1 : a0;
                        uint_t w[4];
                        w[0] = pack2(fmaxf(fmaf(b2f(u[0]), c0.x, h0.x), 0.f),
                                     fmaxf(fmaf(b2f(u[1]), c0.y, h0.y), 0.f));
                        w[1] = pack2(fmaxf(fmaf(b2f(u[2]), c0.z, h0.z), 0.f),
                                     fmaxf(fmaf(b2f(u[3]), c0.w, h0.w), 0.f));
                        w[2] = pack2(fmaxf(fmaf(b2f(u[4]), c1.x, h1.x), 0.f),
                                     fmaxf(fmaf(b2f(u[5]), c1.y, h1.y), 0.f));
                        w[3] = pack2(fmaxf(fmaf(b2f(u[6]), c1.z, h1.z), 0.f),
                                     fmaxf(fmaf(b2f(u[7]), c1.w, h1.w), 0.f));
                        short8_t rr;
                        *(uint4*)&rr = *(const uint4*)w;
                        if (z) a1 = rr; else a0 = rr;
                    }
                }
                #pragma unroll
                for (int nt = 0; nt < 2; ++nt) {
                    int br = wn * 32 + nt * 16 + l16;
                    short8_t bf = *(const short8_t*)&Bs[br * 256 + kt * 128 + ((j ^ l16) * 8)];
                    acc[0][nt] = __builtin_amdgcn_mfma_f32_16x16x32_bf16(a0, bf, acc[0][nt], 0, 0, 0);
                    acc[1][nt] = __builtin_amdgcn_mfma_f32_16x16x32_bf16(a1, bf, acc[1][nt], 0, 0, 0);
                }
            }
            ++step;
        }

        // ---- bias + stats accumulate ----
        #pragma unroll
        for (int mt = 0; mt < 2; ++mt)
            #pragma unroll
            for (int nt = 0; nt < 2; ++nt)
                #pragma unroll
                for (int r = 0; r < 4; ++r) {
                    float v = acc[mt][nt][r] + bvs[nt];
                    acc[mt][nt][r] = v;
                    sSum[nt] += v; sSq[nt] = fmaf(v, v, sSq[nt]);
                }
        if (it == RPT - 1) {
            #pragma unroll
            for (int nt = 0; nt < 2; ++nt) {
                float s = sSum[nt], q = sSq[nt];
                s += __shfl_xor(s, 16); q += __shfl_xor(q, 16);
                s += __shfl_xor(s, 32); q += __shfl_xor(q, 32);
                if (lane < 16) {
                    int colL = wn * 32 + nt * 16 + l16;
                    sred[(wave * 64 + colL) * 2 + 0] = s;
                    sred[(wave * 64 + colL) * 2 + 1] = q;
                }
            }
        }
        __syncthreads();   // kt=1 reads of Abuf[1] done; sred visible

        // ---- swizzled transpose into Abuf[1] (free; in-flight DMA targets buf0) ----
        char* eb = (char*)Abuf[1];
        #pragma unroll
        for (int mt = 0; mt < 2; ++mt)
            #pragma unroll
            for (int nt = 0; nt < 2; ++nt) {
                int colL = wn * 32 + nt * 16 + l16;
                int bc = colL * 2;
                #pragma unroll
                for (int r = 0; r < 4; ++r) {
                    int row = wm * 32 + mt * 16 + quad * 4 + r;
                    int addr = row * 128 + ((((bc >> 4) ^ (row & 7)) << 4) | (bc & 15));
                    *(ushort_t*)(eb + addr) = f2b(acc[mt][nt][r]);
                }
            }
        if (it == RPT - 1 && tid < 128) {
            int colL = tid & 63, qs = tid >> 6;
            int wb = (colL >> 5) * 2;   // the two waves (wm=0,1) owning this col
            float v = sred[(wb * 64 + colL) * 2 + qs] + sred[((wb + 1) * 64 + colL) * 2 + qs];
            (qs ? sqP : sumP)[(size_t)tileId * 128 + n0 + colL] = v;
        }
        __syncthreads();

        // ---- coalesced 16 B stores of the 64-col half (128 B per row) ----
        int r0s = row0 + it * 64;
        #pragma unroll
        for (int p = 0; p < 2; ++p) {
            int s = p * 256 + tid;
            int row = s >> 3, g = s & 7;
            uint4 v = *(const uint4*)(eb + row * 128 + ((g ^ (row & 7)) << 4));
            *(uint4*)((char*)(C + (size_t)(r0s + row) * 128 + n0) + g * 16) = v;
        }
    }
}

// ---------------------------------------------------------------------------
// Persistent pipelined MFMA GEMM for K=128 layers: C = act(A)@W + bias.
// ---------------------------------------------------------------------------
template<int N, int MODE, int STATS, int RPT, typename CT>
__launch_bounds__(256)
__global__ void mfma_gemm3_k(const ushort_t* __restrict__ A, const ushort_t* __restrict__ WT,
                             const float* __restrict__ bias,
                             const float* __restrict__ scale, const float* __restrict__ shift,
                             CT* __restrict__ C, float* __restrict__ sumP, float* __restrict__ sqP) {
    constexpr int WN = N / 2;        // cols per wave-column (64 or 32)
    constexpr int NT = WN / 16;      // 4 (N=128) or 2 (N=64)

    __shared__ __attribute__((aligned(16))) ushort_t Bs[N * 128];
    __shared__ __attribute__((aligned(16))) ushort_t Abuf[2][64 * 128];
    __shared__ float sred[STATS ? 4 * N * 2 : 1];
    __shared__ float s_sc[MODE == 1 ? 128 : 1];
    __shared__ float s_sh[MODE == 1 ? 128 : 1];

    const int tid = threadIdx.x;
    const int lane = tid & 63;
    const int wave = tid >> 6;
    const int wm = wave & 1;
    const int wn = wave >> 1;
    const int quad = lane >> 4;
    const int l16 = lane & 15;
    const int srow = lane >> 4;
    const int sp16 = lane & 15;

    if (MODE == 1 && tid < 128) { s_sc[tid] = scale[tid]; s_sh[tid] = shift[tid]; }

    #pragma unroll
    for (int i = 0; i < N / 16; ++i) {
        int t = i * 4 + wave;
        int r = t * 4 + srow;
        int sp = sp16 ^ (r & 15);
        gld_lds16(WT + (size_t)r * 128 + sp * 8, Bs + t * 512);
    }
    {
        int r0 = blockIdx.x * (RPT * 64);
        #pragma unroll
        for (int i = 0; i < 4; ++i) {
            int t = i * 4 + wave;
            int r = t * 4 + srow;
            int sp = sp16 ^ (r & 15);
            gld_lds16(A + (size_t)(r0 + r) * 128 + sp * 8, Abuf[0] + t * 512);
        }
    }

    float bvs[NT];
    #pragma unroll
    for (int nt = 0; nt < NT; ++nt) bvs[nt] = bias[wn * WN + nt * 16 + l16];
    float sSum[STATS ? NT : 1] = {0.f}, sSq[STATS ? NT : 1] = {0.f};

    for (int it = 0; it < RPT; ++it) {
        __syncthreads();
        if (it + 1 < RPT) {
            int r0 = blockIdx.x * (RPT * 64) + (it + 1) * 64;
            #pragma unroll
            for (int i = 0; i < 4; ++i) {
                int t = i * 4 + wave;
                int r = t * 4 + srow;
                int sp = sp16 ^ (r & 15);
                gld_lds16(A + (size_t)(r0 + r) * 128 + sp * 8, Abuf[(it + 1) & 1] + t * 512);
            }
        }
        const ushort_t* As = Abuf[it & 1];

        float4_t acc[2][NT];
        #pragma unroll
        for (int mt = 0; mt < 2; ++mt)
            #pragma unroll
            for (int nt = 0; nt < NT; ++nt) acc[mt][nt] = (float4_t)0.f;

        #pragma unroll
        for (int kk = 0; kk < 4; ++kk) {
            int j = kk * 4 + quad;
            short8_t a0 = *(const short8_t*)&As[(wm * 32 + l16) * 128 + ((j ^ l16) * 8)];
            short8_t a1 = *(const short8_t*)&As[(wm * 32 + 16 + l16) * 128 + ((j ^ l16) * 8)];
            if (MODE == 1) {
                int kb = kk * 32 + quad * 8;
                float4 c0 = *(const float4*)&s_sc[kb], c1 = *(const float4*)&s_sc[kb + 4];
                float4 h0 = *(const float4*)&s_sh[kb], h1 = *(const float4*)&s_sh[kb + 4];
                #pragma unroll
                for (int z = 0; z < 2; ++z) {
                    ushort_t u[8];
                    *(short8_t*)u = z ? a1 : a0;
                    uint_t w[4];
                    w[0] = pack2(fmaxf(fmaf(b2f(u[0]), c0.x, h0.x), 0.f),
                                 fmaxf(fmaf(b2f(u[1]), c0.y, h0.y), 0.f));
                    w[1] = pack2(fmaxf(fmaf(b2f(u[2]), c0.z, h0.z), 0.f),
                                 fmaxf(fmaf(b2f(u[3]), c0.w, h0.w), 0.f));
                    w[2] = pack2(fmaxf(fmaf(b2f(u[4]), c1.x, h1.x), 0.f),
                                 fmaxf(fmaf(b2f(u[5]), c1.y, h1.y), 0.f));
                    w[3] = pack2(fmaxf(fmaf(b2f(u[6]), c1.z, h1.z), 0.f),
                                 fmaxf(fmaf(b2f(u[7]), c1.w, h1.w), 0.f));
                    short8_t rr;
                    *(uint4*)&rr = *(const uint4*)w;
                    if (z) a1 = rr; else a0 = rr;
                }
            }
            #pragma unroll
            for (int nt = 0; nt < NT; ++nt) {
                short8_t bf = *(const short8_t*)&Bs[(wn * WN + nt * 16 + l16) * 128 + ((j ^ l16) * 8)];
                acc[0][nt] = __builtin_amdgcn_mfma_f32_16x16x32_bf16(a0, bf, acc[0][nt], 0, 0, 0);
                acc[1][nt] = __builtin_amdgcn_mfma_f32_16x16x32_bf16(a1, bf, acc[1][nt], 0, 0, 0);
            }
        }

        #pragma unroll
        for (int mt = 0; mt < 2; ++mt)
            #pragma unroll
            for (int nt = 0; nt < NT; ++nt)
                #pragma unroll
                for (int r = 0; r < 4; ++r) {
                    float v = acc[mt][nt][r] + bvs[nt];
                    acc[mt][nt][r] = v;
                    if (STATS) { sSum[nt] += v; sSq[nt] = fmaf(v, v, sSq[nt]); }
                }
        if (STATS && it == RPT - 1) {
            #pragma unroll
            for (int nt = 0; nt < NT; ++nt) {
                float s = sSum[nt], q = sSq[nt];
                s += __shfl_xor(s, 16); q += __shfl_xor(q, 16);
                s += __shfl_xor(s, 32); q += __shfl_xor(q, 32);
                if (lane < 16) {
                    int col = wn * WN + nt * 16 + l16;
                    sred[(wave * N + col) * 2 + 0] = s;
                    sred[(wave * N + col) * 2 + 1] = q;
                }
            }
        }
        __syncthreads();

        char* eb = (char*)Abuf[it & 1];
        #pragma unroll
        for (int mt = 0; mt < 2; ++mt)
            #pragma unroll
            for (int nt = 0; nt < NT; ++nt) {
                int col = wn * WN + nt * 16 + l16;
                int bc = col * (int)sizeof(CT);
                #pragma unroll
                for (int r = 0; r < 4; ++r) {
                    int row = wm * 32 + mt * 16 + quad * 4 + r;
                    int addr = row * 256 + ((((bc >> 4) ^ (row & 15)) << 4) | (bc & 15));
                    if constexpr (sizeof(CT) == 4) *(float*)(eb + addr) = acc[mt][nt][r];
                    else                           *(ushort_t*)(eb + addr) = f2b(acc[mt][nt][r]);
                }
            }
        if (STATS && it == RPT - 1) {
            int col = tid & (N - 1), qs = tid / N;
            int wb = (col / WN) * 2;
            float v = sred[(wb * N + col) * 2 + qs] + sred[((wb + 1) * N + col) * 2 + qs];
            (qs ? sqP : sumP)[(size_t)blockIdx.x * N + col] = v;
        }
        __syncthreads();

        int r0 = blockIdx.x * (RPT * 64) + it * 64;
        #pragma unroll
        for (int p = 0; p < 4; ++p) {
            int s = p * 256 + tid;
            int row = s >> 4, g = s & 15;
            uint4 v = *(const uint4*)(eb + row * 256 + ((g ^ (row & 15)) << 4));
            *(uint4*)((char*)(C + (size_t)(r0 + row) * N) + g * 16) = v;
        }
    }
}

// ---------------------------------------------------------------------------
// fp32 vector GEMM (layer 0: K=32, fp32 input) with fused stats partials.
// ---------------------------------------------------------------------------
template<int K, int N>
__launch_bounds__(256)
__global__ void gemm_f32_k(const float* __restrict__ A, const float* __restrict__ W,
                           const float* __restrict__ bias, ushort_t* __restrict__ C,
                           float* __restrict__ sumP, float* __restrict__ sqP) {
    constexpr int TX = N / 4;        // 32
    constexpr int TY = 256 / TX;     // 8
    constexpr int RM = TILE_M / TY;  // 8

    __shared__ float As[TILE_M][BK + 1];
    __shared__ float Ws[BK][N];
    __shared__ float redst[2][TY][N];

    const int tid = threadIdx.x;
    const int tx = tid % TX;
    const int ty = tid / TX;
    const int row0 = blockIdx.x * TILE_M;
    const int arow = tid >> 2;
    const int acol = (tid & 3) * 8;

    float acc[RM][4];
    #pragma unroll
    for (int r = 0; r < RM; ++r)
        #pragma unroll
        for (int c = 0; c < 4; ++c) acc[r][c] = 0.f;

    for (int k0 = 0; k0 < K; k0 += BK) {
        {
            const float4* p = (const float4*)&A[(size_t)(row0 + arow) * K + k0 + acol];
            float4 x0 = p[0], x1 = p[1];
            As[arow][acol + 0] = x0.x; As[arow][acol + 1] = x0.y;
            As[arow][acol + 2] = x0.z; As[arow][acol + 3] = x0.w;
            As[arow][acol + 4] = x1.x; As[arow][acol + 5] = x1.y;
            As[arow][acol + 6] = x1.z; As[arow][acol + 7] = x1.w;
        }
        #pragma unroll
        for (int i = 0; i < (BK * N) / 256; ++i) {
            int e = i * 256 + tid;
            Ws[e / N][e % N] = W[(size_t)(k0 + e / N) * N + e % N];
        }
        __syncthreads();
        #pragma unroll
        for (int kk = 0; kk < BK; ++kk) {
            float4 wv = *(const float4*)&Ws[kk][tx * 4];
            #pragma unroll
            for (int r = 0; r < RM; ++r) {
                float a = As[ty * RM + r][kk];
                acc[r][0] = fmaf(a, wv.x, acc[r][0]);
                acc[r][1] = fmaf(a, wv.y, acc[r][1]);
                acc[r][2] = fmaf(a, wv.z, acc[r][2]);
                acc[r][3] = fmaf(a, wv.w, acc[r][3]);
            }
        }
        __syncthreads();
    }
    float4 bv = *(const float4*)&bias[tx * 4];
    float s[4] = {0, 0, 0, 0}, q[4] = {0, 0, 0, 0};
    #pragma unroll
    for (int r = 0; r < RM; ++r) {
        float o[4];
        o[0] = acc[r][0] + bv.x; o[1] = acc[r][1] + bv.y;
        o[2] = acc[r][2] + bv.z; o[3] = acc[r][3] + bv.w;
        #pragma unroll
        for (int c = 0; c < 4; ++c) { s[c] += o[c]; q[c] = fmaf(o[c], o[c], q[c]); }
        size_t off = (size_t)(row0 + ty * RM + r) * N + tx * 4;
        uint2 ov;
        ov.x = pack2(o[0], o[1]);
        ov.y = pack2(o[2], o[3]);
        *(uint2*)&C[off] = ov;
    }
    #pragma unroll
    for (int c = 0; c < 4; ++c) {
        redst[0][ty][tx * 4 + c] = s[c];
        redst[1][ty][tx * 4 + c] = q[c];
    }
    __syncthreads();
    {
        int col = tid & (N - 1), qs = tid / N;
        float v = 0.f;
        #pragma unroll
        for (int t = 0; t < TY; ++t) v += redst[qs][t][col];
        (qs ? sqP : sumP)[(size_t)blockIdx.x * N + col] = v;
    }
}

// ---------------------------------------------------------------------------
// Tree-reduce block partials: P[NBLK][128] -> R2[col*64 + chunk] (64 chunks).
// ---------------------------------------------------------------------------
template<int NBLK>
__global__ __launch_bounds__(256) void reduce1_k(const float* __restrict__ sumP,
                                                 const float* __restrict__ sqP,
                                                 float* __restrict__ sumR2,
                                                 float* __restrict__ sqR2) {
    constexpr int ROWS = NBLK / 64;
    const int tid = threadIdx.x;
    const int qs = blockIdx.x & 1;
    const int chunk = blockIdx.x >> 1;
    const float* src = qs ? sqP : sumP;
    float* dst = qs ? sqR2 : sumR2;
    const int col = tid & 127;
    const int half = tid >> 7;
    float s = 0.f;
    for (int r = half; r < ROWS; r += 2)
        s += src[(size_t)(chunk * ROWS + r) * 128 + col];
    __shared__ float red[256];
    red[tid] = s;
    __syncthreads();
    if (tid < 128) dst[col * 64 + chunk] = red[tid] + red[tid + 128];
}

// Reduce 64 chunks; scale = g*rsqrt(var+eps); shift = be - mean*scale
__global__ void finalize_k(const float* __restrict__ sumR2, const float* __restrict__ sqR2,
                           const float* __restrict__ g, const float* __restrict__ be,
                           float* __restrict__ scale, float* __restrict__ shift) {
    const int f = threadIdx.x;  // 128
    const float4* ps = (const float4*)&sumR2[f * REP];
    const float4* pq = (const float4*)&sqR2[f * REP];
    float s = 0.f, q = 0.f;
    #pragma unroll
    for (int i = 0; i < REP / 4; ++i) {
        float4 a = ps[i]; s += (a.x + a.y) + (a.z + a.w);
        float4 b = pq[i]; q += (b.x + b.y) + (b.z + b.w);
    }
    const float invM = 1.f / (float)M_ROWS;
    float mean = s * invM;
    float var = q * invM - mean * mean;
    float sc = g[f] * rsqrtf(var + 1e-5f);
    scale[f] = sc;
    shift[f] = fmaf(-mean, sc, be[f]);
}

// All four weight transposes in one launch: fp32 W[K][N] -> bf16 WT[N][K]
__global__ void transpose_all_k(const float* __restrict__ W1, const float* __restrict__ W2,
                                const float* __restrict__ W3, const float* __restrict__ W4,
                                ushort_t* __restrict__ wt1, ushort_t* __restrict__ wt2,
                                ushort_t* __restrict__ wt3, ushort_t* __restrict__ wt4) {
    int idx = blockIdx.x * 256 + threadIdx.x;
    if (idx < 32768) {                       // W1: 256 x 128
        int k = idx >> 7, n = idx & 127;
        wt1[(size_t)n * 256 + k] = f2b(W1[idx]);
    } else if (idx < 49152) {                // W2: 128 x 128
        int i = idx - 32768;
        int k = i >> 7, n = i & 127;
        wt2[(size_t)n * 128 + k] = f2b(W2[i]);
    } else if (idx < 65536) {                // W3: 128 x 128
        int i = idx - 49152;
        int k = i >> 7, n = i & 127;
        wt3[(size_t)n * 128 + k] = f2b(W3[i]);
    } else if (idx < 73728) {                // W4: 128 x 64
        int i = idx - 65536;
        int k = i >> 6, n = i & 63;
        wt4[(size_t)n * 128 + k] = f2b(W4[i]);
    }
}

// ---------------------------------------------------------------------------
// Chunked causal cummax, one block per (ba) sequence (T=256, 128 feats).
// ---------------------------------------------------------------------------
template<int INPLACE>
__global__ __launch_bounds__(512) void scan_k(const ushort_t* __restrict__ Y,
                                              const float* __restrict__ scale,
                                              const float* __restrict__ shift,
                                              ushort_t* __restrict__ P) {
    const int tid = threadIdx.x;
    const int fp = tid & 63;
    const int chunk = tid >> 6;
    const size_t base = (size_t)blockIdx.x * 256 * 128 + fp * 2;
    const float sc0 = scale[fp * 2], sh0 = shift[fp * 2];
    const float sc1 = scale[fp * 2 + 1], sh1 = shift[fp * 2 + 1];

    __shared__ float cmax[8][128];

    uint_t vals[32];
    float run0 = 0.f, run1 = 0.f;
    #pragma unroll
    for (int i = 0; i < 32; ++i) {
        size_t idx = base + (size_t)(chunk * 32 + i) * 128;
        uint_t u = *(const uint_t*)&Y[idx];
        float v0 = fmaxf(fmaf(b2f((ushort_t)(u & 0xffff)), sc0, sh0), 0.f);
        float v1 = fmaxf(fmaf(b2f((ushort_t)(u >> 16)), sc1, sh1), 0.f);
        run0 = fmaxf(run0, v0);
        run1 = fmaxf(run1, v1);
        vals[i] = pack2(v0, v1);
    }
    cmax[chunk][fp * 2] = run0;
    cmax[chunk][fp * 2 + 1] = run1;
    __syncthreads();
    float p0 = 0.f, p1 = 0.f;
    for (int c = 0; c < chunk; ++c) {
        p0 = fmaxf(p0, cmax[c][fp * 2]);
        p1 = fmaxf(p1, cmax[c][fp * 2 + 1]);
    }
    run0 = p0; run1 = p1;
    ushort_t* dst = INPLACE ? (ushort_t*)Y : P;
    #pragma unroll
    for (int i = 0; i < 32; ++i) {
        uint_t u = vals[i];
        run0 = fmaxf(run0, b2f((ushort_t)(u & 0xffff)));
        run1 = fmaxf(run1, b2f((ushort_t)(u >> 16)));
        *(uint_t*)&dst[base + (size_t)(chunk * 32 + i) * 128] = pack2(run0, run1);
    }
}

extern "C" void kernel_launch(void* const* d_in, const int* in_sizes, int n_in,
                              void* d_out, int out_size, void* d_ws, size_t ws_size,
                              hipStream_t stream) {
    const float* poly = (const float*)d_in[0];
    const float* W0 = (const float*)d_in[1];
    const float* b0 = (const float*)d_in[2];
    const float* g0 = (const float*)d_in[3];
    const float* be0 = (const float*)d_in[4];
    const float* W1 = (const float*)d_in[5];
    const float* b1 = (const float*)d_in[6];
    const float* g1 = (const float*)d_in[7];
    const float* be1 = (const float*)d_in[8];
    const float* W2 = (const float*)d_in[9];
    const float* b2 = (const float*)d_in[10];
    const float* g2 = (const float*)d_in[11];
    const float* be2 = (const float*)d_in[12];
    const float* W3 = (const float*)d_in[13];
    const float* b3 = (const float*)d_in[14];
    const float* g3 = (const float*)d_in[15];
    const float* be3 = (const float*)d_in[16];
    const float* W4 = (const float*)d_in[17];
    const float* b4 = (const float*)d_in[18];
    float* out = (float*)d_out;

    float* st = (float*)d_ws;
    float* sumP = st;
    float* sqP = st + 524288;
    float* sumR2 = st + 1048576;
    float* sqR2 = sumR2 + 8192;
    float* scsh = st + 1064960;
    auto scP = [&](int i) { return scsh + i * 256; };
    auto shP = [&](int i) { return scsh + i * 256 + 128; };
    ushort_t* wt1 = (ushort_t*)((char*)d_ws + 4263936);         // 128 x 256
    ushort_t* wt2 = wt1 + 128 * 256;                            // 128 x 128
    ushort_t* wt3 = wt2 + 128 * 128;                            // 128 x 128
    ushort_t* wt4 = wt3 + 128 * 128;                            // 64 x 128
    ushort_t* h0 = (ushort_t*)((char*)d_ws + 4263936 + 147456);
    ushort_t* h1 = h0 + (size_t)M_ROWS * 128;
    ushort_t* y1 = (ushort_t*)out;   // d_out doubles as y1 scratch (M*128 bf16
                                     // == out_size bytes); overwritten by L4.

    const int G64 = M_ROWS / TILE_M;    // 4096 (L0)
    const int GP = M_ROWS / (64 * 8);   // 512 (persistent kernels, RPT=8)
    const int GBA = 1024;               // one block per (b,a) sequence

    transpose_all_k<<<288, 256, 0, stream>>>(W1, W2, W3, W4, wt1, wt2, wt3, wt4);

    // Layer 0 (fp32 precision): y0 = poly @ W0 + b0 -> h0 (raw bf16) + partials
    gemm_f32_k<32, 128><<<G64, 256, 0, stream>>>(poly, W0, b0, h0, sumP, sqP);
    reduce1_k<4096><<<128, 256, 0, stream>>>(sumP, sqP, sumR2, sqR2);
    finalize_k<<<1, 128, 0, stream>>>(sumR2, sqR2, g0, be0, scP(0), shP(0));

    // P = cummax(bnrelu0(y0)) -> h1 ; h0 stays RAW y0
    scan_k<0><<<GBA, 512, 0, stream>>>(h0, scP(0), shP(0), h1);

    // Layer 1: y1 = [bnrelu0(y0), P] @ W1 + b1 -> d_out scratch (N-split, 2 blk/CU)
    gemm1s_k<8><<<2 * GP, 256, 0, stream>>>(h0, h1, wt1, b1, scP(0), shP(0), y1, sumP, sqP);
    reduce1_k<512><<<128, 256, 0, stream>>>(sumP, sqP, sumR2, sqR2);
    finalize_k<<<1, 128, 0, stream>>>(sumR2, sqR2, g1, be1, scP(1), shP(1));

    // Layer 2: y2 = bnrelu1(y1) @ W2 + b2 : d_out -> h0
    mfma_gemm3_k<128, 1, 1, 8, ushort_t><<<GP, 256, 0, stream>>>(
        y1, wt2, b2, scP(1), shP(1), h0, sumP, sqP);
    reduce1_k<512><<<128, 256, 0, stream>>>(sumP, sqP, sumR2, sqR2);
    finalize_k<<<1, 128, 0, stream>>>(sumR2, sqR2, g2, be2, scP(2), shP(2));

    // pooled = cummax(bnrelu2(y2)) in place in h0
    scan_k<1><<<GBA, 512, 0, stream>>>(h0, scP(2), shP(2), nullptr);

    // Layer 3: y3 = pooled @ W3 + b3 -> h0 (in place), persistent pipeline
    mfma_gemm3_k<128, 0, 1, 8, ushort_t><<<GP, 256, 0, stream>>>(
        h0, wt3, b3, nullptr, nullptr, h0, sumP, sqP);
    reduce1_k<512><<<128, 256, 0, stream>>>(sumP, sqP, sumR2, sqR2);
    finalize_k<<<1, 128, 0, stream>>>(sumR2, sqR2, g3, be3, scP(3), shP(3));

    // Layer 4: out = bnrelu3(y3) @ W4 + b4 -> d_out (fp32; overwrites y1 scratch)
    mfma_gemm3_k<64, 1, 0, 8, float><<<GP, 256, 0, stream>>>(
        h0, wt4, b4, scP(3), shP(3), out, nullptr, nullptr);
}